// Round 1
// baseline (1169.723 us; speedup 1.0000x reference)
//
#include <hip/hip_runtime.h>
#include <math.h>

#define N_NODES 50000
#define NUM_E   800000
#define E_TOT   (NUM_E + N_NODES)   // 850000 (self loops appended)
#define NGRAPH  128
#define XS_COLS 576
#define EPS_BN  1e-5f

static inline int ceil_div(int a, int b) { return (a + b - 1) / b; }

// ---------------- tiled fp32 GEMM:  C[M x Nc] = A[M x K](lda) @ W[K x Nc](ldw) ----------------
template<int BM, int BN, int BK, int TM, int TN>
__global__ __launch_bounds__(256)
void gemm_f32(const float* __restrict__ A, int lda,
              const float* __restrict__ W, int ldw,
              float* __restrict__ C, int ldc,
              int M, int K)
{
    static_assert(TM == 8 && TN == 4 && BK == 16, "tuned variant");
    __shared__ float As[BK][BM + 4];
    __shared__ float Ws[BK][BN + 4];
    const int tid = threadIdx.x;
    const int m0 = blockIdx.x * BM;
    const int n0 = blockIdx.y * BN;
    const int tx = tid % (BN / TN);   // 16
    const int ty = tid / (BN / TN);   // 16

    float acc[TM][TN];
#pragma unroll
    for (int i = 0; i < TM; ++i)
#pragma unroll
        for (int j = 0; j < TN; ++j) acc[i][j] = 0.f;

    for (int k0 = 0; k0 < K; k0 += BK) {
        // A tile: BM x BK, transposed into As[k][m]
        const int ka = tid % BK;
        const int ma0 = tid / BK;     // 0..15
#pragma unroll
        for (int j = 0; j < BM / 16; ++j) {
            int m = m0 + ma0 + j * 16;
            As[ka][ma0 + j * 16] = (m < M) ? A[(size_t)m * lda + k0 + ka] : 0.f;
        }
        // W tile: BK x BN
        const int nw = tid % BN;
        const int kw0 = tid / BN;
#pragma unroll
        for (int j = 0; j < (BK * BN) / 256; ++j) {
            int kw = kw0 + j * (256 / BN);
            Ws[kw][nw] = W[(size_t)(k0 + kw) * ldw + n0 + nw];
        }
        __syncthreads();
#pragma unroll
        for (int k = 0; k < BK; ++k) {
            float4 a0 = *reinterpret_cast<const float4*>(&As[k][ty * TM + 0]);
            float4 a1 = *reinterpret_cast<const float4*>(&As[k][ty * TM + 4]);
            float4 bb = *reinterpret_cast<const float4*>(&Ws[k][tx * TN]);
            float av[TM] = {a0.x, a0.y, a0.z, a0.w, a1.x, a1.y, a1.z, a1.w};
            float bv[TN] = {bb.x, bb.y, bb.z, bb.w};
#pragma unroll
            for (int i = 0; i < TM; ++i)
#pragma unroll
                for (int j = 0; j < TN; ++j)
                    acc[i][j] = fmaf(av[i], bv[j], acc[i][j]);
        }
        __syncthreads();
    }
#pragma unroll
    for (int i = 0; i < TM; ++i) {
        int m = m0 + ty * TM + i;
        if (m < M) {
            float4 v = make_float4(acc[i][0], acc[i][1], acc[i][2], acc[i][3]);
            *reinterpret_cast<float4*>(&C[(size_t)m * ldc + n0 + tx * TN]) = v;
        }
    }
}

// ---------------- a_s / a_d:  a_s[n,h] = sum_c h[n,h*C+c] * asrc[h,c] ----------------
template<int H, int C>
__global__ __launch_bounds__(256)
void attn_coef(const float* __restrict__ hf, const float* __restrict__ asrc,
               const float* __restrict__ adst,
               float* __restrict__ a_s, float* __restrict__ a_d)
{
    constexpr int V = (H * C) / 64;
    const int lane = threadIdx.x & 63;
    const int n = blockIdx.x * 4 + (threadIdx.x >> 6);
    if (n >= N_NODES) return;
    const float* hp = hf + (size_t)n * (H * C) + lane * V;
    float ss = 0.f, dd = 0.f;
    if constexpr (V == 4) {
        float4 hv = *reinterpret_cast<const float4*>(hp);
        float4 sv = *reinterpret_cast<const float4*>(asrc + lane * 4);
        float4 dv = *reinterpret_cast<const float4*>(adst + lane * 4);
        ss = hv.x * sv.x + hv.y * sv.y + hv.z * sv.z + hv.w * sv.w;
        dd = hv.x * dv.x + hv.y * dv.y + hv.z * dv.z + hv.w * dv.w;
    } else {
        float hv = hp[0];
        ss = hv * asrc[lane];
        dd = hv * adst[lane];
    }
    constexpr int GS = C / V;   // lanes per head
#pragma unroll
    for (int o = 1; o < GS; o <<= 1) {
        ss += __shfl_xor(ss, o, 64);
        dd += __shfl_xor(dd, o, 64);
    }
    if ((lane & (GS - 1)) == 0) {
        int hd = lane / GS;
        a_s[(size_t)n * H + hd] = ss;
        a_d[(size_t)n * H + hd] = dd;
    }
}

// ---------------- per-dst GAT aggregation (one wave per destination node) ----------------
template<int H, int C>
__global__ __launch_bounds__(256)
void gat_aggregate(const int* __restrict__ offs, const int* __restrict__ ssrc,
                   const float* __restrict__ a_s, const float* __restrict__ a_d,
                   const float* __restrict__ hf, const float* __restrict__ bias,
                   float* __restrict__ out, int ldo)
{
    constexpr int V = (H * C) / 64;
    const int lane = threadIdx.x & 63;
    const int dst = blockIdx.x * 4 + (threadIdx.x >> 6);
    if (dst >= N_NODES) return;
    const int e0 = offs[dst], e1 = offs[dst + 1];

    float ad[H];
    if constexpr (H == 4) {
        float4 v = *reinterpret_cast<const float4*>(a_d + (size_t)dst * 4);
        ad[0] = v.x; ad[1] = v.y; ad[2] = v.z; ad[3] = v.w;
    } else ad[0] = a_d[dst];

    // phase 1a: per-head max over in-edges
    float mx[H];
#pragma unroll
    for (int t = 0; t < H; ++t) mx[t] = -INFINITY;
    for (int e = e0 + lane; e < e1; e += 64) {
        int s = ssrc[e];
        float asv[H];
        if constexpr (H == 4) {
            float4 v = *reinterpret_cast<const float4*>(a_s + (size_t)s * 4);
            asv[0] = v.x; asv[1] = v.y; asv[2] = v.z; asv[3] = v.w;
        } else asv[0] = a_s[s];
#pragma unroll
        for (int t = 0; t < H; ++t) {
            float l = asv[t] + ad[t];
            l = l > 0.f ? l : 0.2f * l;
            mx[t] = fmaxf(mx[t], l);
        }
    }
#pragma unroll
    for (int t = 0; t < H; ++t)
#pragma unroll
        for (int o = 1; o < 64; o <<= 1) mx[t] = fmaxf(mx[t], __shfl_xor(mx[t], o, 64));

    // phase 1b: per-head sum of exp
    float sm[H];
#pragma unroll
    for (int t = 0; t < H; ++t) sm[t] = 0.f;
    for (int e = e0 + lane; e < e1; e += 64) {
        int s = ssrc[e];
        float asv[H];
        if constexpr (H == 4) {
            float4 v = *reinterpret_cast<const float4*>(a_s + (size_t)s * 4);
            asv[0] = v.x; asv[1] = v.y; asv[2] = v.z; asv[3] = v.w;
        } else asv[0] = a_s[s];
#pragma unroll
        for (int t = 0; t < H; ++t) {
            float l = asv[t] + ad[t];
            l = l > 0.f ? l : 0.2f * l;
            sm[t] += expf(l - mx[t]);
        }
    }
#pragma unroll
    for (int t = 0; t < H; ++t)
#pragma unroll
        for (int o = 1; o < 64; o <<= 1) sm[t] += __shfl_xor(sm[t], o, 64);

    // select this lane's head constants (static-index selects, no scratch)
    const int hd = (lane * V) / C;
    float mxl = mx[0], sml = sm[0], adl = ad[0];
#pragma unroll
    for (int t = 1; t < H; ++t) {
        mxl = (hd == t) ? mx[t] : mxl;
        sml = (hd == t) ? sm[t] : sml;
        adl = (hd == t) ? ad[t] : adl;
    }
    const float invl = 1.f / (sml + 1e-16f);

    // phase 2: weighted accumulation of h[src]
    float acc[V];
#pragma unroll
    for (int k = 0; k < V; ++k) acc[k] = 0.f;
    for (int e = e0; e < e1; ++e) {
        int s = ssrc[e];
        float l = a_s[(size_t)s * H + hd] + adl;
        l = l > 0.f ? l : 0.2f * l;
        float alpha = expf(l - mxl) * invl;
        const float* hp = hf + (size_t)s * (H * C) + lane * V;
        if constexpr (V == 4) {
            float4 hv = *reinterpret_cast<const float4*>(hp);
            acc[0] = fmaf(alpha, hv.x, acc[0]);
            acc[1] = fmaf(alpha, hv.y, acc[1]);
            acc[2] = fmaf(alpha, hv.z, acc[2]);
            acc[3] = fmaf(alpha, hv.w, acc[3]);
        } else {
            acc[0] = fmaf(alpha, hp[0], acc[0]);
        }
    }
    // epilogue: + bias, ELU, store into xs slice of d_out
    if constexpr (V == 4) {
        float4 v;
        float t0 = acc[0] + bias[lane * 4 + 0];
        float t1 = acc[1] + bias[lane * 4 + 1];
        float t2 = acc[2] + bias[lane * 4 + 2];
        float t3 = acc[3] + bias[lane * 4 + 3];
        v.x = t0 > 0.f ? t0 : (expf(t0) - 1.f);
        v.y = t1 > 0.f ? t1 : (expf(t1) - 1.f);
        v.z = t2 > 0.f ? t2 : (expf(t2) - 1.f);
        v.w = t3 > 0.f ? t3 : (expf(t3) - 1.f);
        *reinterpret_cast<float4*>(&out[(size_t)dst * ldo + lane * 4]) = v;
    } else {
        float t0 = acc[0] + bias[lane];
        out[(size_t)dst * ldo + lane] = t0 > 0.f ? t0 : (expf(t0) - 1.f);
    }
}

// ---------------- edge bucketing ----------------
__global__ void edge_count(const int* __restrict__ ei, int* __restrict__ counts)
{
    int i = blockIdx.x * blockDim.x + threadIdx.x;
    if (i >= E_TOT) return;
    int dst = (i < NUM_E) ? ei[NUM_E + i] : (i - NUM_E);
    atomicAdd(&counts[dst], 1);
}

__global__ void edge_scatter(const int* __restrict__ ei, int* __restrict__ cursor,
                             int* __restrict__ ssrc)
{
    int i = blockIdx.x * blockDim.x + threadIdx.x;
    if (i >= E_TOT) return;
    int src, dst;
    if (i < NUM_E) { src = ei[i]; dst = ei[NUM_E + i]; }
    else           { src = dst = i - NUM_E; }
    int pos = atomicAdd(&cursor[dst], 1);
    ssrc[pos] = src;
}

// ---------------- generic scan (blocks of 256) ----------------
__global__ void scan_block(const int* __restrict__ in, int n,
                           int* __restrict__ incl, int* __restrict__ bsum)
{
    __shared__ int sh[256];
    int tid = threadIdx.x;
    int i = blockIdx.x * 256 + tid;
    int v = (i < n) ? in[i] : 0;
    sh[tid] = v;
    __syncthreads();
    for (int o = 1; o < 256; o <<= 1) {
        int t = (tid >= o) ? sh[tid - o] : 0;
        __syncthreads();
        sh[tid] += t;
        __syncthreads();
    }
    if (i < n) incl[i] = sh[tid];
    if (tid == 255) bsum[blockIdx.x] = sh[255];
}

__global__ void scan_sums(int* __restrict__ bsum, int nb)  // single block, in-place exclusive
{
    __shared__ int sh[256];
    int tid = threadIdx.x;
    int v = (tid < nb) ? bsum[tid] : 0;
    sh[tid] = v;
    __syncthreads();
    for (int o = 1; o < 256; o <<= 1) {
        int t = (tid >= o) ? sh[tid - o] : 0;
        __syncthreads();
        sh[tid] += t;
        __syncthreads();
    }
    if (tid < nb) bsum[tid] = sh[tid] - v;
}

__global__ void scan_final(const int* __restrict__ incl, const int* __restrict__ in,
                           const int* __restrict__ bsum, int n,
                           int* __restrict__ offs, int* __restrict__ cursor)
{
    int i = blockIdx.x * 256 + threadIdx.x;
    if (i >= n) return;
    int excl = incl[i] - in[i] + bsum[i / 256];
    offs[i] = excl;
    cursor[i] = excl;
    if (i == n - 1) offs[n] = incl[i] + bsum[i / 256];
}

__global__ void batch_count(const int* __restrict__ batch, int* __restrict__ gcounts)
{
    int i = blockIdx.x * blockDim.x + threadIdx.x;
    if (i < N_NODES) atomicAdd(&gcounts[batch[i]], 1);
}

// ---------------- BatchNorm ----------------
template<int OF>
__global__ __launch_bounds__(256)
void bn_stats(const float* __restrict__ x, int ldx, float* __restrict__ sums)
{
    constexpr int RP = 256 / OF;
    const int tid = threadIdx.x;
    const int col = tid % OF;
    const int rsub = tid / OF;
    float s = 0.f, s2 = 0.f;
    for (int r = blockIdx.x * RP + rsub; r < N_NODES; r += gridDim.x * RP) {
        float v = x[(size_t)r * ldx + col];
        s += v;
        s2 = fmaf(v, v, s2);
    }
    if constexpr (RP > 1) {
        __shared__ float sh[2][256];
        sh[0][tid] = s; sh[1][tid] = s2;
        __syncthreads();
        if (rsub == 0) {
#pragma unroll
            for (int j = 1; j < RP; ++j) { s += sh[0][col + j * OF]; s2 += sh[1][col + j * OF]; }
        }
    }
    if (rsub == 0) {
        atomicAdd(&sums[col], s);
        atomicAdd(&sums[OF + col], s2);
    }
}

template<int OF>
__global__ void bn_finalize(const float* __restrict__ sums, const float* __restrict__ gamma,
                            const float* __restrict__ beta, float* __restrict__ ss)
{
    int c = threadIdx.x;
    if (c >= OF) return;
    float mean = sums[c] / (float)N_NODES;
    float var = sums[OF + c] / (float)N_NODES - mean * mean;
    float inv = rsqrtf(var + EPS_BN);
    float sc = inv * gamma[c];
    ss[c] = sc;
    ss[OF + c] = beta[c] - mean * sc;
}

template<int OF>
__global__ __launch_bounds__(256)
void bn_apply(float* __restrict__ x, int ldx, const float* __restrict__ ss)
{
    int i = blockIdx.x * 256 + threadIdx.x;
    if (i >= N_NODES * OF) return;
    int r = i / OF, c = i % OF;
    float v = x[(size_t)r * ldx + c];
    x[(size_t)r * ldx + c] = fmaf(v, ss[c], ss[OF + c]);
}

// ---------------- graph pooling (batch is sorted -> contiguous rows) ----------------
__global__ void pool_kernel(const float* __restrict__ xs, const int* __restrict__ goffs,
                            float* __restrict__ pool)
{
    int g = blockIdx.x;
    int c = threadIdx.x;  // 576
    int r0 = goffs[g], r1 = goffs[g + 1];
    float s = 0.f;
    for (int r = r0; r < r1; ++r) s += xs[(size_t)r * XS_COLS + c];
    pool[(size_t)g * XS_COLS + c] = s;
}

extern "C" void kernel_launch(void* const* d_in, const int* in_sizes, int n_in,
                              void* d_out, int out_size, void* d_ws, size_t ws_size,
                              hipStream_t stream)
{
    const float* x     = (const float*)d_in[0];
    const int*   ei    = (const int*)d_in[1];
    const int*   batch = (const int*)d_in[2];
    const float* W[3]    = {(const float*)d_in[3],  (const float*)d_in[9],  (const float*)d_in[15]};
    const float* asrc[3] = {(const float*)d_in[4],  (const float*)d_in[10], (const float*)d_in[16]};
    const float* adst[3] = {(const float*)d_in[5],  (const float*)d_in[11], (const float*)d_in[17]};
    const float* bia[3]  = {(const float*)d_in[6],  (const float*)d_in[12], (const float*)d_in[18]};
    const float* gam[3]  = {(const float*)d_in[7],  (const float*)d_in[13], (const float*)d_in[19]};
    const float* bet[3]  = {(const float*)d_in[8],  (const float*)d_in[14], (const float*)d_in[20]};

    char* wp = (char*)d_ws;
    auto alloc = [&](size_t bytes) -> void* {
        void* p = (void*)wp;
        wp += (bytes + 255) & ~(size_t)255;
        return p;
    };
    float* h      = (float*)alloc((size_t)N_NODES * 256 * 4);
    float* a_s    = (float*)alloc((size_t)N_NODES * 4 * 4);
    float* a_d    = (float*)alloc((size_t)N_NODES * 4 * 4);
    int*   counts = (int*)alloc((size_t)N_NODES * 4);
    int*   offs   = (int*)alloc((size_t)(N_NODES + 1) * 4);
    int*   cursor = (int*)alloc((size_t)N_NODES * 4);
    int*   incl   = (int*)alloc((size_t)N_NODES * 4);
    int*   bsums  = (int*)alloc(1024);
    int*   ssrc   = (int*)alloc((size_t)E_TOT * 4);
    float* bnsum  = (float*)alloc(2 * 256 * 4);
    float* bnss   = (float*)alloc(2 * 256 * 4);
    int*   gcounts= (int*)alloc(NGRAPH * 4);
    int*   goffs  = (int*)alloc((NGRAPH + 1) * 4);
    int*   gincl  = (int*)alloc(NGRAPH * 4);
    int*   gbsum  = (int*)alloc(1024);
    int*   gcur   = (int*)alloc(NGRAPH * 4);

    float* pool = (float*)d_out;                    // [128, 576]
    float* xs   = pool + (size_t)NGRAPH * XS_COLS;  // [50000, 576]

    // ---- edge bucketing by dst ----
    hipMemsetAsync(counts, 0, (size_t)N_NODES * 4, stream);
    hipMemsetAsync(gcounts, 0, NGRAPH * 4, stream);
    edge_count<<<ceil_div(E_TOT, 256), 256, 0, stream>>>(ei, counts);
    const int NSB = ceil_div(N_NODES, 256);  // 196
    scan_block<<<NSB, 256, 0, stream>>>(counts, N_NODES, incl, bsums);
    scan_sums<<<1, 256, 0, stream>>>(bsums, NSB);
    scan_final<<<NSB, 256, 0, stream>>>(incl, counts, bsums, N_NODES, offs, cursor);
    edge_scatter<<<ceil_div(E_TOT, 256), 256, 0, stream>>>(ei, cursor, ssrc);
    // ---- graph row ranges ----
    batch_count<<<ceil_div(N_NODES, 256), 256, 0, stream>>>(batch, gcounts);
    scan_block<<<1, 256, 0, stream>>>(gcounts, NGRAPH, gincl, gbsum);
    scan_sums<<<1, 256, 0, stream>>>(gbsum, 1);
    scan_final<<<1, 256, 0, stream>>>(gincl, gcounts, gbsum, NGRAPH, goffs, gcur);

    const int NW = ceil_div(N_NODES, 4);  // 12500 blocks of 4 waves

    // ---------------- layer 0: 128 -> 4x64 concat (256) ----------------
    {
        dim3 grid(ceil_div(N_NODES, 128), 256 / 64);
        gemm_f32<128, 64, 16, 8, 4><<<grid, 256, 0, stream>>>(x, 128, W[0], 256, h, 256, N_NODES, 128);
        attn_coef<4, 64><<<NW, 256, 0, stream>>>(h, asrc[0], adst[0], a_s, a_d);
        gat_aggregate<4, 64><<<NW, 256, 0, stream>>>(offs, ssrc, a_s, a_d, h, bia[0], xs + 0, XS_COLS);
        hipMemsetAsync(bnsum, 0, 2 * 256 * 4, stream);
        bn_stats<256><<<256, 256, 0, stream>>>(xs + 0, XS_COLS, bnsum);
        bn_finalize<256><<<1, 256, 0, stream>>>(bnsum, gam[0], bet[0], bnss);
        bn_apply<256><<<ceil_div(N_NODES * 256, 256), 256, 0, stream>>>(xs + 0, XS_COLS, bnss);
    }
    // ---------------- layer 1: 256 -> 4x64 concat (256) ----------------
    {
        dim3 grid(ceil_div(N_NODES, 128), 256 / 64);
        gemm_f32<128, 64, 16, 8, 4><<<grid, 256, 0, stream>>>(xs + 0, XS_COLS, W[1], 256, h, 256, N_NODES, 256);
        attn_coef<4, 64><<<NW, 256, 0, stream>>>(h, asrc[1], adst[1], a_s, a_d);
        gat_aggregate<4, 64><<<NW, 256, 0, stream>>>(offs, ssrc, a_s, a_d, h, bia[1], xs + 256, XS_COLS);
        hipMemsetAsync(bnsum, 0, 2 * 256 * 4, stream);
        bn_stats<256><<<256, 256, 0, stream>>>(xs + 256, XS_COLS, bnsum);
        bn_finalize<256><<<1, 256, 0, stream>>>(bnsum, gam[1], bet[1], bnss);
        bn_apply<256><<<ceil_div(N_NODES * 256, 256), 256, 0, stream>>>(xs + 256, XS_COLS, bnss);
    }
    // ---------------- layer 2: 256 -> 1x64 (mean over 1 head) ----------------
    {
        dim3 grid(ceil_div(N_NODES, 128), 1);
        gemm_f32<128, 64, 16, 8, 4><<<grid, 256, 0, stream>>>(xs + 256, XS_COLS, W[2], 64, h, 64, N_NODES, 256);
        attn_coef<1, 64><<<NW, 256, 0, stream>>>(h, asrc[2], adst[2], a_s, a_d);
        gat_aggregate<1, 64><<<NW, 256, 0, stream>>>(offs, ssrc, a_s, a_d, h, bia[2], xs + 512, XS_COLS);
        hipMemsetAsync(bnsum, 0, 2 * 64 * 4, stream);
        bn_stats<64><<<256, 256, 0, stream>>>(xs + 512, XS_COLS, bnsum);
        bn_finalize<64><<<1, 64, 0, stream>>>(bnsum, gam[2], bet[2], bnss);
        bn_apply<64><<<ceil_div(N_NODES * 64, 256), 256, 0, stream>>>(xs + 512, XS_COLS, bnss);
    }
    // ---------------- pooling ----------------
    pool_kernel<<<NGRAPH, XS_COLS, 0, stream>>>(xs, goffs, pool);
}

// Round 2
// 840.392 us; speedup vs baseline: 1.3919x; 1.3919x over previous
//
#include <hip/hip_runtime.h>
#include <math.h>

#define N_NODES 50000
#define NUM_E   800000
#define E_TOT   (NUM_E + N_NODES)   // 850000 (self loops appended)
#define M_PAD   50048               // N_NODES rounded up to 128
#define NGRAPH  128
#define XS_COLS 576
#define EPS_BN  1e-5f

static inline int ceil_div(int a, int b) { return (a + b - 1) / b; }

typedef __attribute__((ext_vector_type(8))) short short8;
typedef __attribute__((ext_vector_type(4))) float f32x4;

__device__ __forceinline__ float bf2f(ushort u) {
    union { unsigned int i; float f; } v; v.i = ((unsigned int)u) << 16; return v.f;
}
__device__ __forceinline__ ushort f2bf(float f) {
    union { float f; unsigned int i; } v; v.f = f;
    unsigned int r = v.i + 0x7FFF + ((v.i >> 16) & 1);
    return (ushort)(r >> 16);
}
__device__ __forceinline__ float sel4(float4 a, int hd) {
    float r = a.x;
    r = (hd == 1) ? a.y : r;
    r = (hd == 2) ? a.z : r;
    r = (hd == 3) ? a.w : r;
    return r;
}

// ---------------- converts ----------------
__global__ __launch_bounds__(256) void f32_to_bf16_vec(const float* __restrict__ in,
                                                       ushort* __restrict__ out, int n4)
{
    int i = blockIdx.x * 256 + threadIdx.x;
    if (i >= n4) return;
    float4 v = reinterpret_cast<const float4*>(in)[i];
    ushort4 o;
    o.x = f2bf(v.x); o.y = f2bf(v.y); o.z = f2bf(v.z); o.w = f2bf(v.w);
    reinterpret_cast<ushort4*>(out)[i] = o;
}

// W fp32 [K][N] -> Wt bf16 [N][K]
__global__ __launch_bounds__(256) void w_transpose(const float* __restrict__ W,
                                                   ushort* __restrict__ Wt, int K, int N)
{
    int i = blockIdx.x * 256 + threadIdx.x;
    if (i >= N * K) return;
    int n = i / K, k = i - n * K;
    Wt[i] = f2bf(W[(size_t)k * N + n]);
}

// ---------------- bf16 MFMA GEMM:  C[M x Nc](bf16) = A[M x K](bf16) @ Bt^T ----------------
// A row-major [M_PAD][K]; Bt row-major [Nc][K] (i.e. W transposed); C bf16 [M][ldc]
template<int BM, int BN, int BK>
__global__ __launch_bounds__(256)
void gemm_bf16(const ushort* __restrict__ A, int lda,
               const ushort* __restrict__ Bt, int ldb,
               ushort* __restrict__ C, int ldc, int M, int K)
{
    static_assert(BM == 128 && BN == 64 && BK == 64, "tuned variant");
    __shared__ __align__(16) ushort As[BM][BK + 8];
    __shared__ __align__(16) ushort Bs[BN][BK + 8];
    const int tid = threadIdx.x;
    const int lane = tid & 63;
    const int w = tid >> 6;            // 4 waves: rows w*32..w*32+31
    const int m0 = blockIdx.x * BM;
    const int n0 = blockIdx.y * BN;

    f32x4 acc[2][4] = {};

    for (int k0 = 0; k0 < K; k0 += BK) {
        // stage A tile: 128 x 64 bf16 (1024 chunks of 8)
#pragma unroll
        for (int j = 0; j < 4; ++j) {
            int c = tid + j * 256;
            int r = c >> 3, cc = (c & 7) * 8;
            short8 v = *reinterpret_cast<const short8*>(A + (size_t)(m0 + r) * lda + k0 + cc);
            *reinterpret_cast<short8*>(&As[r][cc]) = v;
        }
        // stage B tile: 64 x 64 bf16 (512 chunks of 8)
#pragma unroll
        for (int j = 0; j < 2; ++j) {
            int c = tid + j * 256;
            int r = c >> 3, cc = (c & 7) * 8;
            short8 v = *reinterpret_cast<const short8*>(Bt + (size_t)(n0 + r) * ldb + k0 + cc);
            *reinterpret_cast<short8*>(&Bs[r][cc]) = v;
        }
        __syncthreads();
#pragma unroll
        for (int kc = 0; kc < BK; kc += 32) {
            short8 a[2], b[4];
#pragma unroll
            for (int mf = 0; mf < 2; ++mf)
                a[mf] = *reinterpret_cast<const short8*>(&As[w * 32 + mf * 16 + (lane & 15)][kc + (lane >> 4) * 8]);
#pragma unroll
            for (int nf = 0; nf < 4; ++nf)
                b[nf] = *reinterpret_cast<const short8*>(&Bs[nf * 16 + (lane & 15)][kc + (lane >> 4) * 8]);
#pragma unroll
            for (int mf = 0; mf < 2; ++mf)
#pragma unroll
                for (int nf = 0; nf < 4; ++nf)
                    acc[mf][nf] = __builtin_amdgcn_mfma_f32_16x16x32_bf16(a[mf], b[nf], acc[mf][nf], 0, 0, 0);
        }
        __syncthreads();
    }
    // C/D layout: col = lane&15, row = (lane>>4)*4 + reg
#pragma unroll
    for (int mf = 0; mf < 2; ++mf) {
        int mbase = m0 + w * 32 + mf * 16 + (lane >> 4) * 4;
#pragma unroll
        for (int r = 0; r < 4; ++r) {
            int m = mbase + r;
            if (m < M) {
#pragma unroll
                for (int nf = 0; nf < 4; ++nf)
                    C[(size_t)m * ldc + n0 + nf * 16 + (lane & 15)] = f2bf(acc[mf][nf][r]);
            }
        }
    }
}

// ---------------- a_s / a_d from bf16 h ----------------
template<int H, int C>
__global__ __launch_bounds__(256)
void attn_coef(const ushort* __restrict__ hf, const float* __restrict__ asrc,
               const float* __restrict__ adst,
               float* __restrict__ a_s, float* __restrict__ a_d)
{
    constexpr int V = (H * C) / 64;
    const int lane = threadIdx.x & 63;
    const int n = blockIdx.x * 4 + (threadIdx.x >> 6);
    if (n >= N_NODES) return;
    const ushort* hp = hf + (size_t)n * (H * C) + lane * V;
    float ss = 0.f, dd = 0.f;
    if constexpr (V == 4) {
        ushort4 hv = *reinterpret_cast<const ushort4*>(hp);
        float h0 = bf2f(hv.x), h1 = bf2f(hv.y), h2 = bf2f(hv.z), h3 = bf2f(hv.w);
        float4 sv = *reinterpret_cast<const float4*>(asrc + lane * 4);
        float4 dv = *reinterpret_cast<const float4*>(adst + lane * 4);
        ss = h0 * sv.x + h1 * sv.y + h2 * sv.z + h3 * sv.w;
        dd = h0 * dv.x + h1 * dv.y + h2 * dv.z + h3 * dv.w;
    } else {
        float hv = bf2f(hp[0]);
        ss = hv * asrc[lane];
        dd = hv * adst[lane];
    }
    constexpr int GS = C / V;   // lanes per head
#pragma unroll
    for (int o = 1; o < GS; o <<= 1) {
        ss += __shfl_xor(ss, o, 64);
        dd += __shfl_xor(dd, o, 64);
    }
    if ((lane & (GS - 1)) == 0) {
        int hd = lane / GS;
        a_s[(size_t)n * H + hd] = ss;
        a_d[(size_t)n * H + hd] = dd;
    }
}

// ---------------- per-dst edge softmax -> alpha buffer ----------------
template<int H>
__global__ __launch_bounds__(256)
void edge_softmax(const int* __restrict__ offs, const int* __restrict__ ssrc,
                  const float* __restrict__ a_s, const float* __restrict__ a_d,
                  float* __restrict__ albuf)
{
    const int lane = threadIdx.x & 63;
    const int dst = blockIdx.x * 4 + (threadIdx.x >> 6);
    if (dst >= N_NODES) return;
    const int e0 = offs[dst], e1 = offs[dst + 1];

    float ad[H];
    if constexpr (H == 4) {
        float4 v = *reinterpret_cast<const float4*>(a_d + (size_t)dst * 4);
        ad[0] = v.x; ad[1] = v.y; ad[2] = v.z; ad[3] = v.w;
    } else ad[0] = a_d[dst];

    float mx[H];
#pragma unroll
    for (int t = 0; t < H; ++t) mx[t] = -INFINITY;
    for (int e = e0 + lane; e < e1; e += 64) {
        int s = ssrc[e];
        float asv[H];
        if constexpr (H == 4) {
            float4 v = *reinterpret_cast<const float4*>(a_s + (size_t)s * 4);
            asv[0] = v.x; asv[1] = v.y; asv[2] = v.z; asv[3] = v.w;
        } else asv[0] = a_s[s];
#pragma unroll
        for (int t = 0; t < H; ++t) {
            float l = asv[t] + ad[t];
            l = l > 0.f ? l : 0.2f * l;
            mx[t] = fmaxf(mx[t], l);
        }
    }
#pragma unroll
    for (int t = 0; t < H; ++t)
#pragma unroll
        for (int o = 1; o < 64; o <<= 1) mx[t] = fmaxf(mx[t], __shfl_xor(mx[t], o, 64));

    float sm[H];
#pragma unroll
    for (int t = 0; t < H; ++t) sm[t] = 0.f;
    for (int e = e0 + lane; e < e1; e += 64) {
        int s = ssrc[e];
        float asv[H];
        if constexpr (H == 4) {
            float4 v = *reinterpret_cast<const float4*>(a_s + (size_t)s * 4);
            asv[0] = v.x; asv[1] = v.y; asv[2] = v.z; asv[3] = v.w;
        } else asv[0] = a_s[s];
#pragma unroll
        for (int t = 0; t < H; ++t) {
            float l = asv[t] + ad[t];
            l = l > 0.f ? l : 0.2f * l;
            sm[t] += expf(l - mx[t]);
        }
    }
#pragma unroll
    for (int t = 0; t < H; ++t)
#pragma unroll
        for (int o = 1; o < 64; o <<= 1) sm[t] += __shfl_xor(sm[t], o, 64);

    float inv[H];
#pragma unroll
    for (int t = 0; t < H; ++t) inv[t] = 1.f / (sm[t] + 1e-16f);

    // write alpha per edge (coalesced: consecutive lanes -> consecutive e)
    for (int e = e0 + lane; e < e1; e += 64) {
        int s = ssrc[e];
        if constexpr (H == 4) {
            float4 v = *reinterpret_cast<const float4*>(a_s + (size_t)s * 4);
            float asv[4] = {v.x, v.y, v.z, v.w};
            float4 al;
            float l0 = asv[0] + ad[0]; l0 = l0 > 0.f ? l0 : 0.2f * l0;
            float l1 = asv[1] + ad[1]; l1 = l1 > 0.f ? l1 : 0.2f * l1;
            float l2 = asv[2] + ad[2]; l2 = l2 > 0.f ? l2 : 0.2f * l2;
            float l3 = asv[3] + ad[3]; l3 = l3 > 0.f ? l3 : 0.2f * l3;
            al.x = expf(l0 - mx[0]) * inv[0];
            al.y = expf(l1 - mx[1]) * inv[1];
            al.z = expf(l2 - mx[2]) * inv[2];
            al.w = expf(l3 - mx[3]) * inv[3];
            *reinterpret_cast<float4*>(albuf + (size_t)e * 4) = al;
        } else {
            float l = a_s[s] + ad[0];
            l = l > 0.f ? l : 0.2f * l;
            albuf[e] = expf(l - mx[0]) * inv[0];
        }
    }
}

// ---------------- weighted gather:  out[dst] = sum_e alpha[e] * h[src[e]] ----------------
template<int H, int C>
__global__ __launch_bounds__(256)
void gat_gather(const int* __restrict__ offs, const int* __restrict__ ssrc,
                const float* __restrict__ albuf, const ushort* __restrict__ hf,
                const float* __restrict__ bias, float* __restrict__ out, int ldo)
{
    constexpr int V = (H * C) / 64;   // 4 or 1
    const int lane = threadIdx.x & 63;
    const int dst = blockIdx.x * 4 + (threadIdx.x >> 6);
    if (dst >= N_NODES) return;
    const int e0 = offs[dst], e1 = offs[dst + 1];
    const int hd = (lane * V) / C;

    float acc[V];
#pragma unroll
    for (int k = 0; k < V; ++k) acc[k] = 0.f;

    int e = e0;
    for (; e + 1 < e1; e += 2) {
        int s0 = ssrc[e], s1 = ssrc[e + 1];
        float al0, al1;
        if constexpr (H == 4) {
            float4 A0 = *reinterpret_cast<const float4*>(albuf + (size_t)e * 4);
            float4 A1 = *reinterpret_cast<const float4*>(albuf + (size_t)(e + 1) * 4);
            al0 = sel4(A0, hd); al1 = sel4(A1, hd);
        } else { al0 = albuf[e]; al1 = albuf[e + 1]; }
        if constexpr (V == 4) {
            ushort4 h0 = *reinterpret_cast<const ushort4*>(hf + (size_t)s0 * (H * C) + lane * 4);
            ushort4 h1 = *reinterpret_cast<const ushort4*>(hf + (size_t)s1 * (H * C) + lane * 4);
            acc[0] = fmaf(al0, bf2f(h0.x), acc[0]);
            acc[1] = fmaf(al0, bf2f(h0.y), acc[1]);
            acc[2] = fmaf(al0, bf2f(h0.z), acc[2]);
            acc[3] = fmaf(al0, bf2f(h0.w), acc[3]);
            acc[0] = fmaf(al1, bf2f(h1.x), acc[0]);
            acc[1] = fmaf(al1, bf2f(h1.y), acc[1]);
            acc[2] = fmaf(al1, bf2f(h1.z), acc[2]);
            acc[3] = fmaf(al1, bf2f(h1.w), acc[3]);
        } else {
            acc[0] = fmaf(al0, bf2f(hf[(size_t)s0 * (H * C) + lane]), acc[0]);
            acc[0] = fmaf(al1, bf2f(hf[(size_t)s1 * (H * C) + lane]), acc[0]);
        }
    }
    if (e < e1) {
        int s0 = ssrc[e];
        float al0;
        if constexpr (H == 4) {
            float4 A0 = *reinterpret_cast<const float4*>(albuf + (size_t)e * 4);
            al0 = sel4(A0, hd);
        } else al0 = albuf[e];
        if constexpr (V == 4) {
            ushort4 h0 = *reinterpret_cast<const ushort4*>(hf + (size_t)s0 * (H * C) + lane * 4);
            acc[0] = fmaf(al0, bf2f(h0.x), acc[0]);
            acc[1] = fmaf(al0, bf2f(h0.y), acc[1]);
            acc[2] = fmaf(al0, bf2f(h0.z), acc[2]);
            acc[3] = fmaf(al0, bf2f(h0.w), acc[3]);
        } else {
            acc[0] = fmaf(al0, bf2f(hf[(size_t)s0 * (H * C) + lane]), acc[0]);
        }
    }
    // epilogue: + bias, ELU, store
    if constexpr (V == 4) {
        float t0 = acc[0] + bias[lane * 4 + 0];
        float t1 = acc[1] + bias[lane * 4 + 1];
        float t2 = acc[2] + bias[lane * 4 + 2];
        float t3 = acc[3] + bias[lane * 4 + 3];
        float4 v;
        v.x = t0 > 0.f ? t0 : (expf(t0) - 1.f);
        v.y = t1 > 0.f ? t1 : (expf(t1) - 1.f);
        v.z = t2 > 0.f ? t2 : (expf(t2) - 1.f);
        v.w = t3 > 0.f ? t3 : (expf(t3) - 1.f);
        *reinterpret_cast<float4*>(&out[(size_t)dst * ldo + lane * 4]) = v;
    } else {
        float t0 = acc[0] + bias[lane];
        out[(size_t)dst * ldo + lane] = t0 > 0.f ? t0 : (expf(t0) - 1.f);
    }
}

// ---------------- edge bucketing ----------------
__global__ void edge_count(const int* __restrict__ ei, int* __restrict__ counts)
{
    int i = blockIdx.x * blockDim.x + threadIdx.x;
    if (i >= E_TOT) return;
    int dst = (i < NUM_E) ? ei[NUM_E + i] : (i - NUM_E);
    atomicAdd(&counts[dst], 1);
}

__global__ void edge_scatter(const int* __restrict__ ei, int* __restrict__ cursor,
                             int* __restrict__ ssrc)
{
    int i = blockIdx.x * blockDim.x + threadIdx.x;
    if (i >= E_TOT) return;
    int src, dst;
    if (i < NUM_E) { src = ei[i]; dst = ei[NUM_E + i]; }
    else           { src = dst = i - NUM_E; }
    int pos = atomicAdd(&cursor[dst], 1);
    ssrc[pos] = src;
}

// ---------------- generic scan (blocks of 256) ----------------
__global__ void scan_block(const int* __restrict__ in, int n,
                           int* __restrict__ incl, int* __restrict__ bsum)
{
    __shared__ int sh[256];
    int tid = threadIdx.x;
    int i = blockIdx.x * 256 + tid;
    int v = (i < n) ? in[i] : 0;
    sh[tid] = v;
    __syncthreads();
    for (int o = 1; o < 256; o <<= 1) {
        int t = (tid >= o) ? sh[tid - o] : 0;
        __syncthreads();
        sh[tid] += t;
        __syncthreads();
    }
    if (i < n) incl[i] = sh[tid];
    if (tid == 255) bsum[blockIdx.x] = sh[255];
}

__global__ void scan_sums(int* __restrict__ bsum, int nb)
{
    __shared__ int sh[256];
    int tid = threadIdx.x;
    int v = (tid < nb) ? bsum[tid] : 0;
    sh[tid] = v;
    __syncthreads();
    for (int o = 1; o < 256; o <<= 1) {
        int t = (tid >= o) ? sh[tid - o] : 0;
        __syncthreads();
        sh[tid] += t;
        __syncthreads();
    }
    if (tid < nb) bsum[tid] = sh[tid] - v;
}

__global__ void scan_final(const int* __restrict__ incl, const int* __restrict__ in,
                           const int* __restrict__ bsum, int n,
                           int* __restrict__ offs, int* __restrict__ cursor)
{
    int i = blockIdx.x * 256 + threadIdx.x;
    if (i >= n) return;
    int excl = incl[i] - in[i] + bsum[i / 256];
    offs[i] = excl;
    cursor[i] = excl;
    if (i == n - 1) offs[n] = incl[i] + bsum[i / 256];
}

__global__ void batch_count(const int* __restrict__ batch, int* __restrict__ gcounts)
{
    int i = blockIdx.x * blockDim.x + threadIdx.x;
    if (i < N_NODES) atomicAdd(&gcounts[batch[i]], 1);
}

// ---------------- BatchNorm ----------------
template<int OF>
__global__ __launch_bounds__(256)
void bn_stats(const float* __restrict__ x, int ldx, float* __restrict__ sums)
{
    constexpr int RP = 256 / OF;
    const int tid = threadIdx.x;
    const int col = tid % OF;
    const int rsub = tid / OF;
    float s = 0.f, s2 = 0.f;
    for (int r = blockIdx.x * RP + rsub; r < N_NODES; r += gridDim.x * RP) {
        float v = x[(size_t)r * ldx + col];
        s += v;
        s2 = fmaf(v, v, s2);
    }
    if constexpr (RP > 1) {
        __shared__ float sh[2][256];
        sh[0][tid] = s; sh[1][tid] = s2;
        __syncthreads();
        if (rsub == 0) {
#pragma unroll
            for (int j = 1; j < RP; ++j) { s += sh[0][col + j * OF]; s2 += sh[1][col + j * OF]; }
        }
    }
    if (rsub == 0) {
        atomicAdd(&sums[col], s);
        atomicAdd(&sums[OF + col], s2);
    }
}

template<int OF>
__global__ void bn_finalize(const float* __restrict__ sums, const float* __restrict__ gamma,
                            const float* __restrict__ beta, float* __restrict__ ss)
{
    int c = threadIdx.x;
    if (c >= OF) return;
    float mean = sums[c] / (float)N_NODES;
    float var = sums[OF + c] / (float)N_NODES - mean * mean;
    float inv = rsqrtf(var + EPS_BN);
    float sc = inv * gamma[c];
    ss[c] = sc;
    ss[OF + c] = beta[c] - mean * sc;
}

// BN apply in-place on xs slice; optionally also emit packed bf16 copy (next GEMM input)
template<int OF, bool WB>
__global__ __launch_bounds__(256)
void bn_apply(float* __restrict__ x, int ldx, const float* __restrict__ ss,
              ushort* __restrict__ xb, int ldxb)
{
    int i = blockIdx.x * 256 + threadIdx.x;
    if (i >= N_NODES * OF) return;
    int r = i / OF, c = i - r * OF;
    float v = fmaf(x[(size_t)r * ldx + c], ss[c], ss[OF + c]);
    x[(size_t)r * ldx + c] = v;
    if constexpr (WB) xb[(size_t)r * ldxb + c] = f2bf(v);
}

// ---------------- pooling: 4 partial blocks per graph + atomics ----------------
__global__ void pool_kernel(const float* __restrict__ xs, const int* __restrict__ goffs,
                            float* __restrict__ pool)
{
    int g = blockIdx.x >> 2, part = blockIdx.x & 3;
    int c = threadIdx.x;  // 576
    int r0 = goffs[g], r1 = goffs[g + 1];
    int cnt = r1 - r0;
    int p0 = r0 + (cnt * part) / 4;
    int p1 = r0 + (cnt * (part + 1)) / 4;
    float s = 0.f;
    for (int r = p0; r < p1; ++r) s += xs[(size_t)r * XS_COLS + c];
    if (p1 > p0) atomicAdd(&pool[(size_t)g * XS_COLS + c], s);
}

extern "C" void kernel_launch(void* const* d_in, const int* in_sizes, int n_in,
                              void* d_out, int out_size, void* d_ws, size_t ws_size,
                              hipStream_t stream)
{
    const float* x     = (const float*)d_in[0];
    const int*   ei    = (const int*)d_in[1];
    const int*   batch = (const int*)d_in[2];
    const float* W[3]    = {(const float*)d_in[3],  (const float*)d_in[9],  (const float*)d_in[15]};
    const float* asrc[3] = {(const float*)d_in[4],  (const float*)d_in[10], (const float*)d_in[16]};
    const float* adst[3] = {(const float*)d_in[5],  (const float*)d_in[11], (const float*)d_in[17]};
    const float* bia[3]  = {(const float*)d_in[6],  (const float*)d_in[12], (const float*)d_in[18]};
    const float* gam[3]  = {(const float*)d_in[7],  (const float*)d_in[13], (const float*)d_in[19]};
    const float* bet[3]  = {(const float*)d_in[8],  (const float*)d_in[14], (const float*)d_in[20]};

    char* wp = (char*)d_ws;
    auto alloc = [&](size_t bytes) -> void* {
        void* p = (void*)wp;
        wp += (bytes + 255) & ~(size_t)255;
        return p;
    };
    ushort* hbf   = (ushort*)alloc((size_t)N_NODES * 256 * 2);   // bf16 h (max 256 cols)
    ushort* Abf0  = (ushort*)alloc((size_t)M_PAD * 128 * 2);     // layer0 GEMM input
    ushort* AbfA  = (ushort*)alloc((size_t)M_PAD * 256 * 2);     // layer1/2 GEMM input
    float*  albuf = (float*)alloc((size_t)E_TOT * 4 * 4);        // per-edge alpha (max H=4)
    float*  a_s   = (float*)alloc((size_t)N_NODES * 4 * 4);
    float*  a_d   = (float*)alloc((size_t)N_NODES * 4 * 4);
    int*    counts = (int*)alloc((size_t)N_NODES * 4);
    int*    offs   = (int*)alloc((size_t)(N_NODES + 1) * 4);
    int*    cursor = (int*)alloc((size_t)N_NODES * 4);
    int*    incl   = (int*)alloc((size_t)N_NODES * 4);
    int*    bsums  = (int*)alloc(1024);
    int*    ssrc   = (int*)alloc((size_t)E_TOT * 4);
    float*  bnsum  = (float*)alloc(2 * 256 * 4);
    float*  bnss   = (float*)alloc(2 * 256 * 4);
    int*    gcounts= (int*)alloc(NGRAPH * 4);
    int*    goffs  = (int*)alloc((NGRAPH + 1) * 4);
    int*    gincl  = (int*)alloc(NGRAPH * 4);
    int*    gbsum  = (int*)alloc(1024);
    int*    gcur   = (int*)alloc(NGRAPH * 4);
    ushort* Wt0    = (ushort*)alloc(256 * 128 * 2);
    ushort* Wt1    = (ushort*)alloc(256 * 256 * 2);
    ushort* Wt2    = (ushort*)alloc(64 * 256 * 2);

    float* pool = (float*)d_out;                    // [128, 576]
    float* xs   = pool + (size_t)NGRAPH * XS_COLS;  // [50000, 576]

    // ---- setup: edge bucketing by dst, graph offsets, weight transposes, x->bf16 ----
    hipMemsetAsync(counts, 0, (size_t)N_NODES * 4, stream);
    hipMemsetAsync(gcounts, 0, NGRAPH * 4, stream);
    edge_count<<<ceil_div(E_TOT, 256), 256, 0, stream>>>(ei, counts);
    const int NSB = ceil_div(N_NODES, 256);
    scan_block<<<NSB, 256, 0, stream>>>(counts, N_NODES, incl, bsums);
    scan_sums<<<1, 256, 0, stream>>>(bsums, NSB);
    scan_final<<<NSB, 256, 0, stream>>>(incl, counts, bsums, N_NODES, offs, cursor);
    edge_scatter<<<ceil_div(E_TOT, 256), 256, 0, stream>>>(ei, cursor, ssrc);
    batch_count<<<ceil_div(N_NODES, 256), 256, 0, stream>>>(batch, gcounts);
    scan_block<<<1, 256, 0, stream>>>(gcounts, NGRAPH, gincl, gbsum);
    scan_sums<<<1, 256, 0, stream>>>(gbsum, 1);
    scan_final<<<1, 256, 0, stream>>>(gincl, gcounts, gbsum, NGRAPH, goffs, gcur);

    w_transpose<<<ceil_div(256 * 128, 256), 256, 0, stream>>>(W[0], Wt0, 128, 256);
    w_transpose<<<ceil_div(256 * 256, 256), 256, 0, stream>>>(W[1], Wt1, 256, 256);
    w_transpose<<<ceil_div(64 * 256, 256), 256, 0, stream>>>(W[2], Wt2, 256, 64);
    f32_to_bf16_vec<<<ceil_div(N_NODES * 128 / 4, 256), 256, 0, stream>>>(x, Abf0, N_NODES * 128 / 4);

    const int NW = ceil_div(N_NODES, 4);     // per-dst-wave kernels, 4 waves/block
    const int NMB = ceil_div(N_NODES, 128);  // 391 GEMM row-blocks

    // ---------------- layer 0: 128 -> 4x64 concat (256) ----------------
    {
        dim3 grid(NMB, 4);
        gemm_bf16<128, 64, 64><<<grid, 256, 0, stream>>>(Abf0, 128, Wt0, 128, hbf, 256, N_NODES, 128);
        attn_coef<4, 64><<<NW, 256, 0, stream>>>(hbf, asrc[0], adst[0], a_s, a_d);
        edge_softmax<4><<<NW, 256, 0, stream>>>(offs, ssrc, a_s, a_d, albuf);
        gat_gather<4, 64><<<NW, 256, 0, stream>>>(offs, ssrc, albuf, hbf, bia[0], xs + 0, XS_COLS);
        hipMemsetAsync(bnsum, 0, 2 * 256 * 4, stream);
        bn_stats<256><<<256, 256, 0, stream>>>(xs + 0, XS_COLS, bnsum);
        bn_finalize<256><<<1, 256, 0, stream>>>(bnsum, gam[0], bet[0], bnss);
        bn_apply<256, true><<<ceil_div(N_NODES * 256, 256), 256, 0, stream>>>(xs + 0, XS_COLS, bnss, AbfA, 256);
    }
    // ---------------- layer 1: 256 -> 4x64 concat (256) ----------------
    {
        dim3 grid(NMB, 4);
        gemm_bf16<128, 64, 64><<<grid, 256, 0, stream>>>(AbfA, 256, Wt1, 256, hbf, 256, N_NODES, 256);
        attn_coef<4, 64><<<NW, 256, 0, stream>>>(hbf, asrc[1], adst[1], a_s, a_d);
        edge_softmax<4><<<NW, 256, 0, stream>>>(offs, ssrc, a_s, a_d, albuf);
        gat_gather<4, 64><<<NW, 256, 0, stream>>>(offs, ssrc, albuf, hbf, bia[1], xs + 256, XS_COLS);
        hipMemsetAsync(bnsum, 0, 2 * 256 * 4, stream);
        bn_stats<256><<<256, 256, 0, stream>>>(xs + 256, XS_COLS, bnsum);
        bn_finalize<256><<<1, 256, 0, stream>>>(bnsum, gam[1], bet[1], bnss);
        bn_apply<256, true><<<ceil_div(N_NODES * 256, 256), 256, 0, stream>>>(xs + 256, XS_COLS, bnss, AbfA, 256);
    }
    // ---------------- layer 2: 256 -> 1x64 ----------------
    {
        dim3 grid(NMB, 1);
        gemm_bf16<128, 64, 64><<<grid, 256, 0, stream>>>(AbfA, 256, Wt2, 256, hbf, 64, N_NODES, 256);
        attn_coef<1, 64><<<NW, 256, 0, stream>>>(hbf, asrc[2], adst[2], a_s, a_d);
        edge_softmax<1><<<NW, 256, 0, stream>>>(offs, ssrc, a_s, a_d, albuf);
        gat_gather<1, 64><<<NW, 256, 0, stream>>>(offs, ssrc, albuf, hbf, bia[2], xs + 512, XS_COLS);
        hipMemsetAsync(bnsum, 0, 2 * 64 * 4, stream);
        bn_stats<64><<<256, 256, 0, stream>>>(xs + 512, XS_COLS, bnsum);
        bn_finalize<64><<<1, 64, 0, stream>>>(bnsum, gam[2], bet[2], bnss);
        bn_apply<64, false><<<ceil_div(N_NODES * 64, 256), 256, 0, stream>>>(xs + 512, XS_COLS, bnss, nullptr, 0);
    }
    // ---------------- pooling ----------------
    hipMemsetAsync(pool, 0, (size_t)NGRAPH * XS_COLS * 4, stream);
    pool_kernel<<<NGRAPH * 4, XS_COLS, 0, stream>>>(xs, goffs, pool);
}

// Round 3
// 714.689 us; speedup vs baseline: 1.6367x; 1.1759x over previous
//
#include <hip/hip_runtime.h>
#include <math.h>

#define N_NODES 50000
#define NUM_E   800000
#define E_TOT   (NUM_E + N_NODES)   // 850000 (self loops appended)
#define M_PAD   50048               // N_NODES rounded up to 128
#define NGRAPH  128
#define XS_COLS 576
#define EPS_BN  1e-5f

static inline int ceil_div(int a, int b) { return (a + b - 1) / b; }

typedef __attribute__((ext_vector_type(8))) short short8;
typedef __attribute__((ext_vector_type(4))) float f32x4;

__device__ __forceinline__ float bf2f(ushort u) {
    union { unsigned int i; float f; } v; v.i = ((unsigned int)u) << 16; return v.f;
}
__device__ __forceinline__ ushort f2bf(float f) {
    union { float f; unsigned int i; } v; v.f = f;
    unsigned int r = v.i + 0x7FFF + ((v.i >> 16) & 1);
    return (ushort)(r >> 16);
}
__device__ __forceinline__ float sel4(float4 a, int hd) {
    float r = a.x;
    r = (hd == 1) ? a.y : r;
    r = (hd == 2) ? a.z : r;
    r = (hd == 3) ? a.w : r;
    return r;
}

// ---------------- converts ----------------
__global__ __launch_bounds__(256) void f32_to_bf16_vec(const float* __restrict__ in,
                                                       ushort* __restrict__ out, int n4)
{
    int i = blockIdx.x * 256 + threadIdx.x;
    if (i >= n4) return;
    float4 v = reinterpret_cast<const float4*>(in)[i];
    ushort4 o;
    o.x = f2bf(v.x); o.y = f2bf(v.y); o.z = f2bf(v.z); o.w = f2bf(v.w);
    reinterpret_cast<ushort4*>(out)[i] = o;
}

// W fp32 [K][N] -> Wt bf16 [N][K]
__global__ __launch_bounds__(256) void w_transpose(const float* __restrict__ W,
                                                   ushort* __restrict__ Wt, int K, int N)
{
    int i = blockIdx.x * 256 + threadIdx.x;
    if (i >= N * K) return;
    int n = i / K, k = i - n * K;
    Wt[i] = f2bf(W[(size_t)k * N + n]);
}

// ---------------- bf16 MFMA GEMM:  C[M x Nc](bf16) = A[M x K](bf16) @ Bt^T ----------------
template<int BM, int BN, int BK>
__global__ __launch_bounds__(256)
void gemm_bf16(const ushort* __restrict__ A, int lda,
               const ushort* __restrict__ Bt, int ldb,
               ushort* __restrict__ C, int ldc, int M, int K)
{
    static_assert(BM == 128 && BN == 64 && BK == 64, "tuned variant");
    __shared__ __align__(16) ushort As[BM][BK + 8];
    __shared__ __align__(16) ushort Bs[BN][BK + 8];
    const int tid = threadIdx.x;
    const int lane = tid & 63;
    const int w = tid >> 6;            // 4 waves: rows w*32..w*32+31
    const int m0 = blockIdx.x * BM;
    const int n0 = blockIdx.y * BN;

    f32x4 acc[2][4] = {};

    for (int k0 = 0; k0 < K; k0 += BK) {
#pragma unroll
        for (int j = 0; j < 4; ++j) {
            int c = tid + j * 256;
            int r = c >> 3, cc = (c & 7) * 8;
            short8 v = *reinterpret_cast<const short8*>(A + (size_t)(m0 + r) * lda + k0 + cc);
            *reinterpret_cast<short8*>(&As[r][cc]) = v;
        }
#pragma unroll
        for (int j = 0; j < 2; ++j) {
            int c = tid + j * 256;
            int r = c >> 3, cc = (c & 7) * 8;
            short8 v = *reinterpret_cast<const short8*>(Bt + (size_t)(n0 + r) * ldb + k0 + cc);
            *reinterpret_cast<short8*>(&Bs[r][cc]) = v;
        }
        __syncthreads();
#pragma unroll
        for (int kc = 0; kc < BK; kc += 32) {
            short8 a[2], b[4];
#pragma unroll
            for (int mf = 0; mf < 2; ++mf)
                a[mf] = *reinterpret_cast<const short8*>(&As[w * 32 + mf * 16 + (lane & 15)][kc + (lane >> 4) * 8]);
#pragma unroll
            for (int nf = 0; nf < 4; ++nf)
                b[nf] = *reinterpret_cast<const short8*>(&Bs[nf * 16 + (lane & 15)][kc + (lane >> 4) * 8]);
#pragma unroll
            for (int mf = 0; mf < 2; ++mf)
#pragma unroll
                for (int nf = 0; nf < 4; ++nf)
                    acc[mf][nf] = __builtin_amdgcn_mfma_f32_16x16x32_bf16(a[mf], b[nf], acc[mf][nf], 0, 0, 0);
        }
        __syncthreads();
    }
#pragma unroll
    for (int mf = 0; mf < 2; ++mf) {
        int mbase = m0 + w * 32 + mf * 16 + (lane >> 4) * 4;
#pragma unroll
        for (int r = 0; r < 4; ++r) {
            int m = mbase + r;
            if (m < M) {
#pragma unroll
                for (int nf = 0; nf < 4; ++nf)
                    C[(size_t)m * ldc + n0 + nf * 16 + (lane & 15)] = f2bf(acc[mf][nf][r]);
            }
        }
    }
}

// ---------------- a_s / a_d from bf16 h ----------------
template<int H, int C>
__global__ __launch_bounds__(256)
void attn_coef(const ushort* __restrict__ hf, const float* __restrict__ asrc,
               const float* __restrict__ adst,
               float* __restrict__ a_s, float* __restrict__ a_d)
{
    constexpr int V = (H * C) / 64;
    const int lane = threadIdx.x & 63;
    const int n = blockIdx.x * 4 + (threadIdx.x >> 6);
    if (n >= N_NODES) return;
    const ushort* hp = hf + (size_t)n * (H * C) + lane * V;
    float ss = 0.f, dd = 0.f;
    if constexpr (V == 4) {
        ushort4 hv = *reinterpret_cast<const ushort4*>(hp);
        float h0 = bf2f(hv.x), h1 = bf2f(hv.y), h2 = bf2f(hv.z), h3 = bf2f(hv.w);
        float4 sv = *reinterpret_cast<const float4*>(asrc + lane * 4);
        float4 dv = *reinterpret_cast<const float4*>(adst + lane * 4);
        ss = h0 * sv.x + h1 * sv.y + h2 * sv.z + h3 * sv.w;
        dd = h0 * dv.x + h1 * dv.y + h2 * dv.z + h3 * dv.w;
    } else {
        float hv = bf2f(hp[0]);
        ss = hv * asrc[lane];
        dd = hv * adst[lane];
    }
    constexpr int GS = C / V;   // lanes per head
#pragma unroll
    for (int o = 1; o < GS; o <<= 1) {
        ss += __shfl_xor(ss, o, 64);
        dd += __shfl_xor(dd, o, 64);
    }
    if ((lane & (GS - 1)) == 0) {
        int hd = lane / GS;
        a_s[(size_t)n * H + hd] = ss;
        a_d[(size_t)n * H + hd] = dd;
    }
}

// ---------------- per-dst edge softmax -> alpha buffer ----------------
template<int H>
__global__ __launch_bounds__(256)
void edge_softmax(const int* __restrict__ offs, const int* __restrict__ ssrc,
                  const float* __restrict__ a_s, const float* __restrict__ a_d,
                  float* __restrict__ albuf)
{
    const int lane = threadIdx.x & 63;
    const int dst = blockIdx.x * 4 + (threadIdx.x >> 6);
    if (dst >= N_NODES) return;
    const int e0 = offs[dst], e1 = offs[dst + 1];

    float ad[H];
    if constexpr (H == 4) {
        float4 v = *reinterpret_cast<const float4*>(a_d + (size_t)dst * 4);
        ad[0] = v.x; ad[1] = v.y; ad[2] = v.z; ad[3] = v.w;
    } else ad[0] = a_d[dst];

    float mx[H];
#pragma unroll
    for (int t = 0; t < H; ++t) mx[t] = -INFINITY;
    for (int e = e0 + lane; e < e1; e += 64) {
        int s = ssrc[e];
        float asv[H];
        if constexpr (H == 4) {
            float4 v = *reinterpret_cast<const float4*>(a_s + (size_t)s * 4);
            asv[0] = v.x; asv[1] = v.y; asv[2] = v.z; asv[3] = v.w;
        } else asv[0] = a_s[s];
#pragma unroll
        for (int t = 0; t < H; ++t) {
            float l = asv[t] + ad[t];
            l = l > 0.f ? l : 0.2f * l;
            mx[t] = fmaxf(mx[t], l);
        }
    }
#pragma unroll
    for (int t = 0; t < H; ++t)
#pragma unroll
        for (int o = 1; o < 64; o <<= 1) mx[t] = fmaxf(mx[t], __shfl_xor(mx[t], o, 64));

    float sm[H];
#pragma unroll
    for (int t = 0; t < H; ++t) sm[t] = 0.f;
    for (int e = e0 + lane; e < e1; e += 64) {
        int s = ssrc[e];
        float asv[H];
        if constexpr (H == 4) {
            float4 v = *reinterpret_cast<const float4*>(a_s + (size_t)s * 4);
            asv[0] = v.x; asv[1] = v.y; asv[2] = v.z; asv[3] = v.w;
        } else asv[0] = a_s[s];
#pragma unroll
        for (int t = 0; t < H; ++t) {
            float l = asv[t] + ad[t];
            l = l > 0.f ? l : 0.2f * l;
            sm[t] += expf(l - mx[t]);
        }
    }
#pragma unroll
    for (int t = 0; t < H; ++t)
#pragma unroll
        for (int o = 1; o < 64; o <<= 1) sm[t] += __shfl_xor(sm[t], o, 64);

    float inv[H];
#pragma unroll
    for (int t = 0; t < H; ++t) inv[t] = 1.f / (sm[t] + 1e-16f);

    for (int e = e0 + lane; e < e1; e += 64) {
        int s = ssrc[e];
        if constexpr (H == 4) {
            float4 v = *reinterpret_cast<const float4*>(a_s + (size_t)s * 4);
            float asv[4] = {v.x, v.y, v.z, v.w};
            float4 al;
            float l0 = asv[0] + ad[0]; l0 = l0 > 0.f ? l0 : 0.2f * l0;
            float l1 = asv[1] + ad[1]; l1 = l1 > 0.f ? l1 : 0.2f * l1;
            float l2 = asv[2] + ad[2]; l2 = l2 > 0.f ? l2 : 0.2f * l2;
            float l3 = asv[3] + ad[3]; l3 = l3 > 0.f ? l3 : 0.2f * l3;
            al.x = expf(l0 - mx[0]) * inv[0];
            al.y = expf(l1 - mx[1]) * inv[1];
            al.z = expf(l2 - mx[2]) * inv[2];
            al.w = expf(l3 - mx[3]) * inv[3];
            *reinterpret_cast<float4*>(albuf + (size_t)e * 4) = al;
        } else {
            float l = a_s[s] + ad[0];
            l = l > 0.f ? l : 0.2f * l;
            albuf[e] = expf(l - mx[0]) * inv[0];
        }
    }
}

// ---------------- weighted gather:  out[dst] = sum_e alpha[e] * h[src[e]] ----------------
template<int H, int C>
__global__ __launch_bounds__(256)
void gat_gather(const int* __restrict__ offs, const int* __restrict__ ssrc,
                const float* __restrict__ albuf, const ushort* __restrict__ hf,
                const float* __restrict__ bias, float* __restrict__ out, int ldo)
{
    constexpr int V = (H * C) / 64;   // 4 or 1
    const int lane = threadIdx.x & 63;
    const int dst = blockIdx.x * 4 + (threadIdx.x >> 6);
    if (dst >= N_NODES) return;
    const int e0 = offs[dst], e1 = offs[dst + 1];
    const int hd = (lane * V) / C;

    float acc[V];
#pragma unroll
    for (int k = 0; k < V; ++k) acc[k] = 0.f;

    int e = e0;
    for (; e + 1 < e1; e += 2) {
        int s0 = ssrc[e], s1 = ssrc[e + 1];
        float al0, al1;
        if constexpr (H == 4) {
            float4 A0 = *reinterpret_cast<const float4*>(albuf + (size_t)e * 4);
            float4 A1 = *reinterpret_cast<const float4*>(albuf + (size_t)(e + 1) * 4);
            al0 = sel4(A0, hd); al1 = sel4(A1, hd);
        } else { al0 = albuf[e]; al1 = albuf[e + 1]; }
        if constexpr (V == 4) {
            ushort4 h0 = *reinterpret_cast<const ushort4*>(hf + (size_t)s0 * (H * C) + lane * 4);
            ushort4 h1 = *reinterpret_cast<const ushort4*>(hf + (size_t)s1 * (H * C) + lane * 4);
            acc[0] = fmaf(al0, bf2f(h0.x), acc[0]);
            acc[1] = fmaf(al0, bf2f(h0.y), acc[1]);
            acc[2] = fmaf(al0, bf2f(h0.z), acc[2]);
            acc[3] = fmaf(al0, bf2f(h0.w), acc[3]);
            acc[0] = fmaf(al1, bf2f(h1.x), acc[0]);
            acc[1] = fmaf(al1, bf2f(h1.y), acc[1]);
            acc[2] = fmaf(al1, bf2f(h1.z), acc[2]);
            acc[3] = fmaf(al1, bf2f(h1.w), acc[3]);
        } else {
            acc[0] = fmaf(al0, bf2f(hf[(size_t)s0 * (H * C) + lane]), acc[0]);
            acc[0] = fmaf(al1, bf2f(hf[(size_t)s1 * (H * C) + lane]), acc[0]);
        }
    }
    if (e < e1) {
        int s0 = ssrc[e];
        float al0;
        if constexpr (H == 4) {
            float4 A0 = *reinterpret_cast<const float4*>(albuf + (size_t)e * 4);
            al0 = sel4(A0, hd);
        } else al0 = albuf[e];
        if constexpr (V == 4) {
            ushort4 h0 = *reinterpret_cast<const ushort4*>(hf + (size_t)s0 * (H * C) + lane * 4);
            acc[0] = fmaf(al0, bf2f(h0.x), acc[0]);
            acc[1] = fmaf(al0, bf2f(h0.y), acc[1]);
            acc[2] = fmaf(al0, bf2f(h0.z), acc[2]);
            acc[3] = fmaf(al0, bf2f(h0.w), acc[3]);
        } else {
            acc[0] = fmaf(al0, bf2f(hf[(size_t)s0 * (H * C) + lane]), acc[0]);
        }
    }
    if constexpr (V == 4) {
        float t0 = acc[0] + bias[lane * 4 + 0];
        float t1 = acc[1] + bias[lane * 4 + 1];
        float t2 = acc[2] + bias[lane * 4 + 2];
        float t3 = acc[3] + bias[lane * 4 + 3];
        float4 v;
        v.x = t0 > 0.f ? t0 : (expf(t0) - 1.f);
        v.y = t1 > 0.f ? t1 : (expf(t1) - 1.f);
        v.z = t2 > 0.f ? t2 : (expf(t2) - 1.f);
        v.w = t3 > 0.f ? t3 : (expf(t3) - 1.f);
        *reinterpret_cast<float4*>(&out[(size_t)dst * ldo + lane * 4]) = v;
    } else {
        float t0 = acc[0] + bias[lane];
        out[(size_t)dst * ldo + lane] = t0 > 0.f ? t0 : (expf(t0) - 1.f);
    }
}

// ---------------- edge bucketing ----------------
__global__ void edge_count(const int* __restrict__ ei, int* __restrict__ counts)
{
    int i = blockIdx.x * blockDim.x + threadIdx.x;
    if (i >= E_TOT) return;
    int dst = (i < NUM_E) ? ei[NUM_E + i] : (i - NUM_E);
    atomicAdd(&counts[dst], 1);
}

__global__ void edge_scatter(const int* __restrict__ ei, int* __restrict__ cursor,
                             int* __restrict__ ssrc)
{
    int i = blockIdx.x * blockDim.x + threadIdx.x;
    if (i >= E_TOT) return;
    int src, dst;
    if (i < NUM_E) { src = ei[i]; dst = ei[NUM_E + i]; }
    else           { src = dst = i - NUM_E; }
    int pos = atomicAdd(&cursor[dst], 1);
    ssrc[pos] = src;
}

// ---------------- generic scan (blocks of 256) ----------------
__global__ void scan_block(const int* __restrict__ in, int n,
                           int* __restrict__ incl, int* __restrict__ bsum)
{
    __shared__ int sh[256];
    int tid = threadIdx.x;
    int i = blockIdx.x * 256 + tid;
    int v = (i < n) ? in[i] : 0;
    sh[tid] = v;
    __syncthreads();
    for (int o = 1; o < 256; o <<= 1) {
        int t = (tid >= o) ? sh[tid - o] : 0;
        __syncthreads();
        sh[tid] += t;
        __syncthreads();
    }
    if (i < n) incl[i] = sh[tid];
    if (tid == 255) bsum[blockIdx.x] = sh[255];
}

__global__ void scan_sums(int* __restrict__ bsum, int nb)
{
    __shared__ int sh[256];
    int tid = threadIdx.x;
    int v = (tid < nb) ? bsum[tid] : 0;
    sh[tid] = v;
    __syncthreads();
    for (int o = 1; o < 256; o <<= 1) {
        int t = (tid >= o) ? sh[tid - o] : 0;
        __syncthreads();
        sh[tid] += t;
        __syncthreads();
    }
    if (tid < nb) bsum[tid] = sh[tid] - v;
}

__global__ void scan_final(const int* __restrict__ incl, const int* __restrict__ in,
                           const int* __restrict__ bsum, int n,
                           int* __restrict__ offs, int* __restrict__ cursor)
{
    int i = blockIdx.x * 256 + threadIdx.x;
    if (i >= n) return;
    int excl = incl[i] - in[i] + bsum[i / 256];
    offs[i] = excl;
    cursor[i] = excl;
    if (i == n - 1) offs[n] = incl[i] + bsum[i / 256];
}

// ---------------- graph row ranges from SORTED batch (no atomics) ----------------
__global__ void graph_bounds(const int* __restrict__ batch, int* __restrict__ goffs)
{
    int i = blockIdx.x * 256 + threadIdx.x;
    if (i >= N_NODES) return;
    int b = batch[i];
    int prev = (i == 0) ? -1 : batch[i - 1];
    for (int g = prev + 1; g <= b; ++g) goffs[g] = i;          // first row of graph g
    if (i == N_NODES - 1)
        for (int g = b + 1; g <= NGRAPH; ++g) goffs[g] = N_NODES;
}

// ---------------- BatchNorm ----------------
template<int OF>
__global__ __launch_bounds__(256)
void bn_stats(const float* __restrict__ x, int ldx, float* __restrict__ sums)
{
    constexpr int RP = 256 / OF;
    const int tid = threadIdx.x;
    const int col = tid % OF;
    const int rsub = tid / OF;
    float s = 0.f, s2 = 0.f;
    for (int r = blockIdx.x * RP + rsub; r < N_NODES; r += gridDim.x * RP) {
        float v = x[(size_t)r * ldx + col];
        s += v;
        s2 = fmaf(v, v, s2);
    }
    if constexpr (RP > 1) {
        __shared__ float sh[2][256];
        sh[0][tid] = s; sh[1][tid] = s2;
        __syncthreads();
        if (rsub == 0) {
#pragma unroll
            for (int j = 1; j < RP; ++j) { s += sh[0][col + j * OF]; s2 += sh[1][col + j * OF]; }
        }
    }
    if (rsub == 0) {
        atomicAdd(&sums[col], s);
        atomicAdd(&sums[OF + col], s2);
    }
}

template<int OF>
__global__ void bn_finalize(const float* __restrict__ sums, const float* __restrict__ gamma,
                            const float* __restrict__ beta, float* __restrict__ ss)
{
    int c = threadIdx.x;
    if (c >= OF) return;
    float mean = sums[c] / (float)N_NODES;
    float var = sums[OF + c] / (float)N_NODES - mean * mean;
    float inv = rsqrtf(var + EPS_BN);
    float sc = inv * gamma[c];
    ss[c] = sc;
    ss[OF + c] = beta[c] - mean * sc;
}

template<int OF, bool WB>
__global__ __launch_bounds__(256)
void bn_apply(float* __restrict__ x, int ldx, const float* __restrict__ ss,
              ushort* __restrict__ xb, int ldxb)
{
    int i = blockIdx.x * 256 + threadIdx.x;
    if (i >= N_NODES * OF) return;
    int r = i / OF, c = i - r * OF;
    float v = fmaf(x[(size_t)r * ldx + c], ss[c], ss[OF + c]);
    x[(size_t)r * ldx + c] = v;
    if constexpr (WB) xb[(size_t)r * ldxb + c] = f2bf(v);
}

// ---------------- pooling: 4 partial blocks per graph + atomics ----------------
__global__ void pool_kernel(const float* __restrict__ xs, const int* __restrict__ goffs,
                            float* __restrict__ pool)
{
    int g = blockIdx.x >> 2, part = blockIdx.x & 3;
    int c = threadIdx.x;  // 576
    int r0 = goffs[g], r1 = goffs[g + 1];
    int cnt = r1 - r0;
    int p0 = r0 + (cnt * part) / 4;
    int p1 = r0 + (cnt * (part + 1)) / 4;
    float s = 0.f;
    for (int r = p0; r < p1; ++r) s += xs[(size_t)r * XS_COLS + c];
    if (p1 > p0) atomicAdd(&pool[(size_t)g * XS_COLS + c], s);
}

extern "C" void kernel_launch(void* const* d_in, const int* in_sizes, int n_in,
                              void* d_out, int out_size, void* d_ws, size_t ws_size,
                              hipStream_t stream)
{
    const float* x     = (const float*)d_in[0];
    const int*   ei    = (const int*)d_in[1];
    const int*   batch = (const int*)d_in[2];
    const float* W[3]    = {(const float*)d_in[3],  (const float*)d_in[9],  (const float*)d_in[15]};
    const float* asrc[3] = {(const float*)d_in[4],  (const float*)d_in[10], (const float*)d_in[16]};
    const float* adst[3] = {(const float*)d_in[5],  (const float*)d_in[11], (const float*)d_in[17]};
    const float* bia[3]  = {(const float*)d_in[6],  (const float*)d_in[12], (const float*)d_in[18]};
    const float* gam[3]  = {(const float*)d_in[7],  (const float*)d_in[13], (const float*)d_in[19]};
    const float* bet[3]  = {(const float*)d_in[8],  (const float*)d_in[14], (const float*)d_in[20]};

    char* wp = (char*)d_ws;
    auto alloc = [&](size_t bytes) -> void* {
        void* p = (void*)wp;
        wp += (bytes + 255) & ~(size_t)255;
        return p;
    };
    ushort* hbf   = (ushort*)alloc((size_t)N_NODES * 256 * 2);
    ushort* Abf0  = (ushort*)alloc((size_t)M_PAD * 128 * 2);
    ushort* AbfA  = (ushort*)alloc((size_t)M_PAD * 256 * 2);
    float*  albuf = (float*)alloc((size_t)E_TOT * 4 * 4);
    float*  a_s   = (float*)alloc((size_t)N_NODES * 4 * 4);
    float*  a_d   = (float*)alloc((size_t)N_NODES * 4 * 4);
    int*    counts = (int*)alloc((size_t)N_NODES * 4);
    int*    offs   = (int*)alloc((size_t)(N_NODES + 1) * 4);
    int*    cursor = (int*)alloc((size_t)N_NODES * 4);
    int*    incl   = (int*)alloc((size_t)N_NODES * 4);
    int*    bsums  = (int*)alloc(1024);
    int*    ssrc   = (int*)alloc((size_t)E_TOT * 4);
    float*  bnsum  = (float*)alloc(2 * 256 * 4);
    float*  bnss   = (float*)alloc(2 * 256 * 4);
    int*    goffs  = (int*)alloc((NGRAPH + 1) * 4);
    ushort* Wt0    = (ushort*)alloc(256 * 128 * 2);
    ushort* Wt1    = (ushort*)alloc(256 * 256 * 2);
    ushort* Wt2    = (ushort*)alloc(64 * 256 * 2);

    float* pool = (float*)d_out;                    // [128, 576]
    float* xs   = pool + (size_t)NGRAPH * XS_COLS;  // [50000, 576]

    // ---- setup: edge bucketing by dst, graph bounds, weight transposes, x->bf16 ----
    hipMemsetAsync(counts, 0, (size_t)N_NODES * 4, stream);
    edge_count<<<ceil_div(E_TOT, 256), 256, 0, stream>>>(ei, counts);
    const int NSB = ceil_div(N_NODES, 256);
    scan_block<<<NSB, 256, 0, stream>>>(counts, N_NODES, incl, bsums);
    scan_sums<<<1, 256, 0, stream>>>(bsums, NSB);
    scan_final<<<NSB, 256, 0, stream>>>(incl, counts, bsums, N_NODES, offs, cursor);
    edge_scatter<<<ceil_div(E_TOT, 256), 256, 0, stream>>>(ei, cursor, ssrc);
    graph_bounds<<<ceil_div(N_NODES, 256), 256, 0, stream>>>(batch, goffs);

    w_transpose<<<ceil_div(256 * 128, 256), 256, 0, stream>>>(W[0], Wt0, 128, 256);
    w_transpose<<<ceil_div(256 * 256, 256), 256, 0, stream>>>(W[1], Wt1, 256, 256);
    w_transpose<<<ceil_div(64 * 256, 256), 256, 0, stream>>>(W[2], Wt2, 256, 64);
    f32_to_bf16_vec<<<ceil_div(N_NODES * 128 / 4, 256), 256, 0, stream>>>(x, Abf0, N_NODES * 128 / 4);

    const int NW = ceil_div(N_NODES, 4);
    const int NMB = ceil_div(N_NODES, 128);

    // ---------------- layer 0: 128 -> 4x64 concat (256) ----------------
    {
        dim3 grid(NMB, 4);
        gemm_bf16<128, 64, 64><<<grid, 256, 0, stream>>>(Abf0, 128, Wt0, 128, hbf, 256, N_NODES, 128);
        attn_coef<4, 64><<<NW, 256, 0, stream>>>(hbf, asrc[0], adst[0], a_s, a_d);
        edge_softmax<4><<<NW, 256, 0, stream>>>(offs, ssrc, a_s, a_d, albuf);
        gat_gather<4, 64><<<NW, 256, 0, stream>>>(offs, ssrc, albuf, hbf, bia[0], xs + 0, XS_COLS);
        hipMemsetAsync(bnsum, 0, 2 * 256 * 4, stream);
        bn_stats<256><<<256, 256, 0, stream>>>(xs + 0, XS_COLS, bnsum);
        bn_finalize<256><<<1, 256, 0, stream>>>(bnsum, gam[0], bet[0], bnss);
        bn_apply<256, true><<<ceil_div(N_NODES * 256, 256), 256, 0, stream>>>(xs + 0, XS_COLS, bnss, AbfA, 256);
    }
    // ---------------- layer 1: 256 -> 4x64 concat (256) ----------------
    {
        dim3 grid(NMB, 4);
        gemm_bf16<128, 64, 64><<<grid, 256, 0, stream>>>(AbfA, 256, Wt1, 256, hbf, 256, N_NODES, 256);
        attn_coef<4, 64><<<NW, 256, 0, stream>>>(hbf, asrc[1], adst[1], a_s, a_d);
        edge_softmax<4><<<NW, 256, 0, stream>>>(offs, ssrc, a_s, a_d, albuf);
        gat_gather<4, 64><<<NW, 256, 0, stream>>>(offs, ssrc, albuf, hbf, bia[1], xs + 256, XS_COLS);
        hipMemsetAsync(bnsum, 0, 2 * 256 * 4, stream);
        bn_stats<256><<<256, 256, 0, stream>>>(xs + 256, XS_COLS, bnsum);
        bn_finalize<256><<<1, 256, 0, stream>>>(bnsum, gam[1], bet[1], bnss);
        bn_apply<256, true><<<ceil_div(N_NODES * 256, 256), 256, 0, stream>>>(xs + 256, XS_COLS, bnss, AbfA, 256);
    }
    // ---------------- layer 2: 256 -> 1x64 ----------------
    {
        dim3 grid(NMB, 1);
        gemm_bf16<128, 64, 64><<<grid, 256, 0, stream>>>(AbfA, 256, Wt2, 256, hbf, 64, N_NODES, 256);
        attn_coef<1, 64><<<NW, 256, 0, stream>>>(hbf, asrc[2], adst[2], a_s, a_d);
        edge_softmax<1><<<NW, 256, 0, stream>>>(offs, ssrc, a_s, a_d, albuf);
        gat_gather<1, 64><<<NW, 256, 0, stream>>>(offs, ssrc, albuf, hbf, bia[2], xs + 512, XS_COLS);
        hipMemsetAsync(bnsum, 0, 2 * 64 * 4, stream);
        bn_stats<64><<<256, 256, 0, stream>>>(xs + 512, XS_COLS, bnsum);
        bn_finalize<64><<<1, 64, 0, stream>>>(bnsum, gam[2], bet[2], bnss);
        bn_apply<64, false><<<ceil_div(N_NODES * 64, 256), 256, 0, stream>>>(xs + 512, XS_COLS, bnss, nullptr, 0);
    }
    // ---------------- pooling ----------------
    hipMemsetAsync(pool, 0, (size_t)NGRAPH * XS_COLS * 4, stream);
    pool_kernel<<<NGRAPH * 4, XS_COLS, 0, stream>>>(xs, goffs, pool);
}

// Round 4
// 625.410 us; speedup vs baseline: 1.8703x; 1.1428x over previous
//
#include <hip/hip_runtime.h>
#include <math.h>

#define N_NODES 50000
#define NUM_E   800000
#define E_TOT   (NUM_E + N_NODES)   // 850000 (self loops appended)
#define M_PAD   50048               // N_NODES rounded up to 128
#define NGRAPH  128
#define XS_COLS 576
#define EPS_BN  1e-5f

static inline int ceil_div(int a, int b) { return (a + b - 1) / b; }

typedef __attribute__((ext_vector_type(8))) short short8;
typedef __attribute__((ext_vector_type(4))) float f32x4;

__device__ __forceinline__ float bf2f(ushort u) {
    union { unsigned int i; float f; } v; v.i = ((unsigned int)u) << 16; return v.f;
}
__device__ __forceinline__ ushort f2bf(float f) {
    union { float f; unsigned int i; } v; v.f = f;
    unsigned int r = v.i + 0x7FFF + ((v.i >> 16) & 1);
    return (ushort)(r >> 16);
}
__device__ __forceinline__ float lrelu(float l) { return l > 0.f ? l : 0.2f * l; }

// ---------------- prep: x->bf16 + 3 weight transposes, one kernel ----------------
__global__ __launch_bounds__(256)
void prep_all(const float* __restrict__ x, const float* __restrict__ W0,
              const float* __restrict__ W1, const float* __restrict__ W2,
              ushort* __restrict__ Abf0, ushort* __restrict__ Wt0,
              ushort* __restrict__ Wt1, ushort* __restrict__ Wt2)
{
    int i = blockIdx.x * 256 + threadIdx.x;
    const int NX4 = N_NODES * 128 / 4;   // 1,600,000 float4s
    if (i < NX4) {
        float4 v = reinterpret_cast<const float4*>(x)[i];
        ushort4 o;
        o.x = f2bf(v.x); o.y = f2bf(v.y); o.z = f2bf(v.z); o.w = f2bf(v.w);
        reinterpret_cast<ushort4*>(Abf0)[i] = o;
        return;
    }
    int j = i - NX4;
    if (j < 256 * 128) {                          // Wt0[n*128+k] = W0[k*256+n]
        Wt0[j] = f2bf(W0[(size_t)(j % 128) * 256 + (j / 128)]);
        return;
    }
    j -= 256 * 128;
    if (j < 256 * 256) {                          // Wt1[n*256+k] = W1[k*256+n]
        Wt1[j] = f2bf(W1[(size_t)(j % 256) * 256 + (j / 256)]);
        return;
    }
    j -= 256 * 256;
    if (j < 64 * 256) {                           // Wt2[n*256+k] = W2[k*64+n]
        Wt2[j] = f2bf(W2[(size_t)(j % 256) * 64 + (j / 256)]);
    }
}

// ---------------- bf16 MFMA GEMM:  C[M x Nc](bf16) = A[M x K](bf16) @ Bt^T ----------------
template<int BM, int BN, int BK>
__global__ __launch_bounds__(256)
void gemm_bf16(const ushort* __restrict__ A, int lda,
               const ushort* __restrict__ Bt, int ldb,
               ushort* __restrict__ C, int ldc, int M, int K)
{
    static_assert(BM == 128 && BN == 64 && BK == 64, "tuned variant");
    __shared__ __align__(16) ushort As[BM][BK + 8];
    __shared__ __align__(16) ushort Bs[BN][BK + 8];
    const int tid = threadIdx.x;
    const int lane = tid & 63;
    const int w = tid >> 6;
    const int m0 = blockIdx.x * BM;
    const int n0 = blockIdx.y * BN;

    f32x4 acc[2][4] = {};

    for (int k0 = 0; k0 < K; k0 += BK) {
#pragma unroll
        for (int j = 0; j < 4; ++j) {
            int c = tid + j * 256;
            int r = c >> 3, cc = (c & 7) * 8;
            short8 v = *reinterpret_cast<const short8*>(A + (size_t)(m0 + r) * lda + k0 + cc);
            *reinterpret_cast<short8*>(&As[r][cc]) = v;
        }
#pragma unroll
        for (int j = 0; j < 2; ++j) {
            int c = tid + j * 256;
            int r = c >> 3, cc = (c & 7) * 8;
            short8 v = *reinterpret_cast<const short8*>(Bt + (size_t)(n0 + r) * ldb + k0 + cc);
            *reinterpret_cast<short8*>(&Bs[r][cc]) = v;
        }
        __syncthreads();
#pragma unroll
        for (int kc = 0; kc < BK; kc += 32) {
            short8 a[2], b[4];
#pragma unroll
            for (int mf = 0; mf < 2; ++mf)
                a[mf] = *reinterpret_cast<const short8*>(&As[w * 32 + mf * 16 + (lane & 15)][kc + (lane >> 4) * 8]);
#pragma unroll
            for (int nf = 0; nf < 4; ++nf)
                b[nf] = *reinterpret_cast<const short8*>(&Bs[nf * 16 + (lane & 15)][kc + (lane >> 4) * 8]);
#pragma unroll
            for (int mf = 0; mf < 2; ++mf)
#pragma unroll
                for (int nf = 0; nf < 4; ++nf)
                    acc[mf][nf] = __builtin_amdgcn_mfma_f32_16x16x32_bf16(a[mf], b[nf], acc[mf][nf], 0, 0, 0);
        }
        __syncthreads();
    }
#pragma unroll
    for (int mf = 0; mf < 2; ++mf) {
        int mbase = m0 + w * 32 + mf * 16 + (lane >> 4) * 4;
#pragma unroll
        for (int r = 0; r < 4; ++r) {
            int m = mbase + r;
            if (m < M) {
#pragma unroll
                for (int nf = 0; nf < 4; ++nf)
                    C[(size_t)m * ldc + n0 + nf * 16 + (lane & 15)] = f2bf(acc[mf][nf][r]);
            }
        }
    }
}

// ---------------- a_s / a_d from bf16 h ----------------
template<int H, int C>
__global__ __launch_bounds__(256)
void attn_coef(const ushort* __restrict__ hf, const float* __restrict__ asrc,
               const float* __restrict__ adst,
               float* __restrict__ a_s, float* __restrict__ a_d)
{
    constexpr int V = (H * C) / 64;
    const int lane = threadIdx.x & 63;
    const int n = blockIdx.x * 4 + (threadIdx.x >> 6);
    if (n >= N_NODES) return;
    const ushort* hp = hf + (size_t)n * (H * C) + lane * V;
    float ss = 0.f, dd = 0.f;
    if constexpr (V == 4) {
        ushort4 hv = *reinterpret_cast<const ushort4*>(hp);
        float h0 = bf2f(hv.x), h1 = bf2f(hv.y), h2 = bf2f(hv.z), h3 = bf2f(hv.w);
        float4 sv = *reinterpret_cast<const float4*>(asrc + lane * 4);
        float4 dv = *reinterpret_cast<const float4*>(adst + lane * 4);
        ss = h0 * sv.x + h1 * sv.y + h2 * sv.z + h3 * sv.w;
        dd = h0 * dv.x + h1 * dv.y + h2 * dv.z + h3 * dv.w;
    } else {
        float hv = bf2f(hp[0]);
        ss = hv * asrc[lane];
        dd = hv * adst[lane];
    }
    constexpr int GS = C / V;
#pragma unroll
    for (int o = 1; o < GS; o <<= 1) {
        ss += __shfl_xor(ss, o, 64);
        dd += __shfl_xor(dd, o, 64);
    }
    if ((lane & (GS - 1)) == 0) {
        int hd = lane / GS;
        a_s[(size_t)n * H + hd] = ss;
        a_d[(size_t)n * H + hd] = dd;
    }
}

// ---------------- fused softmax + weighted gather (one wave per dst) ----------------
template<int H, int C>
__global__ __launch_bounds__(256)
void gat_fused(const int* __restrict__ offs, const int* __restrict__ ssrc,
               const float* __restrict__ a_s, const float* __restrict__ a_d,
               const ushort* __restrict__ hf, const float* __restrict__ bias,
               float* __restrict__ out, int ldo)
{
    constexpr int V = (H * C) / 64;   // 4 or 1
    const int lane = threadIdx.x & 63;
    const int dst = blockIdx.x * 4 + (threadIdx.x >> 6);
    if (dst >= N_NODES) return;
    const int e0 = offs[dst], e1 = offs[dst + 1];
    const int deg = e1 - e0;

    float ad[H];
    if constexpr (H == 4) {
        float4 v = *reinterpret_cast<const float4*>(a_d + (size_t)dst * 4);
        ad[0] = v.x; ad[1] = v.y; ad[2] = v.z; ad[3] = v.w;
    } else ad[0] = a_d[dst];

    float mx[H], sm[H];

    if (deg <= 64) {
        // single lane-parallel pass: one edge per lane, softmax in registers
        int e = e0 + lane;
        bool act = e < e1;
        int s = ssrc[act ? e : e0];
        float l[H];
        if constexpr (H == 4) {
            float4 v = *reinterpret_cast<const float4*>(a_s + (size_t)s * 4);
            l[0] = lrelu(v.x + ad[0]); l[1] = lrelu(v.y + ad[1]);
            l[2] = lrelu(v.z + ad[2]); l[3] = lrelu(v.w + ad[3]);
        } else l[0] = lrelu(a_s[s] + ad[0]);
#pragma unroll
        for (int t = 0; t < H; ++t) {
            mx[t] = act ? l[t] : -INFINITY;
#pragma unroll
            for (int o = 1; o < 64; o <<= 1) mx[t] = fmaxf(mx[t], __shfl_xor(mx[t], o, 64));
            sm[t] = act ? __expf(l[t] - mx[t]) : 0.f;
#pragma unroll
            for (int o = 1; o < 64; o <<= 1) sm[t] += __shfl_xor(sm[t], o, 64);
        }
    } else {
        // strided two-pass fallback (rare)
#pragma unroll
        for (int t = 0; t < H; ++t) mx[t] = -INFINITY;
        for (int e = e0 + lane; e < e1; e += 64) {
            int s = ssrc[e];
            float asv[H];
            if constexpr (H == 4) {
                float4 v = *reinterpret_cast<const float4*>(a_s + (size_t)s * 4);
                asv[0] = v.x; asv[1] = v.y; asv[2] = v.z; asv[3] = v.w;
            } else asv[0] = a_s[s];
#pragma unroll
            for (int t = 0; t < H; ++t) mx[t] = fmaxf(mx[t], lrelu(asv[t] + ad[t]));
        }
#pragma unroll
        for (int t = 0; t < H; ++t)
#pragma unroll
            for (int o = 1; o < 64; o <<= 1) mx[t] = fmaxf(mx[t], __shfl_xor(mx[t], o, 64));
#pragma unroll
        for (int t = 0; t < H; ++t) sm[t] = 0.f;
        for (int e = e0 + lane; e < e1; e += 64) {
            int s = ssrc[e];
            float asv[H];
            if constexpr (H == 4) {
                float4 v = *reinterpret_cast<const float4*>(a_s + (size_t)s * 4);
                asv[0] = v.x; asv[1] = v.y; asv[2] = v.z; asv[3] = v.w;
            } else asv[0] = a_s[s];
#pragma unroll
            for (int t = 0; t < H; ++t) sm[t] += __expf(lrelu(asv[t] + ad[t]) - mx[t]);
        }
#pragma unroll
        for (int t = 0; t < H; ++t)
#pragma unroll
            for (int o = 1; o < 64; o <<= 1) sm[t] += __shfl_xor(sm[t], o, 64);
    }

    // per-lane head constants
    const int hd = (lane * V) / C;
    float mxl = mx[0], sml = sm[0], adl = ad[0];
#pragma unroll
    for (int t = 1; t < H; ++t) {
        mxl = (hd == t) ? mx[t] : mxl;
        sml = (hd == t) ? sm[t] : sml;
        adl = (hd == t) ? ad[t] : adl;
    }
    const float invl = 1.f / (sml + 1e-16f);

    // phase 2: serial weighted accumulation, alpha recomputed (a_s is L2-resident)
    float acc[V];
#pragma unroll
    for (int k = 0; k < V; ++k) acc[k] = 0.f;

    int e = e0;
    for (; e + 3 < e1; e += 4) {
        int s0 = ssrc[e + 0], s1 = ssrc[e + 1], s2 = ssrc[e + 2], s3 = ssrc[e + 3];
        float b0 = a_s[(size_t)s0 * H + hd];
        float b1 = a_s[(size_t)s1 * H + hd];
        float b2 = a_s[(size_t)s2 * H + hd];
        float b3 = a_s[(size_t)s3 * H + hd];
        float al0 = __expf(lrelu(b0 + adl) - mxl) * invl;
        float al1 = __expf(lrelu(b1 + adl) - mxl) * invl;
        float al2 = __expf(lrelu(b2 + adl) - mxl) * invl;
        float al3 = __expf(lrelu(b3 + adl) - mxl) * invl;
        if constexpr (V == 4) {
            ushort4 h0 = *reinterpret_cast<const ushort4*>(hf + (size_t)s0 * (H * C) + lane * 4);
            ushort4 h1 = *reinterpret_cast<const ushort4*>(hf + (size_t)s1 * (H * C) + lane * 4);
            ushort4 h2 = *reinterpret_cast<const ushort4*>(hf + (size_t)s2 * (H * C) + lane * 4);
            ushort4 h3 = *reinterpret_cast<const ushort4*>(hf + (size_t)s3 * (H * C) + lane * 4);
            acc[0] = fmaf(al0, bf2f(h0.x), acc[0]); acc[1] = fmaf(al0, bf2f(h0.y), acc[1]);
            acc[2] = fmaf(al0, bf2f(h0.z), acc[2]); acc[3] = fmaf(al0, bf2f(h0.w), acc[3]);
            acc[0] = fmaf(al1, bf2f(h1.x), acc[0]); acc[1] = fmaf(al1, bf2f(h1.y), acc[1]);
            acc[2] = fmaf(al1, bf2f(h1.z), acc[2]); acc[3] = fmaf(al1, bf2f(h1.w), acc[3]);
            acc[0] = fmaf(al2, bf2f(h2.x), acc[0]); acc[1] = fmaf(al2, bf2f(h2.y), acc[1]);
            acc[2] = fmaf(al2, bf2f(h2.z), acc[2]); acc[3] = fmaf(al2, bf2f(h2.w), acc[3]);
            acc[0] = fmaf(al3, bf2f(h3.x), acc[0]); acc[1] = fmaf(al3, bf2f(h3.y), acc[1]);
            acc[2] = fmaf(al3, bf2f(h3.z), acc[2]); acc[3] = fmaf(al3, bf2f(h3.w), acc[3]);
        } else {
            acc[0] = fmaf(al0, bf2f(hf[(size_t)s0 * (H * C) + lane]), acc[0]);
            acc[0] = fmaf(al1, bf2f(hf[(size_t)s1 * (H * C) + lane]), acc[0]);
            acc[0] = fmaf(al2, bf2f(hf[(size_t)s2 * (H * C) + lane]), acc[0]);
            acc[0] = fmaf(al3, bf2f(hf[(size_t)s3 * (H * C) + lane]), acc[0]);
        }
    }
    for (; e < e1; ++e) {
        int s0 = ssrc[e];
        float b0 = a_s[(size_t)s0 * H + hd];
        float al0 = __expf(lrelu(b0 + adl) - mxl) * invl;
        if constexpr (V == 4) {
            ushort4 h0 = *reinterpret_cast<const ushort4*>(hf + (size_t)s0 * (H * C) + lane * 4);
            acc[0] = fmaf(al0, bf2f(h0.x), acc[0]); acc[1] = fmaf(al0, bf2f(h0.y), acc[1]);
            acc[2] = fmaf(al0, bf2f(h0.z), acc[2]); acc[3] = fmaf(al0, bf2f(h0.w), acc[3]);
        } else {
            acc[0] = fmaf(al0, bf2f(hf[(size_t)s0 * (H * C) + lane]), acc[0]);
        }
    }

    // epilogue: + bias, ELU, store
    if constexpr (V == 4) {
        float t0 = acc[0] + bias[lane * 4 + 0];
        float t1 = acc[1] + bias[lane * 4 + 1];
        float t2 = acc[2] + bias[lane * 4 + 2];
        float t3 = acc[3] + bias[lane * 4 + 3];
        float4 v;
        v.x = t0 > 0.f ? t0 : (expf(t0) - 1.f);
        v.y = t1 > 0.f ? t1 : (expf(t1) - 1.f);
        v.z = t2 > 0.f ? t2 : (expf(t2) - 1.f);
        v.w = t3 > 0.f ? t3 : (expf(t3) - 1.f);
        *reinterpret_cast<float4*>(&out[(size_t)dst * ldo + lane * 4]) = v;
    } else {
        float t0 = acc[0] + bias[lane];
        out[(size_t)dst * ldo + lane] = t0 > 0.f ? t0 : (expf(t0) - 1.f);
    }
}

// ---------------- edge bucketing ----------------
__global__ void edge_count(const int* __restrict__ ei, int* __restrict__ counts)
{
    int i = blockIdx.x * blockDim.x + threadIdx.x;
    if (i >= E_TOT) return;
    int dst = (i < NUM_E) ? ei[NUM_E + i] : (i - NUM_E);
    atomicAdd(&counts[dst], 1);
}

__global__ void edge_scatter(const int* __restrict__ ei, int* __restrict__ cursor,
                             int* __restrict__ ssrc)
{
    int i = blockIdx.x * blockDim.x + threadIdx.x;
    if (i >= E_TOT) return;
    int src, dst;
    if (i < NUM_E) { src = ei[i]; dst = ei[NUM_E + i]; }
    else           { src = dst = i - NUM_E; }
    int pos = atomicAdd(&cursor[dst], 1);
    ssrc[pos] = src;
}

// ---------------- generic scan (blocks of 256) ----------------
__global__ void scan_block(const int* __restrict__ in, int n,
                           int* __restrict__ incl, int* __restrict__ bsum)
{
    __shared__ int sh[256];
    int tid = threadIdx.x;
    int i = blockIdx.x * 256 + tid;
    int v = (i < n) ? in[i] : 0;
    sh[tid] = v;
    __syncthreads();
    for (int o = 1; o < 256; o <<= 1) {
        int t = (tid >= o) ? sh[tid - o] : 0;
        __syncthreads();
        sh[tid] += t;
        __syncthreads();
    }
    if (i < n) incl[i] = sh[tid];
    if (tid == 255) bsum[blockIdx.x] = sh[255];
}

__global__ void scan_sums(int* __restrict__ bsum, int nb)
{
    __shared__ int sh[256];
    int tid = threadIdx.x;
    int v = (tid < nb) ? bsum[tid] : 0;
    sh[tid] = v;
    __syncthreads();
    for (int o = 1; o < 256; o <<= 1) {
        int t = (tid >= o) ? sh[tid - o] : 0;
        __syncthreads();
        sh[tid] += t;
        __syncthreads();
    }
    if (tid < nb) bsum[tid] = sh[tid] - v;
}

__global__ void scan_final(const int* __restrict__ incl, const int* __restrict__ in,
                           const int* __restrict__ bsum, int n,
                           int* __restrict__ offs, int* __restrict__ cursor)
{
    int i = blockIdx.x * 256 + threadIdx.x;
    if (i >= n) return;
    int excl = incl[i] - in[i] + bsum[i / 256];
    offs[i] = excl;
    cursor[i] = excl;
    if (i == n - 1) offs[n] = incl[i] + bsum[i / 256];
}

// ---------------- graph row ranges from SORTED batch (no atomics) ----------------
__global__ void graph_bounds(const int* __restrict__ batch, int* __restrict__ goffs)
{
    int i = blockIdx.x * 256 + threadIdx.x;
    if (i >= N_NODES) return;
    int b = batch[i];
    int prev = (i == 0) ? -1 : batch[i - 1];
    for (int g = prev + 1; g <= b; ++g) goffs[g] = i;
    if (i == N_NODES - 1)
        for (int g = b + 1; g <= NGRAPH; ++g) goffs[g] = N_NODES;
}

// ---------------- BatchNorm: per-block partials (no atomics, no memset) ----------------
template<int OF>
__global__ __launch_bounds__(256)
void bn_stats(const float* __restrict__ x, int ldx, float* __restrict__ part)
{
    constexpr int RP = 256 / OF;
    const int tid = threadIdx.x;
    const int col = tid % OF;
    const int rsub = tid / OF;
    float s = 0.f, s2 = 0.f;
    for (int r = blockIdx.x * RP + rsub; r < N_NODES; r += gridDim.x * RP) {
        float v = x[(size_t)r * ldx + col];
        s += v;
        s2 = fmaf(v, v, s2);
    }
    if constexpr (RP > 1) {
        __shared__ float sh[2][256];
        sh[0][tid] = s; sh[1][tid] = s2;
        __syncthreads();
        if (rsub == 0) {
#pragma unroll
            for (int j = 1; j < RP; ++j) { s += sh[0][col + j * OF]; s2 += sh[1][col + j * OF]; }
        }
    }
    if (rsub == 0) {
        part[(size_t)blockIdx.x * 2 * OF + col] = s;
        part[(size_t)blockIdx.x * 2 * OF + OF + col] = s2;
    }
}

template<int OF>
__global__ void bn_finalize(const float* __restrict__ part, const float* __restrict__ gamma,
                            const float* __restrict__ beta, float* __restrict__ ss)
{
    int c = threadIdx.x;
    if (c >= OF) return;
    float s = 0.f, s2 = 0.f;
    for (int b = 0; b < 256; ++b) {
        s += part[(size_t)b * 2 * OF + c];
        s2 += part[(size_t)b * 2 * OF + OF + c];
    }
    float mean = s / (float)N_NODES;
    float var = s2 / (float)N_NODES - mean * mean;
    float inv = rsqrtf(var + EPS_BN);
    float sc = inv * gamma[c];
    ss[c] = sc;
    ss[OF + c] = beta[c] - mean * sc;
}

template<int OF, bool WB>
__global__ __launch_bounds__(256)
void bn_apply(float* __restrict__ x, int ldx, const float* __restrict__ ss,
              ushort* __restrict__ xb, int ldxb)
{
    int i = blockIdx.x * 256 + threadIdx.x;
    if (i >= N_NODES * OF) return;
    int r = i / OF, c = i - r * OF;
    float v = fmaf(x[(size_t)r * ldx + c], ss[c], ss[OF + c]);
    x[(size_t)r * ldx + c] = v;
    if constexpr (WB) xb[(size_t)r * ldxb + c] = f2bf(v);
}

// ---------------- pooling: 4 partial blocks per graph + atomics ----------------
__global__ void pool_kernel(const float* __restrict__ xs, const int* __restrict__ goffs,
                            float* __restrict__ pool)
{
    int g = blockIdx.x >> 2, part = blockIdx.x & 3;
    int c = threadIdx.x;  // 576
    int r0 = goffs[g], r1 = goffs[g + 1];
    int cnt = r1 - r0;
    int p0 = r0 + (cnt * part) / 4;
    int p1 = r0 + (cnt * (part + 1)) / 4;
    float s = 0.f;
    for (int r = p0; r < p1; ++r) s += xs[(size_t)r * XS_COLS + c];
    if (p1 > p0) atomicAdd(&pool[(size_t)g * XS_COLS + c], s);
}

extern "C" void kernel_launch(void* const* d_in, const int* in_sizes, int n_in,
                              void* d_out, int out_size, void* d_ws, size_t ws_size,
                              hipStream_t stream)
{
    const float* x     = (const float*)d_in[0];
    const int*   ei    = (const int*)d_in[1];
    const int*   batch = (const int*)d_in[2];
    const float* W[3]    = {(const float*)d_in[3],  (const float*)d_in[9],  (const float*)d_in[15]};
    const float* asrc[3] = {(const float*)d_in[4],  (const float*)d_in[10], (const float*)d_in[16]};
    const float* adst[3] = {(const float*)d_in[5],  (const float*)d_in[11], (const float*)d_in[17]};
    const float* bia[3]  = {(const float*)d_in[6],  (const float*)d_in[12], (const float*)d_in[18]};
    const float* gam[3]  = {(const float*)d_in[7],  (const float*)d_in[13], (const float*)d_in[19]};
    const float* bet[3]  = {(const float*)d_in[8],  (const float*)d_in[14], (const float*)d_in[20]};

    char* wp = (char*)d_ws;
    auto alloc = [&](size_t bytes) -> void* {
        void* p = (void*)wp;
        wp += (bytes + 255) & ~(size_t)255;
        return p;
    };
    ushort* hbf   = (ushort*)alloc((size_t)N_NODES * 256 * 2);
    ushort* Abf0  = (ushort*)alloc((size_t)M_PAD * 128 * 2);
    ushort* AbfA  = (ushort*)alloc((size_t)M_PAD * 256 * 2);
    float*  a_s   = (float*)alloc((size_t)N_NODES * 4 * 4);
    float*  a_d   = (float*)alloc((size_t)N_NODES * 4 * 4);
    int*    counts = (int*)alloc((size_t)N_NODES * 4);
    int*    offs   = (int*)alloc((size_t)(N_NODES + 1) * 4);
    int*    cursor = (int*)alloc((size_t)N_NODES * 4);
    int*    incl   = (int*)alloc((size_t)N_NODES * 4);
    int*    bsums  = (int*)alloc(1024);
    int*    ssrc   = (int*)alloc((size_t)E_TOT * 4);
    float*  bnpart = (float*)alloc((size_t)256 * 2 * 256 * 4);
    float*  bnss   = (float*)alloc(2 * 256 * 4);
    int*    goffs  = (int*)alloc((NGRAPH + 1) * 4);
    ushort* Wt0    = (ushort*)alloc(256 * 128 * 2);
    ushort* Wt1    = (ushort*)alloc(256 * 256 * 2);
    ushort* Wt2    = (ushort*)alloc(64 * 256 * 2);

    float* pool = (float*)d_out;                    // [128, 576]
    float* xs   = pool + (size_t)NGRAPH * XS_COLS;  // [50000, 576]

    // ---- setup ----
    hipMemsetAsync(counts, 0, (size_t)N_NODES * 4, stream);
    edge_count<<<ceil_div(E_TOT, 256), 256, 0, stream>>>(ei, counts);
    const int NSB = ceil_div(N_NODES, 256);
    scan_block<<<NSB, 256, 0, stream>>>(counts, N_NODES, incl, bsums);
    scan_sums<<<1, 256, 0, stream>>>(bsums, NSB);
    scan_final<<<NSB, 256, 0, stream>>>(incl, counts, bsums, N_NODES, offs, cursor);
    edge_scatter<<<ceil_div(E_TOT, 256), 256, 0, stream>>>(ei, cursor, ssrc);
    graph_bounds<<<ceil_div(N_NODES, 256), 256, 0, stream>>>(batch, goffs);
    const int PREP_ITEMS = N_NODES * 128 / 4 + 256 * 128 + 256 * 256 + 64 * 256;
    prep_all<<<ceil_div(PREP_ITEMS, 256), 256, 0, stream>>>(x, W[0], W[1], W[2], Abf0, Wt0, Wt1, Wt2);

    const int NW = ceil_div(N_NODES, 4);
    const int NMB = ceil_div(N_NODES, 128);

    // ---------------- layer 0: 128 -> 4x64 concat (256) ----------------
    {
        dim3 grid(NMB, 4);
        gemm_bf16<128, 64, 64><<<grid, 256, 0, stream>>>(Abf0, 128, Wt0, 128, hbf, 256, N_NODES, 128);
        attn_coef<4, 64><<<NW, 256, 0, stream>>>(hbf, asrc[0], adst[0], a_s, a_d);
        gat_fused<4, 64><<<NW, 256, 0, stream>>>(offs, ssrc, a_s, a_d, hbf, bia[0], xs + 0, XS_COLS);
        bn_stats<256><<<256, 256, 0, stream>>>(xs + 0, XS_COLS, bnpart);
        bn_finalize<256><<<1, 256, 0, stream>>>(bnpart, gam[0], bet[0], bnss);
        bn_apply<256, true><<<ceil_div(N_NODES * 256, 256), 256, 0, stream>>>(xs + 0, XS_COLS, bnss, AbfA, 256);
    }
    // ---------------- layer 1: 256 -> 4x64 concat (256) ----------------
    {
        dim3 grid(NMB, 4);
        gemm_bf16<128, 64, 64><<<grid, 256, 0, stream>>>(AbfA, 256, Wt1, 256, hbf, 256, N_NODES, 256);
        attn_coef<4, 64><<<NW, 256, 0, stream>>>(hbf, asrc[1], adst[1], a_s, a_d);
        gat_fused<4, 64><<<NW, 256, 0, stream>>>(offs, ssrc, a_s, a_d, hbf, bia[1], xs + 256, XS_COLS);
        bn_stats<256><<<256, 256, 0, stream>>>(xs + 256, XS_COLS, bnpart);
        bn_finalize<256><<<1, 256, 0, stream>>>(bnpart, gam[1], bet[1], bnss);
        bn_apply<256, true><<<ceil_div(N_NODES * 256, 256), 256, 0, stream>>>(xs + 256, XS_COLS, bnss, AbfA, 256);
    }
    // ---------------- layer 2: 256 -> 1x64 ----------------
    {
        dim3 grid(NMB, 1);
        gemm_bf16<128, 64, 64><<<grid, 256, 0, stream>>>(AbfA, 256, Wt2, 256, hbf, 64, N_NODES, 256);
        attn_coef<1, 64><<<NW, 256, 0, stream>>>(hbf, asrc[2], adst[2], a_s, a_d);
        gat_fused<1, 64><<<NW, 256, 0, stream>>>(offs, ssrc, a_s, a_d, hbf, bia[2], xs + 512, XS_COLS);
        bn_stats<64><<<256, 256, 0, stream>>>(xs + 512, XS_COLS, bnpart);
        bn_finalize<64><<<1, 64, 0, stream>>>(bnpart, gam[2], bet[2], bnss);
        bn_apply<64, false><<<ceil_div(N_NODES * 64, 256), 256, 0, stream>>>(xs + 512, XS_COLS, bnss, nullptr, 0);
    }
    // ---------------- pooling ----------------
    hipMemsetAsync(pool, 0, (size_t)NGRAPH * XS_COLS * 4, stream);
    pool_kernel<<<NGRAPH * 4, XS_COLS, 0, stream>>>(xs, goffs, pool);
}

// Round 5
// 600.668 us; speedup vs baseline: 1.9474x; 1.0412x over previous
//
#include <hip/hip_runtime.h>
#include <math.h>

#define N_NODES 50000
#define NUM_E   800000
#define E_TOT   (NUM_E + N_NODES)   // 850000 (self loops appended)
#define M_PAD   50048               // N_NODES rounded up to 128
#define NGRAPH  128
#define XS_COLS 576
#define EPS_BN  1e-5f

static inline int ceil_div(int a, int b) { return (a + b - 1) / b; }

typedef __attribute__((ext_vector_type(8))) short short8;
typedef __attribute__((ext_vector_type(4))) float f32x4;

__device__ __forceinline__ float bf2f(ushort u) {
    union { unsigned int i; float f; } v; v.i = ((unsigned int)u) << 16; return v.f;
}
__device__ __forceinline__ ushort f2bf(float f) {
    union { float f; unsigned int i; } v; v.f = f;
    unsigned int r = v.i + 0x7FFF + ((v.i >> 16) & 1);
    return (ushort)(r >> 16);
}
__device__ __forceinline__ float lrelu(float l) { return l > 0.f ? l : 0.2f * l; }

// ---------------- prep: x->bf16 + 3 weight transposes, one kernel ----------------
__global__ __launch_bounds__(256)
void prep_all(const float* __restrict__ x, const float* __restrict__ W0,
              const float* __restrict__ W1, const float* __restrict__ W2,
              ushort* __restrict__ Abf0, ushort* __restrict__ Wt0,
              ushort* __restrict__ Wt1, ushort* __restrict__ Wt2)
{
    int i = blockIdx.x * 256 + threadIdx.x;
    const int NX4 = N_NODES * 128 / 4;
    if (i < NX4) {
        float4 v = reinterpret_cast<const float4*>(x)[i];
        ushort4 o;
        o.x = f2bf(v.x); o.y = f2bf(v.y); o.z = f2bf(v.z); o.w = f2bf(v.w);
        reinterpret_cast<ushort4*>(Abf0)[i] = o;
        return;
    }
    int j = i - NX4;
    if (j < 256 * 128) { Wt0[j] = f2bf(W0[(size_t)(j % 128) * 256 + (j / 128)]); return; }
    j -= 256 * 128;
    if (j < 256 * 256) { Wt1[j] = f2bf(W1[(size_t)(j % 256) * 256 + (j / 256)]); return; }
    j -= 256 * 256;
    if (j < 64 * 256)  { Wt2[j] = f2bf(W2[(size_t)(j % 256) * 64 + (j / 256)]); }
}

// ---------------- bf16 MFMA GEMM + fused attention-coefficient epilogue ----------------
// C[M x Nc](bf16) = A[M x K](bf16) @ Bt^T ; block (bx,by) covers cols of head `by`
// (BN=64 == head width), so a_s/a_d for its rows reduce fully in-block from fp32 acc.
template<int BM, int BN, int BK, int H>
__global__ __launch_bounds__(256)
void gemm_bf16(const ushort* __restrict__ A, int lda,
               const ushort* __restrict__ Bt, int ldb,
               ushort* __restrict__ C, int ldc, int M, int K,
               const float* __restrict__ asrc, const float* __restrict__ adst,
               float* __restrict__ a_s, float* __restrict__ a_d)
{
    static_assert(BM == 128 && BN == 64 && BK == 64, "tuned variant");
    __shared__ __align__(16) ushort As[BM][BK + 8];
    __shared__ __align__(16) ushort Bs[BN][BK + 8];
    const int tid = threadIdx.x;
    const int lane = tid & 63;
    const int w = tid >> 6;
    const int m0 = blockIdx.x * BM;
    const int n0 = blockIdx.y * BN;

    f32x4 acc[2][4] = {};

    for (int k0 = 0; k0 < K; k0 += BK) {
#pragma unroll
        for (int j = 0; j < 4; ++j) {
            int c = tid + j * 256;
            int r = c >> 3, cc = (c & 7) * 8;
            short8 v = *reinterpret_cast<const short8*>(A + (size_t)(m0 + r) * lda + k0 + cc);
            *reinterpret_cast<short8*>(&As[r][cc]) = v;
        }
#pragma unroll
        for (int j = 0; j < 2; ++j) {
            int c = tid + j * 256;
            int r = c >> 3, cc = (c & 7) * 8;
            short8 v = *reinterpret_cast<const short8*>(Bt + (size_t)(n0 + r) * ldb + k0 + cc);
            *reinterpret_cast<short8*>(&Bs[r][cc]) = v;
        }
        __syncthreads();
#pragma unroll
        for (int kc = 0; kc < BK; kc += 32) {
            short8 a[2], b[4];
#pragma unroll
            for (int mf = 0; mf < 2; ++mf)
                a[mf] = *reinterpret_cast<const short8*>(&As[w * 32 + mf * 16 + (lane & 15)][kc + (lane >> 4) * 8]);
#pragma unroll
            for (int nf = 0; nf < 4; ++nf)
                b[nf] = *reinterpret_cast<const short8*>(&Bs[nf * 16 + (lane & 15)][kc + (lane >> 4) * 8]);
#pragma unroll
            for (int mf = 0; mf < 2; ++mf)
#pragma unroll
                for (int nf = 0; nf < 4; ++nf)
                    acc[mf][nf] = __builtin_amdgcn_mfma_f32_16x16x32_bf16(a[mf], b[nf], acc[mf][nf], 0, 0, 0);
        }
        __syncthreads();
    }

    // C-write (bf16): col = n0 + nf*16 + (lane&15), row = m0 + w*32 + mf*16 + (lane>>4)*4 + r
#pragma unroll
    for (int mf = 0; mf < 2; ++mf) {
        int mbase = m0 + w * 32 + mf * 16 + (lane >> 4) * 4;
#pragma unroll
        for (int r = 0; r < 4; ++r) {
            int m = mbase + r;
            if (m < M) {
#pragma unroll
                for (int nf = 0; nf < 4; ++nf)
                    C[(size_t)m * ldc + n0 + nf * 16 + (lane & 15)] = f2bf(acc[mf][nf][r]);
            }
        }
    }

    // attention-coefficient epilogue: a_s[m,hd] = sum_cols acc*asrc, hd = blockIdx.y
    const int hd = blockIdx.y;
    float asl[4], adl[4];
#pragma unroll
    for (int nf = 0; nf < 4; ++nf) {
        int col = n0 + nf * 16 + (lane & 15);
        asl[nf] = asrc[col];
        adl[nf] = adst[col];
    }
#pragma unroll
    for (int mf = 0; mf < 2; ++mf) {
#pragma unroll
        for (int r = 0; r < 4; ++r) {
            float ps = 0.f, pd = 0.f;
#pragma unroll
            for (int nf = 0; nf < 4; ++nf) {
                ps = fmaf(acc[mf][nf][r], asl[nf], ps);
                pd = fmaf(acc[mf][nf][r], adl[nf], pd);
            }
#pragma unroll
            for (int o = 1; o < 16; o <<= 1) {
                ps += __shfl_xor(ps, o, 64);
                pd += __shfl_xor(pd, o, 64);
            }
            int m = m0 + w * 32 + mf * 16 + (lane >> 4) * 4 + r;
            if ((lane & 15) == 0 && m < M) {
                a_s[(size_t)m * H + hd] = ps;
                a_d[(size_t)m * H + hd] = pd;
            }
        }
    }
}

// ---------------- fused softmax + weighted gather (one wave per dst) ----------------
template<int H, int C>
__global__ __launch_bounds__(256)
void gat_fused(const int* __restrict__ offs, const int* __restrict__ ssrc,
               const float* __restrict__ a_s, const float* __restrict__ a_d,
               const ushort* __restrict__ hf, const float* __restrict__ bias,
               float* __restrict__ out, int ldo)
{
    constexpr int V = (H * C) / 64;   // 4 or 1
    __shared__ float alsh[4][64 * H];
    const int lane = threadIdx.x & 63;
    const int wv = threadIdx.x >> 6;
    const int dst = blockIdx.x * 4 + wv;
    if (dst >= N_NODES) return;
    const int e0 = offs[dst], e1 = offs[dst + 1];
    const int deg = e1 - e0;
    const int hd = (lane * V) / C;

    float ad[H];
    if constexpr (H == 4) {
        float4 v = *reinterpret_cast<const float4*>(a_d + (size_t)dst * 4);
        ad[0] = v.x; ad[1] = v.y; ad[2] = v.z; ad[3] = v.w;
    } else ad[0] = a_d[dst];

    float acc[V];
#pragma unroll
    for (int k = 0; k < V; ++k) acc[k] = 0.f;

    if (deg <= 64) {
        // ---- phase 1: one edge per lane; alpha computed once, cached in LDS ----
        int e = e0 + lane;
        bool act = e < e1;
        int s = ssrc[act ? e : e0];
        float l[H], mx[H], sm[H];
        if constexpr (H == 4) {
            float4 v = *reinterpret_cast<const float4*>(a_s + (size_t)s * 4);
            l[0] = lrelu(v.x + ad[0]); l[1] = lrelu(v.y + ad[1]);
            l[2] = lrelu(v.z + ad[2]); l[3] = lrelu(v.w + ad[3]);
        } else l[0] = lrelu(a_s[s] + ad[0]);
#pragma unroll
        for (int t = 0; t < H; ++t) {
            mx[t] = act ? l[t] : -INFINITY;
#pragma unroll
            for (int o = 1; o < 64; o <<= 1) mx[t] = fmaxf(mx[t], __shfl_xor(mx[t], o, 64));
            sm[t] = act ? __expf(l[t] - mx[t]) : 0.f;
#pragma unroll
            for (int o = 1; o < 64; o <<= 1) sm[t] += __shfl_xor(sm[t], o, 64);
        }
        if constexpr (H == 4) {
            float4 av;
            av.x = act ? __expf(l[0] - mx[0]) / (sm[0] + 1e-16f) : 0.f;
            av.y = act ? __expf(l[1] - mx[1]) / (sm[1] + 1e-16f) : 0.f;
            av.z = act ? __expf(l[2] - mx[2]) / (sm[2] + 1e-16f) : 0.f;
            av.w = act ? __expf(l[3] - mx[3]) / (sm[3] + 1e-16f) : 0.f;
            *reinterpret_cast<float4*>(&alsh[wv][lane * 4]) = av;
        } else {
            alsh[wv][lane] = act ? __expf(l[0] - mx[0]) / (sm[0] + 1e-16f) : 0.f;
        }
        // ---- phase 2: serial gather, alpha from LDS broadcast ----
        int e2 = e0;
        for (; e2 + 3 < e1; e2 += 4) {
            int i0 = e2 - e0;
            int s0 = ssrc[e2 + 0], s1 = ssrc[e2 + 1], s2 = ssrc[e2 + 2], s3 = ssrc[e2 + 3];
            float al0 = alsh[wv][(i0 + 0) * H + hd];
            float al1 = alsh[wv][(i0 + 1) * H + hd];
            float al2 = alsh[wv][(i0 + 2) * H + hd];
            float al3 = alsh[wv][(i0 + 3) * H + hd];
            if constexpr (V == 4) {
                ushort4 h0 = *reinterpret_cast<const ushort4*>(hf + (size_t)s0 * (H * C) + lane * 4);
                ushort4 h1 = *reinterpret_cast<const ushort4*>(hf + (size_t)s1 * (H * C) + lane * 4);
                ushort4 h2 = *reinterpret_cast<const ushort4*>(hf + (size_t)s2 * (H * C) + lane * 4);
                ushort4 h3 = *reinterpret_cast<const ushort4*>(hf + (size_t)s3 * (H * C) + lane * 4);
                acc[0] = fmaf(al0, bf2f(h0.x), acc[0]); acc[1] = fmaf(al0, bf2f(h0.y), acc[1]);
                acc[2] = fmaf(al0, bf2f(h0.z), acc[2]); acc[3] = fmaf(al0, bf2f(h0.w), acc[3]);
                acc[0] = fmaf(al1, bf2f(h1.x), acc[0]); acc[1] = fmaf(al1, bf2f(h1.y), acc[1]);
                acc[2] = fmaf(al1, bf2f(h1.z), acc[2]); acc[3] = fmaf(al1, bf2f(h1.w), acc[3]);
                acc[0] = fmaf(al2, bf2f(h2.x), acc[0]); acc[1] = fmaf(al2, bf2f(h2.y), acc[1]);
                acc[2] = fmaf(al2, bf2f(h2.z), acc[2]); acc[3] = fmaf(al2, bf2f(h2.w), acc[3]);
                acc[0] = fmaf(al3, bf2f(h3.x), acc[0]); acc[1] = fmaf(al3, bf2f(h3.y), acc[1]);
                acc[2] = fmaf(al3, bf2f(h3.z), acc[2]); acc[3] = fmaf(al3, bf2f(h3.w), acc[3]);
            } else {
                acc[0] = fmaf(al0, bf2f(hf[(size_t)s0 * (H * C) + lane]), acc[0]);
                acc[0] = fmaf(al1, bf2f(hf[(size_t)s1 * (H * C) + lane]), acc[0]);
                acc[0] = fmaf(al2, bf2f(hf[(size_t)s2 * (H * C) + lane]), acc[0]);
                acc[0] = fmaf(al3, bf2f(hf[(size_t)s3 * (H * C) + lane]), acc[0]);
            }
        }
        for (; e2 < e1; ++e2) {
            int s0 = ssrc[e2];
            float al0 = alsh[wv][(e2 - e0) * H + hd];
            if constexpr (V == 4) {
                ushort4 h0 = *reinterpret_cast<const ushort4*>(hf + (size_t)s0 * (H * C) + lane * 4);
                acc[0] = fmaf(al0, bf2f(h0.x), acc[0]); acc[1] = fmaf(al0, bf2f(h0.y), acc[1]);
                acc[2] = fmaf(al0, bf2f(h0.z), acc[2]); acc[3] = fmaf(al0, bf2f(h0.w), acc[3]);
            } else {
                acc[0] = fmaf(al0, bf2f(hf[(size_t)s0 * (H * C) + lane]), acc[0]);
            }
        }
    } else {
        // ---- fallback (deg > 64, rare): strided two-pass softmax + recompute ----
        float mx[H], sm[H];
#pragma unroll
        for (int t = 0; t < H; ++t) mx[t] = -INFINITY;
        for (int e = e0 + lane; e < e1; e += 64) {
            int s = ssrc[e];
            float asv[H];
            if constexpr (H == 4) {
                float4 v = *reinterpret_cast<const float4*>(a_s + (size_t)s * 4);
                asv[0] = v.x; asv[1] = v.y; asv[2] = v.z; asv[3] = v.w;
            } else asv[0] = a_s[s];
#pragma unroll
            for (int t = 0; t < H; ++t) mx[t] = fmaxf(mx[t], lrelu(asv[t] + ad[t]));
        }
#pragma unroll
        for (int t = 0; t < H; ++t)
#pragma unroll
            for (int o = 1; o < 64; o <<= 1) mx[t] = fmaxf(mx[t], __shfl_xor(mx[t], o, 64));
#pragma unroll
        for (int t = 0; t < H; ++t) sm[t] = 0.f;
        for (int e = e0 + lane; e < e1; e += 64) {
            int s = ssrc[e];
            float asv[H];
            if constexpr (H == 4) {
                float4 v = *reinterpret_cast<const float4*>(a_s + (size_t)s * 4);
                asv[0] = v.x; asv[1] = v.y; asv[2] = v.z; asv[3] = v.w;
            } else asv[0] = a_s[s];
#pragma unroll
            for (int t = 0; t < H; ++t) sm[t] += __expf(lrelu(asv[t] + ad[t]) - mx[t]);
        }
#pragma unroll
        for (int t = 0; t < H; ++t)
#pragma unroll
            for (int o = 1; o < 64; o <<= 1) sm[t] += __shfl_xor(sm[t], o, 64);

        float mxl = mx[0], sml = sm[0], adl = ad[0];
#pragma unroll
        for (int t = 1; t < H; ++t) {
            mxl = (hd == t) ? mx[t] : mxl;
            sml = (hd == t) ? sm[t] : sml;
            adl = (hd == t) ? ad[t] : adl;
        }
        const float invl = 1.f / (sml + 1e-16f);
        for (int e = e0; e < e1; ++e) {
            int s0 = ssrc[e];
            float al0 = __expf(lrelu(a_s[(size_t)s0 * H + hd] + adl) - mxl) * invl;
            if constexpr (V == 4) {
                ushort4 h0 = *reinterpret_cast<const ushort4*>(hf + (size_t)s0 * (H * C) + lane * 4);
                acc[0] = fmaf(al0, bf2f(h0.x), acc[0]); acc[1] = fmaf(al0, bf2f(h0.y), acc[1]);
                acc[2] = fmaf(al0, bf2f(h0.z), acc[2]); acc[3] = fmaf(al0, bf2f(h0.w), acc[3]);
            } else {
                acc[0] = fmaf(al0, bf2f(hf[(size_t)s0 * (H * C) + lane]), acc[0]);
            }
        }
    }

    // epilogue: + bias, ELU, store
    if constexpr (V == 4) {
        float t0 = acc[0] + bias[lane * 4 + 0];
        float t1 = acc[1] + bias[lane * 4 + 1];
        float t2 = acc[2] + bias[lane * 4 + 2];
        float t3 = acc[3] + bias[lane * 4 + 3];
        float4 v;
        v.x = t0 > 0.f ? t0 : (expf(t0) - 1.f);
        v.y = t1 > 0.f ? t1 : (expf(t1) - 1.f);
        v.z = t2 > 0.f ? t2 : (expf(t2) - 1.f);
        v.w = t3 > 0.f ? t3 : (expf(t3) - 1.f);
        *reinterpret_cast<float4*>(&out[(size_t)dst * ldo + lane * 4]) = v;
    } else {
        float t0 = acc[0] + bias[lane];
        out[(size_t)dst * ldo + lane] = t0 > 0.f ? t0 : (expf(t0) - 1.f);
    }
}

// ---------------- edge bucketing ----------------
__global__ void edge_count(const int* __restrict__ ei, int* __restrict__ counts)
{
    int i = blockIdx.x * blockDim.x + threadIdx.x;
    if (i >= E_TOT) return;
    int dst = (i < NUM_E) ? ei[NUM_E + i] : (i - NUM_E);
    atomicAdd(&counts[dst], 1);
}

__global__ void edge_scatter(const int* __restrict__ ei, int* __restrict__ cursor,
                             int* __restrict__ ssrc)
{
    int i = blockIdx.x * blockDim.x + threadIdx.x;
    if (i >= E_TOT) return;
    int src, dst;
    if (i < NUM_E) { src = ei[i]; dst = ei[NUM_E + i]; }
    else           { src = dst = i - NUM_E; }
    int pos = atomicAdd(&cursor[dst], 1);
    ssrc[pos] = src;
}

// ---------------- generic scan (blocks of 256) ----------------
__global__ void scan_block(const int* __restrict__ in, int n,
                           int* __restrict__ incl, int* __restrict__ bsum)
{
    __shared__ int sh[256];
    int tid = threadIdx.x;
    int i = blockIdx.x * 256 + tid;
    int v = (i < n) ? in[i] : 0;
    sh[tid] = v;
    __syncthreads();
    for (int o = 1; o < 256; o <<= 1) {
        int t = (tid >= o) ? sh[tid - o] : 0;
        __syncthreads();
        sh[tid] += t;
        __syncthreads();
    }
    if (i < n) incl[i] = sh[tid];
    if (tid == 255) bsum[blockIdx.x] = sh[255];
}

__global__ void scan_sums(int* __restrict__ bsum, int nb)
{
    __shared__ int sh[256];
    int tid = threadIdx.x;
    int v = (tid < nb) ? bsum[tid] : 0;
    sh[tid] = v;
    __syncthreads();
    for (int o = 1; o < 256; o <<= 1) {
        int t = (tid >= o) ? sh[tid - o] : 0;
        __syncthreads();
        sh[tid] += t;
        __syncthreads();
    }
    if (tid < nb) bsum[tid] = sh[tid] - v;
}

__global__ void scan_final(const int* __restrict__ incl, const int* __restrict__ in,
                           const int* __restrict__ bsum, int n,
                           int* __restrict__ offs, int* __restrict__ cursor)
{
    int i = blockIdx.x * 256 + threadIdx.x;
    if (i >= n) return;
    int excl = incl[i] - in[i] + bsum[i / 256];
    offs[i] = excl;
    cursor[i] = excl;
    if (i == n - 1) offs[n] = incl[i] + bsum[i / 256];
}

// ---------------- graph row ranges from SORTED batch (no atomics) ----------------
__global__ void graph_bounds(const int* __restrict__ batch, int* __restrict__ goffs)
{
    int i = blockIdx.x * 256 + threadIdx.x;
    if (i >= N_NODES) return;
    int b = batch[i];
    int prev = (i == 0) ? -1 : batch[i - 1];
    for (int g = prev + 1; g <= b; ++g) goffs[g] = i;
    if (i == N_NODES - 1)
        for (int g = b + 1; g <= NGRAPH; ++g) goffs[g] = N_NODES;
}

// ---------------- BatchNorm: per-block partials (no atomics, no memset) ----------------
template<int OF>
__global__ __launch_bounds__(256)
void bn_stats(const float* __restrict__ x, int ldx, float* __restrict__ part)
{
    constexpr int RP = 256 / OF;
    const int tid = threadIdx.x;
    const int col = tid % OF;
    const int rsub = tid / OF;
    float s = 0.f, s2 = 0.f;
    for (int r = blockIdx.x * RP + rsub; r < N_NODES; r += gridDim.x * RP) {
        float v = x[(size_t)r * ldx + col];
        s += v;
        s2 = fmaf(v, v, s2);
    }
    if constexpr (RP > 1) {
        __shared__ float sh[2][256];
        sh[0][tid] = s; sh[1][tid] = s2;
        __syncthreads();
        if (rsub == 0) {
#pragma unroll
            for (int j = 1; j < RP; ++j) { s += sh[0][col + j * OF]; s2 += sh[1][col + j * OF]; }
        }
    }
    if (rsub == 0) {
        part[(size_t)blockIdx.x * 2 * OF + col] = s;
        part[(size_t)blockIdx.x * 2 * OF + OF + col] = s2;
    }
}

template<int OF>
__global__ void bn_finalize(const float* __restrict__ part, const float* __restrict__ gamma,
                            const float* __restrict__ beta, float* __restrict__ ss)
{
    int c = threadIdx.x;
    if (c >= OF) return;
    float s = 0.f, s2 = 0.f;
    for (int b = 0; b < 256; ++b) {
        s += part[(size_t)b * 2 * OF + c];
        s2 += part[(size_t)b * 2 * OF + OF + c];
    }
    float mean = s / (float)N_NODES;
    float var = s2 / (float)N_NODES - mean * mean;
    float inv = rsqrtf(var + EPS_BN);
    float sc = inv * gamma[c];
    ss[c] = sc;
    ss[OF + c] = beta[c] - mean * sc;
}

template<int OF, bool WB>
__global__ __launch_bounds__(256)
void bn_apply(float* __restrict__ x, int ldx, const float* __restrict__ ss,
              ushort* __restrict__ xb, int ldxb)
{
    int i = blockIdx.x * 256 + threadIdx.x;
    if (i >= N_NODES * OF) return;
    int r = i / OF, c = i - r * OF;
    float v = fmaf(x[(size_t)r * ldx + c], ss[c], ss[OF + c]);
    x[(size_t)r * ldx + c] = v;
    if constexpr (WB) xb[(size_t)r * ldxb + c] = f2bf(v);
}

// ---------------- pooling: 4 partial blocks per graph + atomics ----------------
__global__ void pool_kernel(const float* __restrict__ xs, const int* __restrict__ goffs,
                            float* __restrict__ pool)
{
    int g = blockIdx.x >> 2, part = blockIdx.x & 3;
    int c = threadIdx.x;  // 576
    int r0 = goffs[g], r1 = goffs[g + 1];
    int cnt = r1 - r0;
    int p0 = r0 + (cnt * part) / 4;
    int p1 = r0 + (cnt * (part + 1)) / 4;
    float s = 0.f;
    for (int r = p0; r < p1; ++r) s += xs[(size_t)r * XS_COLS + c];
    if (p1 > p0) atomicAdd(&pool[(size_t)g * XS_COLS + c], s);
}

extern "C" void kernel_launch(void* const* d_in, const int* in_sizes, int n_in,
                              void* d_out, int out_size, void* d_ws, size_t ws_size,
                              hipStream_t stream)
{
    const float* x     = (const float*)d_in[0];
    const int*   ei    = (const int*)d_in[1];
    const int*   batch = (const int*)d_in[2];
    const float* W[3]    = {(const float*)d_in[3],  (const float*)d_in[9],  (const float*)d_in[15]};
    const float* asrc[3] = {(const float*)d_in[4],  (const float*)d_in[10], (const float*)d_in[16]};
    const float* adst[3] = {(const float*)d_in[5],  (const float*)d_in[11], (const float*)d_in[17]};
    const float* bia[3]  = {(const float*)d_in[6],  (const float*)d_in[12], (const float*)d_in[18]};
    const float* gam[3]  = {(const float*)d_in[7],  (const float*)d_in[13], (const float*)d_in[19]};
    const float* bet[3]  = {(const float*)d_in[8],  (const float*)d_in[14], (const float*)d_in[20]};

    char* wp = (char*)d_ws;
    auto alloc = [&](size_t bytes) -> void* {
        void* p = (void*)wp;
        wp += (bytes + 255) & ~(size_t)255;
        return p;
    };
    ushort* hbf   = (ushort*)alloc((size_t)N_NODES * 256 * 2);
    ushort* Abf0  = (ushort*)alloc((size_t)M_PAD * 128 * 2);
    ushort* AbfA  = (ushort*)alloc((size_t)M_PAD * 256 * 2);
    float*  a_s   = (float*)alloc((size_t)N_NODES * 4 * 4);
    float*  a_d   = (float*)alloc((size_t)N_NODES * 4 * 4);
    int*    counts = (int*)alloc((size_t)N_NODES * 4);
    int*    offs   = (int*)alloc((size_t)(N_NODES + 1) * 4);
    int*    cursor = (int*)alloc((size_t)N_NODES * 4);
    int*    incl   = (int*)alloc((size_t)N_NODES * 4);
    int*    bsums  = (int*)alloc(1024);
    int*    ssrc   = (int*)alloc((size_t)E_TOT * 4);
    float*  bnpart = (float*)alloc((size_t)256 * 2 * 256 * 4);
    float*  bnss   = (float*)alloc(2 * 256 * 4);
    int*    goffs  = (int*)alloc((NGRAPH + 1) * 4);
    ushort* Wt0    = (ushort*)alloc(256 * 128 * 2);
    ushort* Wt1    = (ushort*)alloc(256 * 256 * 2);
    ushort* Wt2    = (ushort*)alloc(64 * 256 * 2);

    float* pool = (float*)d_out;                    // [128, 576]
    float* xs   = pool + (size_t)NGRAPH * XS_COLS;  // [50000, 576]

    // ---- setup ----
    hipMemsetAsync(counts, 0, (size_t)N_NODES * 4, stream);
    edge_count<<<ceil_div(E_TOT, 256), 256, 0, stream>>>(ei, counts);
    const int NSB = ceil_div(N_NODES, 256);
    scan_block<<<NSB, 256, 0, stream>>>(counts, N_NODES, incl, bsums);
    scan_sums<<<1, 256, 0, stream>>>(bsums, NSB);
    scan_final<<<NSB, 256, 0, stream>>>(incl, counts, bsums, N_NODES, offs, cursor);
    edge_scatter<<<ceil_div(E_TOT, 256), 256, 0, stream>>>(ei, cursor, ssrc);
    graph_bounds<<<ceil_div(N_NODES, 256), 256, 0, stream>>>(batch, goffs);
    const int PREP_ITEMS = N_NODES * 128 / 4 + 256 * 128 + 256 * 256 + 64 * 256;
    prep_all<<<ceil_div(PREP_ITEMS, 256), 256, 0, stream>>>(x, W[0], W[1], W[2], Abf0, Wt0, Wt1, Wt2);

    const int NW = ceil_div(N_NODES, 4);
    const int NMB = ceil_div(N_NODES, 128);

    // ---------------- layer 0: 128 -> 4x64 concat (256) ----------------
    {
        dim3 grid(NMB, 4);
        gemm_bf16<128, 64, 64, 4><<<grid, 256, 0, stream>>>(Abf0, 128, Wt0, 128, hbf, 256, N_NODES, 128,
                                                            asrc[0], adst[0], a_s, a_d);
        gat_fused<4, 64><<<NW, 256, 0, stream>>>(offs, ssrc, a_s, a_d, hbf, bia[0], xs + 0, XS_COLS);
        bn_stats<256><<<256, 256, 0, stream>>>(xs + 0, XS_COLS, bnpart);
        bn_finalize<256><<<1, 256, 0, stream>>>(bnpart, gam[0], bet[0], bnss);
        bn_apply<256, true><<<ceil_div(N_NODES * 256, 256), 256, 0, stream>>>(xs + 0, XS_COLS, bnss, AbfA, 256);
    }
    // ---------------- layer 1: 256 -> 4x64 concat (256) ----------------
    {
        dim3 grid(NMB, 4);
        gemm_bf16<128, 64, 64, 4><<<grid, 256, 0, stream>>>(AbfA, 256, Wt1, 256, hbf, 256, N_NODES, 256,
                                                            asrc[1], adst[1], a_s, a_d);
        gat_fused<4, 64><<<NW, 256, 0, stream>>>(offs, ssrc, a_s, a_d, hbf, bia[1], xs + 256, XS_COLS);
        bn_stats<256><<<256, 256, 0, stream>>>(xs + 256, XS_COLS, bnpart);
        bn_finalize<256><<<1, 256, 0, stream>>>(bnpart, gam[1], bet[1], bnss);
        bn_apply<256, true><<<ceil_div(N_NODES * 256, 256), 256, 0, stream>>>(xs + 256, XS_COLS, bnss, AbfA, 256);
    }
    // ---------------- layer 2: 256 -> 1x64 ----------------
    {
        dim3 grid(NMB, 1);
        gemm_bf16<128, 64, 64, 1><<<grid, 256, 0, stream>>>(AbfA, 256, Wt2, 256, hbf, 64, N_NODES, 256,
                                                            asrc[2], adst[2], a_s, a_d);
        gat_fused<1, 64><<<NW, 256, 0, stream>>>(offs, ssrc, a_s, a_d, hbf, bia[2], xs + 512, XS_COLS);
        bn_stats<64><<<256, 256, 0, stream>>>(xs + 512, XS_COLS, bnpart);
        bn_finalize<64><<<1, 64, 0, stream>>>(bnpart, gam[2], bet[2], bnss);
        bn_apply<64, false><<<ceil_div(N_NODES * 64, 256), 256, 0, stream>>>(xs + 512, XS_COLS, bnss, nullptr, 0);
    }
    // ---------------- pooling ----------------
    hipMemsetAsync(pool, 0, (size_t)NGRAPH * XS_COLS * 4, stream);
    pool_kernel<<<NGRAPH * 4, XS_COLS, 0, stream>>>(xs, goffs, pool);
}

// Round 6
// 554.799 us; speedup vs baseline: 2.1084x; 1.0827x over previous
//
#include <hip/hip_runtime.h>
#include <math.h>

#define N_NODES 50000
#define NUM_E   800000
#define E_TOT   (NUM_E + N_NODES)   // 850000 (self loops appended)
#define M_PAD   50048               // N_NODES rounded up to 128
#define NGRAPH  128
#define XS_COLS 576
#define EPS_BN  1e-5f

static inline int ceil_div(int a, int b) { return (a + b - 1) / b; }

typedef __attribute__((ext_vector_type(8))) short short8;
typedef __attribute__((ext_vector_type(4))) float f32x4;

__device__ __forceinline__ float bf2f(ushort u) {
    union { unsigned int i; float f; } v; v.i = ((unsigned int)u) << 16; return v.f;
}
__device__ __forceinline__ ushort f2bf(float f) {
    union { float f; unsigned int i; } v; v.f = f;
    unsigned int r = v.i + 0x7FFF + ((v.i >> 16) & 1);
    return (ushort)(r >> 16);
}
__device__ __forceinline__ float lrelu(float l) { return l > 0.f ? l : 0.2f * l; }

// ---------------- prep: x->bf16 + 3 weight transposes, one kernel ----------------
__global__ __launch_bounds__(256)
void prep_all(const float* __restrict__ x, const float* __restrict__ W0,
              const float* __restrict__ W1, const float* __restrict__ W2,
              ushort* __restrict__ Abf0, ushort* __restrict__ Wt0,
              ushort* __restrict__ Wt1, ushort* __restrict__ Wt2)
{
    int i = blockIdx.x * 256 + threadIdx.x;
    const int NX4 = N_NODES * 128 / 4;
    if (i < NX4) {
        float4 v = reinterpret_cast<const float4*>(x)[i];
        ushort4 o;
        o.x = f2bf(v.x); o.y = f2bf(v.y); o.z = f2bf(v.z); o.w = f2bf(v.w);
        reinterpret_cast<ushort4*>(Abf0)[i] = o;
        return;
    }
    int j = i - NX4;
    if (j < 256 * 128) { Wt0[j] = f2bf(W0[(size_t)(j % 128) * 256 + (j / 128)]); return; }
    j -= 256 * 128;
    if (j < 256 * 256) { Wt1[j] = f2bf(W1[(size_t)(j % 256) * 256 + (j / 256)]); return; }
    j -= 256 * 256;
    if (j < 64 * 256)  { Wt2[j] = f2bf(W2[(size_t)(j % 256) * 64 + (j / 256)]); }
}

// ---------------- wide bf16 MFMA GEMM (BM=128, BN=256=all cols, 8 waves) ----------------
// C[M x 256](bf16) = A[M x K] @ Bt^T; single column block -> A read exactly once.
// Fused attention-coefficient epilogue for all H=4 heads (head = col/64).
__global__ __launch_bounds__(512)
void gemm_bf16_w(const ushort* __restrict__ A, int lda,
                 const ushort* __restrict__ Bt, int ldb,
                 ushort* __restrict__ C, int M, int K,
                 const float* __restrict__ asrc, const float* __restrict__ adst,
                 float* __restrict__ a_s, float* __restrict__ a_d)
{
    __shared__ __align__(16) ushort As[128][64 + 8];
    __shared__ __align__(16) ushort Bs[256][64 + 8];
    const int tid = threadIdx.x;
    const int lane = tid & 63;
    const int w = tid >> 6;            // 8 waves: rows w*16 .. w*16+15
    const int m0 = blockIdx.x * 128;

    f32x4 acc[16] = {};

    for (int k0 = 0; k0 < K; k0 += 64) {
        // stage A: 128x64 = 1024 short8 chunks, 2 per thread
#pragma unroll
        for (int j = 0; j < 2; ++j) {
            int c = tid + j * 512;
            int r = c >> 3, cc = (c & 7) * 8;
            short8 v = *reinterpret_cast<const short8*>(A + (size_t)(m0 + r) * lda + k0 + cc);
            *reinterpret_cast<short8*>(&As[r][cc]) = v;
        }
        // stage B: 256x64 = 2048 chunks, 4 per thread
#pragma unroll
        for (int j = 0; j < 4; ++j) {
            int c = tid + j * 512;
            int r = c >> 3, cc = (c & 7) * 8;
            short8 v = *reinterpret_cast<const short8*>(Bt + (size_t)r * ldb + k0 + cc);
            *reinterpret_cast<short8*>(&Bs[r][cc]) = v;
        }
        __syncthreads();
#pragma unroll
        for (int kc = 0; kc < 64; kc += 32) {
            short8 a = *reinterpret_cast<const short8*>(&As[w * 16 + (lane & 15)][kc + (lane >> 4) * 8]);
#pragma unroll
            for (int nf = 0; nf < 16; ++nf) {
                short8 b = *reinterpret_cast<const short8*>(&Bs[nf * 16 + (lane & 15)][kc + (lane >> 4) * 8]);
                acc[nf] = __builtin_amdgcn_mfma_f32_16x16x32_bf16(a, b, acc[nf], 0, 0, 0);
            }
        }
        __syncthreads();
    }

    // C write: row = m0 + w*16 + (lane>>4)*4 + r ; col = nf*16 + (lane&15)
    const int mbase = m0 + w * 16 + (lane >> 4) * 4;
#pragma unroll
    for (int r = 0; r < 4; ++r) {
        int m = mbase + r;
        if (m < M) {
#pragma unroll
            for (int nf = 0; nf < 16; ++nf)
                C[(size_t)m * 256 + nf * 16 + (lane & 15)] = f2bf(acc[nf][r]);
        }
    }

    // attention-coefficient epilogue: head h covers nf = 4h..4h+3
    float asl[16], adl[16];
#pragma unroll
    for (int nf = 0; nf < 16; ++nf) {
        int col = nf * 16 + (lane & 15);
        asl[nf] = asrc[col];
        adl[nf] = adst[col];
    }
#pragma unroll
    for (int r = 0; r < 4; ++r) {
        float ps[4] = {0.f, 0.f, 0.f, 0.f};
        float pd[4] = {0.f, 0.f, 0.f, 0.f};
#pragma unroll
        for (int nf = 0; nf < 16; ++nf) {
            int h = nf >> 2;
            ps[h] = fmaf(acc[nf][r], asl[nf], ps[h]);
            pd[h] = fmaf(acc[nf][r], adl[nf], pd[h]);
        }
#pragma unroll
        for (int h = 0; h < 4; ++h) {
#pragma unroll
            for (int o = 1; o < 16; o <<= 1) {
                ps[h] += __shfl_xor(ps[h], o, 64);
                pd[h] += __shfl_xor(pd[h], o, 64);
            }
        }
        int m = mbase + r;
        if ((lane & 15) == 0 && m < M) {
#pragma unroll
            for (int h = 0; h < 4; ++h) {
                a_s[(size_t)m * 4 + h] = ps[h];
                a_d[(size_t)m * 4 + h] = pd[h];
            }
        }
    }
}

// ---------------- narrow GEMM for layer 2 (BN=64, H=1 epilogue) ----------------
template<int BM, int BN, int BK, int H>
__global__ __launch_bounds__(256)
void gemm_bf16(const ushort* __restrict__ A, int lda,
               const ushort* __restrict__ Bt, int ldb,
               ushort* __restrict__ C, int ldc, int M, int K,
               const float* __restrict__ asrc, const float* __restrict__ adst,
               float* __restrict__ a_s, float* __restrict__ a_d)
{
    static_assert(BM == 128 && BN == 64 && BK == 64, "tuned variant");
    __shared__ __align__(16) ushort As[BM][BK + 8];
    __shared__ __align__(16) ushort Bs[BN][BK + 8];
    const int tid = threadIdx.x;
    const int lane = tid & 63;
    const int w = tid >> 6;
    const int m0 = blockIdx.x * BM;
    const int n0 = blockIdx.y * BN;

    f32x4 acc[2][4] = {};

    for (int k0 = 0; k0 < K; k0 += BK) {
#pragma unroll
        for (int j = 0; j < 4; ++j) {
            int c = tid + j * 256;
            int r = c >> 3, cc = (c & 7) * 8;
            short8 v = *reinterpret_cast<const short8*>(A + (size_t)(m0 + r) * lda + k0 + cc);
            *reinterpret_cast<short8*>(&As[r][cc]) = v;
        }
#pragma unroll
        for (int j = 0; j < 2; ++j) {
            int c = tid + j * 256;
            int r = c >> 3, cc = (c & 7) * 8;
            short8 v = *reinterpret_cast<const short8*>(Bt + (size_t)(n0 + r) * ldb + k0 + cc);
            *reinterpret_cast<short8*>(&Bs[r][cc]) = v;
        }
        __syncthreads();
#pragma unroll
        for (int kc = 0; kc < BK; kc += 32) {
            short8 a[2], b[4];
#pragma unroll
            for (int mf = 0; mf < 2; ++mf)
                a[mf] = *reinterpret_cast<const short8*>(&As[w * 32 + mf * 16 + (lane & 15)][kc + (lane >> 4) * 8]);
#pragma unroll
            for (int nf = 0; nf < 4; ++nf)
                b[nf] = *reinterpret_cast<const short8*>(&Bs[nf * 16 + (lane & 15)][kc + (lane >> 4) * 8]);
#pragma unroll
            for (int mf = 0; mf < 2; ++mf)
#pragma unroll
                for (int nf = 0; nf < 4; ++nf)
                    acc[mf][nf] = __builtin_amdgcn_mfma_f32_16x16x32_bf16(a[mf], b[nf], acc[mf][nf], 0, 0, 0);
        }
        __syncthreads();
    }

#pragma unroll
    for (int mf = 0; mf < 2; ++mf) {
        int mbase = m0 + w * 32 + mf * 16 + (lane >> 4) * 4;
#pragma unroll
        for (int r = 0; r < 4; ++r) {
            int m = mbase + r;
            if (m < M) {
#pragma unroll
                for (int nf = 0; nf < 4; ++nf)
                    C[(size_t)m * ldc + n0 + nf * 16 + (lane & 15)] = f2bf(acc[mf][nf][r]);
            }
        }
    }

    const int hd = blockIdx.y;
    float asl[4], adl[4];
#pragma unroll
    for (int nf = 0; nf < 4; ++nf) {
        int col = n0 + nf * 16 + (lane & 15);
        asl[nf] = asrc[col];
        adl[nf] = adst[col];
    }
#pragma unroll
    for (int mf = 0; mf < 2; ++mf) {
#pragma unroll
        for (int r = 0; r < 4; ++r) {
            float ps = 0.f, pd = 0.f;
#pragma unroll
            for (int nf = 0; nf < 4; ++nf) {
                ps = fmaf(acc[mf][nf][r], asl[nf], ps);
                pd = fmaf(acc[mf][nf][r], adl[nf], pd);
            }
#pragma unroll
            for (int o = 1; o < 16; o <<= 1) {
                ps += __shfl_xor(ps, o, 64);
                pd += __shfl_xor(pd, o, 64);
            }
            int m = m0 + w * 32 + mf * 16 + (lane >> 4) * 4 + r;
            if ((lane & 15) == 0 && m < M) {
                a_s[(size_t)m * H + hd] = ps;
                a_d[(size_t)m * H + hd] = pd;
            }
        }
    }
}

// ---------------- fused softmax + weighted gather (one wave per dst) ----------------
template<int H, int C>
__global__ __launch_bounds__(256)
void gat_fused(const int* __restrict__ offs, const int* __restrict__ ssrc,
               const float* __restrict__ a_s, const float* __restrict__ a_d,
               const ushort* __restrict__ hf, const float* __restrict__ bias,
               float* __restrict__ out, int ldo)
{
    constexpr int V = (H * C) / 64;   // 4 or 1
    __shared__ float alsh[4][64 * H];
    const int lane = threadIdx.x & 63;
    const int wv = threadIdx.x >> 6;
    const int dst = blockIdx.x * 4 + wv;
    if (dst >= N_NODES) return;
    const int e0 = offs[dst], e1 = offs[dst + 1];
    const int deg = e1 - e0;
    const int hd = (lane * V) / C;

    float ad[H];
    if constexpr (H == 4) {
        float4 v = *reinterpret_cast<const float4*>(a_d + (size_t)dst * 4);
        ad[0] = v.x; ad[1] = v.y; ad[2] = v.z; ad[3] = v.w;
    } else ad[0] = a_d[dst];

    float acc[V];
#pragma unroll
    for (int k = 0; k < V; ++k) acc[k] = 0.f;

    if (deg <= 64) {
        // ---- phase 1: one edge per lane; alpha computed once, cached in LDS ----
        int e = e0 + lane;
        bool act = e < e1;
        int s = ssrc[act ? e : e0];
        float l[H], mx[H], sm[H];
        if constexpr (H == 4) {
            float4 v = *reinterpret_cast<const float4*>(a_s + (size_t)s * 4);
            l[0] = lrelu(v.x + ad[0]); l[1] = lrelu(v.y + ad[1]);
            l[2] = lrelu(v.z + ad[2]); l[3] = lrelu(v.w + ad[3]);
        } else l[0] = lrelu(a_s[s] + ad[0]);
#pragma unroll
        for (int t = 0; t < H; ++t) {
            mx[t] = act ? l[t] : -INFINITY;
#pragma unroll
            for (int o = 1; o < 64; o <<= 1) mx[t] = fmaxf(mx[t], __shfl_xor(mx[t], o, 64));
            sm[t] = act ? __expf(l[t] - mx[t]) : 0.f;
#pragma unroll
            for (int o = 1; o < 64; o <<= 1) sm[t] += __shfl_xor(sm[t], o, 64);
        }
        if constexpr (H == 4) {
            float4 av;
            av.x = act ? __expf(l[0] - mx[0]) / (sm[0] + 1e-16f) : 0.f;
            av.y = act ? __expf(l[1] - mx[1]) / (sm[1] + 1e-16f) : 0.f;
            av.z = act ? __expf(l[2] - mx[2]) / (sm[2] + 1e-16f) : 0.f;
            av.w = act ? __expf(l[3] - mx[3]) / (sm[3] + 1e-16f) : 0.f;
            *reinterpret_cast<float4*>(&alsh[wv][lane * 4]) = av;
        } else {
            alsh[wv][lane] = act ? __expf(l[0] - mx[0]) / (sm[0] + 1e-16f) : 0.f;
        }
        // ---- phase 2: serial gather, 8-wide; src via shfl broadcast, alpha from LDS ----
        const ushort* hlane = hf + (size_t)lane * V;
        int e2 = e0;
        for (; e2 + 7 < e1; e2 += 8) {
            int base = e2 - e0;
            int sj[8]; float al[8];
#pragma unroll
            for (int j = 0; j < 8; ++j) {
                sj[j] = __shfl(s, base + j, 64);
                al[j] = alsh[wv][(base + j) * H + hd];
            }
            if constexpr (V == 4) {
                ushort4 hv[8];
#pragma unroll
                for (int j = 0; j < 8; ++j)
                    hv[j] = *reinterpret_cast<const ushort4*>(hlane + (size_t)sj[j] * (H * C));
#pragma unroll
                for (int j = 0; j < 8; ++j) {
                    acc[0] = fmaf(al[j], bf2f(hv[j].x), acc[0]);
                    acc[1] = fmaf(al[j], bf2f(hv[j].y), acc[1]);
                    acc[2] = fmaf(al[j], bf2f(hv[j].z), acc[2]);
                    acc[3] = fmaf(al[j], bf2f(hv[j].w), acc[3]);
                }
            } else {
                ushort hv[8];
#pragma unroll
                for (int j = 0; j < 8; ++j)
                    hv[j] = hlane[(size_t)sj[j] * (H * C)];
#pragma unroll
                for (int j = 0; j < 8; ++j)
                    acc[0] = fmaf(al[j], bf2f(hv[j]), acc[0]);
            }
        }
        for (; e2 < e1; ++e2) {
            int base = e2 - e0;
            int s0 = __shfl(s, base, 64);
            float al0 = alsh[wv][base * H + hd];
            if constexpr (V == 4) {
                ushort4 h0 = *reinterpret_cast<const ushort4*>(hlane + (size_t)s0 * (H * C));
                acc[0] = fmaf(al0, bf2f(h0.x), acc[0]); acc[1] = fmaf(al0, bf2f(h0.y), acc[1]);
                acc[2] = fmaf(al0, bf2f(h0.z), acc[2]); acc[3] = fmaf(al0, bf2f(h0.w), acc[3]);
            } else {
                acc[0] = fmaf(al0, bf2f(hlane[(size_t)s0 * (H * C)]), acc[0]);
            }
        }
    } else {
        // ---- fallback (deg > 64, rare): strided two-pass softmax + recompute ----
        float mx[H], sm[H];
#pragma unroll
        for (int t = 0; t < H; ++t) mx[t] = -INFINITY;
        for (int e = e0 + lane; e < e1; e += 64) {
            int s = ssrc[e];
            float asv[H];
            if constexpr (H == 4) {
                float4 v = *reinterpret_cast<const float4*>(a_s + (size_t)s * 4);
                asv[0] = v.x; asv[1] = v.y; asv[2] = v.z; asv[3] = v.w;
            } else asv[0] = a_s[s];
#pragma unroll
            for (int t = 0; t < H; ++t) mx[t] = fmaxf(mx[t], lrelu(asv[t] + ad[t]));
        }
#pragma unroll
        for (int t = 0; t < H; ++t)
#pragma unroll
            for (int o = 1; o < 64; o <<= 1) mx[t] = fmaxf(mx[t], __shfl_xor(mx[t], o, 64));
#pragma unroll
        for (int t = 0; t < H; ++t) sm[t] = 0.f;
        for (int e = e0 + lane; e < e1; e += 64) {
            int s = ssrc[e];
            float asv[H];
            if constexpr (H == 4) {
                float4 v = *reinterpret_cast<const float4*>(a_s + (size_t)s * 4);
                asv[0] = v.x; asv[1] = v.y; asv[2] = v.z; asv[3] = v.w;
            } else asv[0] = a_s[s];
#pragma unroll
            for (int t = 0; t < H; ++t) sm[t] += __expf(lrelu(asv[t] + ad[t]) - mx[t]);
        }
#pragma unroll
        for (int t = 0; t < H; ++t)
#pragma unroll
            for (int o = 1; o < 64; o <<= 1) sm[t] += __shfl_xor(sm[t], o, 64);

        float mxl = mx[0], sml = sm[0], adl = ad[0];
#pragma unroll
        for (int t = 1; t < H; ++t) {
            mxl = (hd == t) ? mx[t] : mxl;
            sml = (hd == t) ? sm[t] : sml;
            adl = (hd == t) ? ad[t] : adl;
        }
        const float invl = 1.f / (sml + 1e-16f);
        for (int e = e0; e < e1; ++e) {
            int s0 = ssrc[e];
            float al0 = __expf(lrelu(a_s[(size_t)s0 * H + hd] + adl) - mxl) * invl;
            if constexpr (V == 4) {
                ushort4 h0 = *reinterpret_cast<const ushort4*>(hf + (size_t)s0 * (H * C) + lane * 4);
                acc[0] = fmaf(al0, bf2f(h0.x), acc[0]); acc[1] = fmaf(al0, bf2f(h0.y), acc[1]);
                acc[2] = fmaf(al0, bf2f(h0.z), acc[2]); acc[3] = fmaf(al0, bf2f(h0.w), acc[3]);
            } else {
                acc[0] = fmaf(al0, bf2f(hf[(size_t)s0 * (H * C) + lane]), acc[0]);
            }
        }
    }

    // epilogue: + bias, ELU, store
    if constexpr (V == 4) {
        float t0 = acc[0] + bias[lane * 4 + 0];
        float t1 = acc[1] + bias[lane * 4 + 1];
        float t2 = acc[2] + bias[lane * 4 + 2];
        float t3 = acc[3] + bias[lane * 4 + 3];
        float4 v;
        v.x = t0 > 0.f ? t0 : (expf(t0) - 1.f);
        v.y = t1 > 0.f ? t1 : (expf(t1) - 1.f);
        v.z = t2 > 0.f ? t2 : (expf(t2) - 1.f);
        v.w = t3 > 0.f ? t3 : (expf(t3) - 1.f);
        *reinterpret_cast<float4*>(&out[(size_t)dst * ldo + lane * 4]) = v;
    } else {
        float t0 = acc[0] + bias[lane];
        out[(size_t)dst * ldo + lane] = t0 > 0.f ? t0 : (expf(t0) - 1.f);
    }
}

// ---------------- edge bucketing ----------------
__global__ void edge_count(const int* __restrict__ ei, int* __restrict__ counts)
{
    int i = blockIdx.x * blockDim.x + threadIdx.x;
    if (i >= E_TOT) return;
    int dst = (i < NUM_E) ? ei[NUM_E + i] : (i - NUM_E);
    atomicAdd(&counts[dst], 1);
}

__global__ void edge_scatter(const int* __restrict__ ei, int* __restrict__ cursor,
                             int* __restrict__ ssrc)
{
    int i = blockIdx.x * blockDim.x + threadIdx.x;
    if (i >= E_TOT) return;
    int src, dst;
    if (i < NUM_E) { src = ei[i]; dst = ei[NUM_E + i]; }
    else           { src = dst = i - NUM_E; }
    int pos = atomicAdd(&cursor[dst], 1);
    ssrc[pos] = src;
}

// ---------------- generic scan (blocks of 256) ----------------
__global__ void scan_block(const int* __restrict__ in, int n,
                           int* __restrict__ incl, int* __restrict__ bsum)
{
    __shared__ int sh[256];
    int tid = threadIdx.x;
    int i = blockIdx.x * 256 + tid;
    int v = (i < n) ? in[i] : 0;
    sh[tid] = v;
    __syncthreads();
    for (int o = 1; o < 256; o <<= 1) {
        int t = (tid >= o) ? sh[tid - o] : 0;
        __syncthreads();
        sh[tid] += t;
        __syncthreads();
    }
    if (i < n) incl[i] = sh[tid];
    if (tid == 255) bsum[blockIdx.x] = sh[255];
}

__global__ void scan_sums(int* __restrict__ bsum, int nb)
{
    __shared__ int sh[256];
    int tid = threadIdx.x;
    int v = (tid < nb) ? bsum[tid] : 0;
    sh[tid] = v;
    __syncthreads();
    for (int o = 1; o < 256; o <<= 1) {
        int t = (tid >= o) ? sh[tid - o] : 0;
        __syncthreads();
        sh[tid] += t;
        __syncthreads();
    }
    if (tid < nb) bsum[tid] = sh[tid] - v;
}

__global__ void scan_final(const int* __restrict__ incl, const int* __restrict__ in,
                           const int* __restrict__ bsum, int n,
                           int* __restrict__ offs, int* __restrict__ cursor)
{
    int i = blockIdx.x * 256 + threadIdx.x;
    if (i >= n) return;
    int excl = incl[i] - in[i] + bsum[i / 256];
    offs[i] = excl;
    cursor[i] = excl;
    if (i == n - 1) offs[n] = incl[i] + bsum[i / 256];
}

// ---------------- BatchNorm: per-block partials (no atomics, no memset) ----------------
template<int OF>
__global__ __launch_bounds__(256)
void bn_stats(const float* __restrict__ x, int ldx, float* __restrict__ part)
{
    constexpr int RP = 256 / OF;
    const int tid = threadIdx.x;
    const int col = tid % OF;
    const int rsub = tid / OF;
    float s = 0.f, s2 = 0.f;
    for (int r = blockIdx.x * RP + rsub; r < N_NODES; r += gridDim.x * RP) {
        float v = x[(size_t)r * ldx + col];
        s += v;
        s2 = fmaf(v, v, s2);
    }
    if constexpr (RP > 1) {
        __shared__ float sh[2][256];
        sh[0][tid] = s; sh[1][tid] = s2;
        __syncthreads();
        if (rsub == 0) {
#pragma unroll
            for (int j = 1; j < RP; ++j) { s += sh[0][col + j * OF]; s2 += sh[1][col + j * OF]; }
        }
    }
    if (rsub == 0) {
        part[(size_t)blockIdx.x * 2 * OF + col] = s;
        part[(size_t)blockIdx.x * 2 * OF + OF + col] = s2;
    }
}

template<int OF>
__global__ void bn_finalize(const float* __restrict__ part, const float* __restrict__ gamma,
                            const float* __restrict__ beta, float* __restrict__ ss)
{
    int c = threadIdx.x;
    if (c >= OF) return;
    float s = 0.f, s2 = 0.f;
    for (int b = 0; b < 256; ++b) {
        s += part[(size_t)b * 2 * OF + c];
        s2 += part[(size_t)b * 2 * OF + OF + c];
    }
    float mean = s / (float)N_NODES;
    float var = s2 / (float)N_NODES - mean * mean;
    float inv = rsqrtf(var + EPS_BN);
    float sc = inv * gamma[c];
    ss[c] = sc;
    ss[OF + c] = beta[c] - mean * sc;
}

// ---------------- BN apply + fused graph pooling (batch sorted -> running sums) ----------------
// block covers 16 rows; thread owns one column (OF=256) or col+4-row-lane (OF=64).
template<int OF, bool WB>
__global__ __launch_bounds__(256)
void bn_apply_pool(float* __restrict__ x, int ldx, const float* __restrict__ ss,
                   ushort* __restrict__ xb, int ldxb,
                   const int* __restrict__ batch, float* __restrict__ pool, int poff)
{
    const int tid = threadIdx.x;
    if constexpr (OF == 256) {
        const int c = tid;
        const int r0 = blockIdx.x * 16;
        const float sc = ss[c], sh = ss[OF + c];
        float psum = 0.f;
        int curg = batch[r0];
#pragma unroll
        for (int i = 0; i < 16; ++i) {
            int r = r0 + i;
            int g = batch[r];
            if (g != curg) {
                atomicAdd(&pool[(size_t)curg * XS_COLS + poff + c], psum);
                psum = 0.f; curg = g;
            }
            float v = fmaf(x[(size_t)r * ldx + c], sc, sh);
            x[(size_t)r * ldx + c] = v;
            if constexpr (WB) xb[(size_t)r * ldxb + c] = f2bf(v);
            psum += v;
        }
        atomicAdd(&pool[(size_t)curg * XS_COLS + poff + c], psum);
    } else {
        const int c = tid & 63;
        const int rsub = tid >> 6;
        const int r0 = blockIdx.x * 16;
        const float sc = ss[c], sh = ss[OF + c];
        float psum = 0.f;
        int curg = batch[r0 + rsub];
#pragma unroll
        for (int i = 0; i < 4; ++i) {
            int r = r0 + rsub + i * 4;
            int g = batch[r];
            if (g != curg) {
                atomicAdd(&pool[(size_t)curg * XS_COLS + poff + c], psum);
                psum = 0.f; curg = g;
            }
            float v = fmaf(x[(size_t)r * ldx + c], sc, sh);
            x[(size_t)r * ldx + c] = v;
            if constexpr (WB) xb[(size_t)r * ldxb + c] = f2bf(v);
            psum += v;
        }
        atomicAdd(&pool[(size_t)curg * XS_COLS + poff + c], psum);
    }
}

extern "C" void kernel_launch(void* const* d_in, const int* in_sizes, int n_in,
                              void* d_out, int out_size, void* d_ws, size_t ws_size,
                              hipStream_t stream)
{
    const float* x     = (const float*)d_in[0];
    const int*   ei    = (const int*)d_in[1];
    const int*   batch = (const int*)d_in[2];
    const float* W[3]    = {(const float*)d_in[3],  (const float*)d_in[9],  (const float*)d_in[15]};
    const float* asrc[3] = {(const float*)d_in[4],  (const float*)d_in[10], (const float*)d_in[16]};
    const float* adst[3] = {(const float*)d_in[5],  (const float*)d_in[11], (const float*)d_in[17]};
    const float* bia[3]  = {(const float*)d_in[6],  (const float*)d_in[12], (const float*)d_in[18]};
    const float* gam[3]  = {(const float*)d_in[7],  (const float*)d_in[13], (const float*)d_in[19]};
    const float* bet[3]  = {(const float*)d_in[8],  (const float*)d_in[14], (const float*)d_in[20]};

    char* wp = (char*)d_ws;
    auto alloc = [&](size_t bytes) -> void* {
        void* p = (void*)wp;
        wp += (bytes + 255) & ~(size_t)255;
        return p;
    };
    ushort* hbf   = (ushort*)alloc((size_t)N_NODES * 256 * 2);
    ushort* Abf0  = (ushort*)alloc((size_t)M_PAD * 128 * 2);
    ushort* AbfA  = (ushort*)alloc((size_t)M_PAD * 256 * 2);
    float*  a_s   = (float*)alloc((size_t)N_NODES * 4 * 4);
    float*  a_d   = (float*)alloc((size_t)N_NODES * 4 * 4);
    int*    counts = (int*)alloc((size_t)N_NODES * 4);
    int*    offs   = (int*)alloc((size_t)(N_NODES + 1) * 4);
    int*    cursor = (int*)alloc((size_t)N_NODES * 4);
    int*    incl   = (int*)alloc((size_t)N_NODES * 4);
    int*    bsums  = (int*)alloc(1024);
    int*    ssrc   = (int*)alloc((size_t)E_TOT * 4);
    float*  bnpart = (float*)alloc((size_t)256 * 2 * 256 * 4);
    float*  bnss   = (float*)alloc(2 * 256 * 4);
    ushort* Wt0    = (ushort*)alloc(256 * 128 * 2);
    ushort* Wt1    = (ushort*)alloc(256 * 256 * 2);
    ushort* Wt2    = (ushort*)alloc(64 * 256 * 2);

    float* pool = (float*)d_out;                    // [128, 576]
    float* xs   = pool + (size_t)NGRAPH * XS_COLS;  // [50000, 576]

    // ---- setup ----
    hipMemsetAsync(counts, 0, (size_t)N_NODES * 4, stream);
    hipMemsetAsync(pool, 0, (size_t)NGRAPH * XS_COLS * 4, stream);
    edge_count<<<ceil_div(E_TOT, 256), 256, 0, stream>>>(ei, counts);
    const int NSB = ceil_div(N_NODES, 256);
    scan_block<<<NSB, 256, 0, stream>>>(counts, N_NODES, incl, bsums);
    scan_sums<<<1, 256, 0, stream>>>(bsums, NSB);
    scan_final<<<NSB, 256, 0, stream>>>(incl, counts, bsums, N_NODES, offs, cursor);
    edge_scatter<<<ceil_div(E_TOT, 256), 256, 0, stream>>>(ei, cursor, ssrc);
    const int PREP_ITEMS = N_NODES * 128 / 4 + 256 * 128 + 256 * 256 + 64 * 256;
    prep_all<<<ceil_div(PREP_ITEMS, 256), 256, 0, stream>>>(x, W[0], W[1], W[2], Abf0, Wt0, Wt1, Wt2);

    const int NW = ceil_div(N_NODES, 4);
    const int NMB = ceil_div(N_NODES, 128);
    const int NBA = N_NODES / 16;   // 3125, exact

    // ---------------- layer 0: 128 -> 4x64 concat (256) ----------------
    {
        gemm_bf16_w<<<NMB, 512, 0, stream>>>(Abf0, 128, Wt0, 128, hbf, N_NODES, 128,
                                             asrc[0], adst[0], a_s, a_d);
        gat_fused<4, 64><<<NW, 256, 0, stream>>>(offs, ssrc, a_s, a_d, hbf, bia[0], xs + 0, XS_COLS);
        bn_stats<256><<<256, 256, 0, stream>>>(xs + 0, XS_COLS, bnpart);
        bn_finalize<256><<<1, 256, 0, stream>>>(bnpart, gam[0], bet[0], bnss);
        bn_apply_pool<256, true><<<NBA, 256, 0, stream>>>(xs + 0, XS_COLS, bnss, AbfA, 256,
                                                          batch, pool, 0);
    }
    // ---------------- layer 1: 256 -> 4x64 concat (256) ----------------
    {
        gemm_bf16_w<<<NMB, 512, 0, stream>>>(AbfA, 256, Wt1, 256, hbf, N_NODES, 256,
                                             asrc[1], adst[1], a_s, a_d);
        gat_fused<4, 64><<<NW, 256, 0, stream>>>(offs, ssrc, a_s, a_d, hbf, bia[1], xs + 256, XS_COLS);
        bn_stats<256><<<256, 256, 0, stream>>>(xs + 256, XS_COLS, bnpart);
        bn_finalize<256><<<1, 256, 0, stream>>>(bnpart, gam[1], bet[1], bnss);
        bn_apply_pool<256, true><<<NBA, 256, 0, stream>>>(xs + 256, XS_COLS, bnss, AbfA, 256,
                                                          batch, pool, 256);
    }
    // ---------------- layer 2: 256 -> 1x64 ----------------
    {
        dim3 grid(NMB, 1);
        gemm_bf16<128, 64, 64, 1><<<grid, 256, 0, stream>>>(AbfA, 256, Wt2, 256, hbf, 64, N_NODES, 256,
                                                            asrc[2], adst[2], a_s, a_d);
        gat_fused<1, 64><<<NW, 256, 0, stream>>>(offs, ssrc, a_s, a_d, hbf, bia[2], xs + 512, XS_COLS);
        bn_stats<64><<<256, 256, 0, stream>>>(xs + 512, XS_COLS, bnpart);
        bn_finalize<64><<<1, 64, 0, stream>>>(bnpart, gam[2], bet[2], bnss);
        bn_apply_pool<64, false><<<NBA, 256, 0, stream>>>(xs + 512, XS_COLS, bnss, nullptr, 0,
                                                          batch, pool, 512);
    }
}

// Round 7
// 532.818 us; speedup vs baseline: 2.1954x; 1.0413x over previous
//
#include <hip/hip_runtime.h>
#include <math.h>

#define N_NODES 50000
#define NUM_E   800000
#define E_TOT   (NUM_E + N_NODES)   // 850000 (self loops appended)
#define M_PAD   50048               // N_NODES rounded up to 128
#define NGRAPH  128
#define XS_COLS 576
#define EPS_BN  1e-5f

static inline int ceil_div(int a, int b) { return (a + b - 1) / b; }

typedef __attribute__((ext_vector_type(8))) short short8;
typedef __attribute__((ext_vector_type(4))) float f32x4;

__device__ __forceinline__ float bf2f(ushort u) {
    union { unsigned int i; float f; } v; v.i = ((unsigned int)u) << 16; return v.f;
}
__device__ __forceinline__ ushort f2bf(float f) {
    union { float f; unsigned int i; } v; v.f = f;
    unsigned int r = v.i + 0x7FFF + ((v.i >> 16) & 1);
    return (ushort)(r >> 16);
}
__device__ __forceinline__ float lrelu(float l) { return l > 0.f ? l : 0.2f * l; }

// ---------------- prep: 3 weight transposes (x conversion folded into GEMM0) ----------------
__global__ __launch_bounds__(256)
void prep_w(const float* __restrict__ W0, const float* __restrict__ W1,
            const float* __restrict__ W2,
            ushort* __restrict__ Wt0, ushort* __restrict__ Wt1, ushort* __restrict__ Wt2)
{
    int j = blockIdx.x * 256 + threadIdx.x;
    if (j < 256 * 128) { Wt0[j] = f2bf(W0[(size_t)(j % 128) * 256 + (j / 128)]); return; }
    j -= 256 * 128;
    if (j < 256 * 256) { Wt1[j] = f2bf(W1[(size_t)(j % 256) * 256 + (j / 256)]); return; }
    j -= 256 * 256;
    if (j < 64 * 256)  { Wt2[j] = f2bf(W2[(size_t)(j % 256) * 64 + (j / 256)]); }
}

// ---------------- wide bf16 MFMA GEMM (BM=128, BN=256=all cols, 8 waves) ----------------
// C[M x 256](bf16) = A[M x K] @ Bt^T; A fp32 (AF32, converted in staging) or bf16.
// Fused attention-coefficient epilogue for all H=4 heads (head = col/64).
template<bool AF32>
__global__ __launch_bounds__(512)
void gemm_bf16_w(const void* __restrict__ Av, int lda,
                 const ushort* __restrict__ Bt, int ldb,
                 ushort* __restrict__ C, int M, int K,
                 const float* __restrict__ asrc, const float* __restrict__ adst,
                 float* __restrict__ a_s, float* __restrict__ a_d)
{
    __shared__ __align__(16) ushort As[128][64 + 8];
    __shared__ __align__(16) ushort Bs[256][64 + 8];
    const int tid = threadIdx.x;
    const int lane = tid & 63;
    const int w = tid >> 6;            // 8 waves: rows w*16 .. w*16+15
    const int m0 = blockIdx.x * 128;

    f32x4 acc[16] = {};

    for (int k0 = 0; k0 < K; k0 += 64) {
        // stage A: 128x64 = 1024 short8 chunks, 2 per thread
#pragma unroll
        for (int j = 0; j < 2; ++j) {
            int c = tid + j * 512;
            int r = c >> 3, cc = (c & 7) * 8;
            if constexpr (AF32) {
                const float* Af = (const float*)Av;
                int m = m0 + r; if (m >= M) m = M - 1;   // clamp: avoid OOB on fp32 input
                float4 v0 = *reinterpret_cast<const float4*>(Af + (size_t)m * lda + k0 + cc);
                float4 v1 = *reinterpret_cast<const float4*>(Af + (size_t)m * lda + k0 + cc + 4);
                short8 v = {(short)f2bf(v0.x), (short)f2bf(v0.y), (short)f2bf(v0.z), (short)f2bf(v0.w),
                            (short)f2bf(v1.x), (short)f2bf(v1.y), (short)f2bf(v1.z), (short)f2bf(v1.w)};
                *reinterpret_cast<short8*>(&As[r][cc]) = v;
            } else {
                const ushort* Ab = (const ushort*)Av;
                short8 v = *reinterpret_cast<const short8*>(Ab + (size_t)(m0 + r) * lda + k0 + cc);
                *reinterpret_cast<short8*>(&As[r][cc]) = v;
            }
        }
        // stage B: 256x64 = 2048 chunks, 4 per thread
#pragma unroll
        for (int j = 0; j < 4; ++j) {
            int c = tid + j * 512;
            int r = c >> 3, cc = (c & 7) * 8;
            short8 v = *reinterpret_cast<const short8*>(Bt + (size_t)r * ldb + k0 + cc);
            *reinterpret_cast<short8*>(&Bs[r][cc]) = v;
        }
        __syncthreads();
#pragma unroll
        for (int kc = 0; kc < 64; kc += 32) {
            short8 a = *reinterpret_cast<const short8*>(&As[w * 16 + (lane & 15)][kc + (lane >> 4) * 8]);
#pragma unroll
            for (int nf = 0; nf < 16; ++nf) {
                short8 b = *reinterpret_cast<const short8*>(&Bs[nf * 16 + (lane & 15)][kc + (lane >> 4) * 8]);
                acc[nf] = __builtin_amdgcn_mfma_f32_16x16x32_bf16(a, b, acc[nf], 0, 0, 0);
            }
        }
        __syncthreads();
    }

    // C write: row = m0 + w*16 + (lane>>4)*4 + r ; col = nf*16 + (lane&15)
    const int mbase = m0 + w * 16 + (lane >> 4) * 4;
#pragma unroll
    for (int r = 0; r < 4; ++r) {
        int m = mbase + r;
        if (m < M) {
#pragma unroll
            for (int nf = 0; nf < 16; ++nf)
                C[(size_t)m * 256 + nf * 16 + (lane & 15)] = f2bf(acc[nf][r]);
        }
    }

    // attention-coefficient epilogue: head h covers nf = 4h..4h+3
    float asl[16], adl[16];
#pragma unroll
    for (int nf = 0; nf < 16; ++nf) {
        int col = nf * 16 + (lane & 15);
        asl[nf] = asrc[col];
        adl[nf] = adst[col];
    }
#pragma unroll
    for (int r = 0; r < 4; ++r) {
        float ps[4] = {0.f, 0.f, 0.f, 0.f};
        float pd[4] = {0.f, 0.f, 0.f, 0.f};
#pragma unroll
        for (int nf = 0; nf < 16; ++nf) {
            int h = nf >> 2;
            ps[h] = fmaf(acc[nf][r], asl[nf], ps[h]);
            pd[h] = fmaf(acc[nf][r], adl[nf], pd[h]);
        }
#pragma unroll
        for (int h = 0; h < 4; ++h) {
#pragma unroll
            for (int o = 1; o < 16; o <<= 1) {
                ps[h] += __shfl_xor(ps[h], o, 64);
                pd[h] += __shfl_xor(pd[h], o, 64);
            }
        }
        int m = mbase + r;
        if ((lane & 15) == 0 && m < M) {
#pragma unroll
            for (int h = 0; h < 4; ++h) {
                a_s[(size_t)m * 4 + h] = ps[h];
                a_d[(size_t)m * 4 + h] = pd[h];
            }
        }
    }
}

// ---------------- narrow GEMM for layer 2 (BN=64, H=1 epilogue) ----------------
template<int BM, int BN, int BK, int H>
__global__ __launch_bounds__(256)
void gemm_bf16(const ushort* __restrict__ A, int lda,
               const ushort* __restrict__ Bt, int ldb,
               ushort* __restrict__ C, int ldc, int M, int K,
               const float* __restrict__ asrc, const float* __restrict__ adst,
               float* __restrict__ a_s, float* __restrict__ a_d)
{
    static_assert(BM == 128 && BN == 64 && BK == 64, "tuned variant");
    __shared__ __align__(16) ushort As[BM][BK + 8];
    __shared__ __align__(16) ushort Bs[BN][BK + 8];
    const int tid = threadIdx.x;
    const int lane = tid & 63;
    const int w = tid >> 6;
    const int m0 = blockIdx.x * BM;
    const int n0 = blockIdx.y * BN;

    f32x4 acc[2][4] = {};

    for (int k0 = 0; k0 < K; k0 += BK) {
#pragma unroll
        for (int j = 0; j < 4; ++j) {
            int c = tid + j * 256;
            int r = c >> 3, cc = (c & 7) * 8;
            short8 v = *reinterpret_cast<const short8*>(A + (size_t)(m0 + r) * lda + k0 + cc);
            *reinterpret_cast<short8*>(&As[r][cc]) = v;
        }
#pragma unroll
        for (int j = 0; j < 2; ++j) {
            int c = tid + j * 256;
            int r = c >> 3, cc = (c & 7) * 8;
            short8 v = *reinterpret_cast<const short8*>(Bt + (size_t)(n0 + r) * ldb + k0 + cc);
            *reinterpret_cast<short8*>(&Bs[r][cc]) = v;
        }
        __syncthreads();
#pragma unroll
        for (int kc = 0; kc < BK; kc += 32) {
            short8 a[2], b[4];
#pragma unroll
            for (int mf = 0; mf < 2; ++mf)
                a[mf] = *reinterpret_cast<const short8*>(&As[w * 32 + mf * 16 + (lane & 15)][kc + (lane >> 4) * 8]);
#pragma unroll
            for (int nf = 0; nf < 4; ++nf)
                b[nf] = *reinterpret_cast<const short8*>(&Bs[nf * 16 + (lane & 15)][kc + (lane >> 4) * 8]);
#pragma unroll
            for (int mf = 0; mf < 2; ++mf)
#pragma unroll
                for (int nf = 0; nf < 4; ++nf)
                    acc[mf][nf] = __builtin_amdgcn_mfma_f32_16x16x32_bf16(a[mf], b[nf], acc[mf][nf], 0, 0, 0);
        }
        __syncthreads();
    }

#pragma unroll
    for (int mf = 0; mf < 2; ++mf) {
        int mbase = m0 + w * 32 + mf * 16 + (lane >> 4) * 4;
#pragma unroll
        for (int r = 0; r < 4; ++r) {
            int m = mbase + r;
            if (m < M) {
#pragma unroll
                for (int nf = 0; nf < 4; ++nf)
                    C[(size_t)m * ldc + n0 + nf * 16 + (lane & 15)] = f2bf(acc[mf][nf][r]);
            }
        }
    }

    const int hd = blockIdx.y;
    float asl[4], adl[4];
#pragma unroll
    for (int nf = 0; nf < 4; ++nf) {
        int col = n0 + nf * 16 + (lane & 15);
        asl[nf] = asrc[col];
        adl[nf] = adst[col];
    }
#pragma unroll
    for (int mf = 0; mf < 2; ++mf) {
#pragma unroll
        for (int r = 0; r < 4; ++r) {
            float ps = 0.f, pd = 0.f;
#pragma unroll
            for (int nf = 0; nf < 4; ++nf) {
                ps = fmaf(acc[mf][nf][r], asl[nf], ps);
                pd = fmaf(acc[mf][nf][r], adl[nf], pd);
            }
#pragma unroll
            for (int o = 1; o < 16; o <<= 1) {
                ps += __shfl_xor(ps, o, 64);
                pd += __shfl_xor(pd, o, 64);
            }
            int m = m0 + w * 32 + mf * 16 + (lane >> 4) * 4 + r;
            if ((lane & 15) == 0 && m < M) {
                a_s[(size_t)m * H + hd] = ps;
                a_d[(size_t)m * H + hd] = pd;
            }
        }
    }
}

// ---------------- fused softmax + weighted gather: 2 dst per wave, 32 lanes each ----------------
// Per-lane V = H*C/32 channels (16B ushort8 loads for H=4) -> half the VMEM instructions.
template<int H, int C>
__global__ __launch_bounds__(256)
void gat_fused2(const int* __restrict__ offs, const int* __restrict__ ssrc,
                const float* __restrict__ a_s, const float* __restrict__ a_d,
                const ushort* __restrict__ hf, const float* __restrict__ bias,
                float* __restrict__ out, int ldo)
{
    constexpr int V = (H * C) / 32;   // 8 (H=4) or 2 (H=1)
    __shared__ float alsh[4][2][64 * H];
    __shared__ int   ssh[4][2][64];
    const int tid = threadIdx.x;
    const int lane = tid & 63;
    const int wv = tid >> 6;
    const int half = lane >> 5;
    const int ll = lane & 31;
    const int dst = blockIdx.x * 8 + wv * 2 + half;
    if (dst >= N_NODES) return;
    const int e0 = offs[dst], e1 = offs[dst + 1];
    const int deg = e1 - e0;
    const int hd = (ll * V) / C;      // H=4: ll>>3 ; H=1: 0

    float ad[H];
    if constexpr (H == 4) {
        float4 v = *reinterpret_cast<const float4*>(a_d + (size_t)dst * 4);
        ad[0] = v.x; ad[1] = v.y; ad[2] = v.z; ad[3] = v.w;
    } else ad[0] = a_d[dst];

    float acc[V];
#pragma unroll
    for (int k = 0; k < V; ++k) acc[k] = 0.f;

    if (deg <= 64) {
        // ---- phase 1: up to 2 edges per lane (32-lane group); alpha+src cached in LDS ----
        const bool a0 = ll < deg;
        const bool a1 = 32 + ll < deg;
        const int s0 = ssrc[e0 + (a0 ? ll : 0)];
        const int s1 = ssrc[e0 + (a1 ? 32 + ll : 0)];
        float l0[H], l1[H], mx[H], sm[H];
        if constexpr (H == 4) {
            float4 v0 = *reinterpret_cast<const float4*>(a_s + (size_t)s0 * 4);
            float4 v1 = *reinterpret_cast<const float4*>(a_s + (size_t)s1 * 4);
            l0[0] = lrelu(v0.x + ad[0]); l0[1] = lrelu(v0.y + ad[1]);
            l0[2] = lrelu(v0.z + ad[2]); l0[3] = lrelu(v0.w + ad[3]);
            l1[0] = lrelu(v1.x + ad[0]); l1[1] = lrelu(v1.y + ad[1]);
            l1[2] = lrelu(v1.z + ad[2]); l1[3] = lrelu(v1.w + ad[3]);
        } else {
            l0[0] = lrelu(a_s[s0] + ad[0]);
            l1[0] = lrelu(a_s[s1] + ad[0]);
        }
#pragma unroll
        for (int t = 0; t < H; ++t) {
            float m = a0 ? l0[t] : -INFINITY;
            if (a1) m = fmaxf(m, l1[t]);
#pragma unroll
            for (int o = 1; o < 32; o <<= 1) m = fmaxf(m, __shfl_xor(m, o, 64));
            mx[t] = m;
            float s = (a0 ? __expf(l0[t] - m) : 0.f) + (a1 ? __expf(l1[t] - m) : 0.f);
#pragma unroll
            for (int o = 1; o < 32; o <<= 1) s += __shfl_xor(s, o, 64);
            sm[t] = s;
        }
        float inv[H];
#pragma unroll
        for (int t = 0; t < H; ++t) inv[t] = 1.f / (sm[t] + 1e-16f);
        if (a0) {
            ssh[wv][half][ll] = s0;
            if constexpr (H == 4) {
                float4 av = {__expf(l0[0] - mx[0]) * inv[0], __expf(l0[1] - mx[1]) * inv[1],
                             __expf(l0[2] - mx[2]) * inv[2], __expf(l0[3] - mx[3]) * inv[3]};
                *reinterpret_cast<float4*>(&alsh[wv][half][ll * 4]) = av;
            } else alsh[wv][half][ll] = __expf(l0[0] - mx[0]) * inv[0];
        }
        if (a1) {
            ssh[wv][half][32 + ll] = s1;
            if constexpr (H == 4) {
                float4 av = {__expf(l1[0] - mx[0]) * inv[0], __expf(l1[1] - mx[1]) * inv[1],
                             __expf(l1[2] - mx[2]) * inv[2], __expf(l1[3] - mx[3]) * inv[3]};
                *reinterpret_cast<float4*>(&alsh[wv][half][(32 + ll) * 4]) = av;
            } else alsh[wv][half][32 + ll] = __expf(l1[0] - mx[0]) * inv[0];
        }
        // same wave produces & consumes its own LDS slots: no barrier needed

        // ---- phase 2: serial gather, 4-wide, 16B loads (H=4) ----
        const ushort* hlane = hf + (size_t)ll * V;
        int j = 0;
        for (; j + 3 < deg; j += 4) {
            int sj[4]; float al[4];
#pragma unroll
            for (int k = 0; k < 4; ++k) {
                sj[k] = ssh[wv][half][j + k];
                al[k] = alsh[wv][half][(j + k) * H + hd];
            }
            if constexpr (V == 8) {
                short8 hv[4];
#pragma unroll
                for (int k = 0; k < 4; ++k)
                    hv[k] = *reinterpret_cast<const short8*>(hlane + (size_t)sj[k] * (H * C));
#pragma unroll
                for (int k = 0; k < 4; ++k)
#pragma unroll
                    for (int i = 0; i < 8; ++i)
                        acc[i] = fmaf(al[k], bf2f((ushort)hv[k][i]), acc[i]);
            } else {
                ushort2 hv[4];
#pragma unroll
                for (int k = 0; k < 4; ++k)
                    hv[k] = *reinterpret_cast<const ushort2*>(hlane + (size_t)sj[k] * (H * C));
#pragma unroll
                for (int k = 0; k < 4; ++k) {
                    acc[0] = fmaf(al[k], bf2f(hv[k].x), acc[0]);
                    acc[1] = fmaf(al[k], bf2f(hv[k].y), acc[1]);
                }
            }
        }
        for (; j < deg; ++j) {
            int sj = ssh[wv][half][j];
            float al = alsh[wv][half][j * H + hd];
            if constexpr (V == 8) {
                short8 hv = *reinterpret_cast<const short8*>(hlane + (size_t)sj * (H * C));
#pragma unroll
                for (int i = 0; i < 8; ++i)
                    acc[i] = fmaf(al, bf2f((ushort)hv[i]), acc[i]);
            } else {
                ushort2 hv = *reinterpret_cast<const ushort2*>(hlane + (size_t)sj * (H * C));
                acc[0] = fmaf(al, bf2f(hv.x), acc[0]);
                acc[1] = fmaf(al, bf2f(hv.y), acc[1]);
            }
        }
    } else {
        // ---- fallback (deg > 64, rare): 32-lane strided two-pass + recompute ----
        float mx[H], sm[H];
#pragma unroll
        for (int t = 0; t < H; ++t) mx[t] = -INFINITY;
        for (int e = e0 + ll; e < e1; e += 32) {
            int s = ssrc[e];
            float asv[H];
            if constexpr (H == 4) {
                float4 v = *reinterpret_cast<const float4*>(a_s + (size_t)s * 4);
                asv[0] = v.x; asv[1] = v.y; asv[2] = v.z; asv[3] = v.w;
            } else asv[0] = a_s[s];
#pragma unroll
            for (int t = 0; t < H; ++t) mx[t] = fmaxf(mx[t], lrelu(asv[t] + ad[t]));
        }
#pragma unroll
        for (int t = 0; t < H; ++t)
#pragma unroll
            for (int o = 1; o < 32; o <<= 1) mx[t] = fmaxf(mx[t], __shfl_xor(mx[t], o, 64));
#pragma unroll
        for (int t = 0; t < H; ++t) sm[t] = 0.f;
        for (int e = e0 + ll; e < e1; e += 32) {
            int s = ssrc[e];
            float asv[H];
            if constexpr (H == 4) {
                float4 v = *reinterpret_cast<const float4*>(a_s + (size_t)s * 4);
                asv[0] = v.x; asv[1] = v.y; asv[2] = v.z; asv[3] = v.w;
            } else asv[0] = a_s[s];
#pragma unroll
            for (int t = 0; t < H; ++t) sm[t] += __expf(lrelu(asv[t] + ad[t]) - mx[t]);
        }
#pragma unroll
        for (int t = 0; t < H; ++t)
#pragma unroll
            for (int o = 1; o < 32; o <<= 1) sm[t] += __shfl_xor(sm[t], o, 64);

        float mxl = mx[0], sml = sm[0], adl = ad[0];
#pragma unroll
        for (int t = 1; t < H; ++t) {
            mxl = (hd == t) ? mx[t] : mxl;
            sml = (hd == t) ? sm[t] : sml;
            adl = (hd == t) ? ad[t] : adl;
        }
        const float invl = 1.f / (sml + 1e-16f);
        const ushort* hlane = hf + (size_t)ll * V;
        for (int e = e0; e < e1; ++e) {
            int s0 = ssrc[e];
            float al0 = __expf(lrelu(a_s[(size_t)s0 * H + hd] + adl) - mxl) * invl;
            if constexpr (V == 8) {
                short8 hv = *reinterpret_cast<const short8*>(hlane + (size_t)s0 * (H * C));
#pragma unroll
                for (int i = 0; i < 8; ++i)
                    acc[i] = fmaf(al0, bf2f((ushort)hv[i]), acc[i]);
            } else {
                ushort2 hv = *reinterpret_cast<const ushort2*>(hlane + (size_t)s0 * (H * C));
                acc[0] = fmaf(al0, bf2f(hv.x), acc[0]);
                acc[1] = fmaf(al0, bf2f(hv.y), acc[1]);
            }
        }
    }

    // epilogue: + bias, ELU, store
    float res[V];
#pragma unroll
    for (int i = 0; i < V; ++i) {
        float t = acc[i] + bias[ll * V + i];
        res[i] = t > 0.f ? t : (expf(t) - 1.f);
    }
    if constexpr (V == 8) {
        float4 v0 = {res[0], res[1], res[2], res[3]};
        float4 v1 = {res[4], res[5], res[6], res[7]};
        *reinterpret_cast<float4*>(&out[(size_t)dst * ldo + ll * 8 + 0]) = v0;
        *reinterpret_cast<float4*>(&out[(size_t)dst * ldo + ll * 8 + 4]) = v1;
    } else {
        float2 v = {res[0], res[1]};
        *reinterpret_cast<float2*>(&out[(size_t)dst * ldo + ll * 2]) = v;
    }
}

// ---------------- edge bucketing ----------------
__global__ void edge_count(const int* __restrict__ ei, int* __restrict__ counts)
{
    int i = blockIdx.x * blockDim.x + threadIdx.x;
    if (i >= E_TOT) return;
    int dst = (i < NUM_E) ? ei[NUM_E + i] : (i - NUM_E);
    atomicAdd(&counts[dst], 1);
}

__global__ void edge_scatter(const int* __restrict__ ei, int* __restrict__ cursor,
                             int* __restrict__ ssrc)
{
    int i = blockIdx.x * blockDim.x + threadIdx.x;
    if (i >= E_TOT) return;
    int src, dst;
    if (i < NUM_E) { src = ei[i]; dst = ei[NUM_E + i]; }
    else           { src = dst = i - NUM_E; }
    int pos = atomicAdd(&cursor[dst], 1);
    ssrc[pos] = src;
}

// ---------------- generic scan (blocks of 256) ----------------
__global__ void scan_block(const int* __restrict__ in, int n,
                           int* __restrict__ incl, int* __restrict__ bsum)
{
    __shared__ int sh[256];
    int tid = threadIdx.x;
    int i = blockIdx.x * 256 + tid;
    int v = (i < n) ? in[i] : 0;
    sh[tid] = v;
    __syncthreads();
    for (int o = 1; o < 256; o <<= 1) {
        int t = (tid >= o) ? sh[tid - o] : 0;
        __syncthreads();
        sh[tid] += t;
        __syncthreads();
    }
    if (i < n) incl[i] = sh[tid];
    if (tid == 255) bsum[blockIdx.x] = sh[255];
}

__global__ void scan_sums(int* __restrict__ bsum, int nb)
{
    __shared__ int sh[256];
    int tid = threadIdx.x;
    int v = (tid < nb) ? bsum[tid] : 0;
    sh[tid] = v;
    __syncthreads();
    for (int o = 1; o < 256; o <<= 1) {
        int t = (tid >= o) ? sh[tid - o] : 0;
        __syncthreads();
        sh[tid] += t;
        __syncthreads();
    }
    if (tid < nb) bsum[tid] = sh[tid] - v;
}

__global__ void scan_final(const int* __restrict__ incl, const int* __restrict__ in,
                           const int* __restrict__ bsum, int n,
                           int* __restrict__ offs, int* __restrict__ cursor)
{
    int i = blockIdx.x * 256 + threadIdx.x;
    if (i >= n) return;
    int excl = incl[i] - in[i] + bsum[i / 256];
    offs[i] = excl;
    cursor[i] = excl;
    if (i == n - 1) offs[n] = incl[i] + bsum[i / 256];
}

// ---------------- BatchNorm: per-block partials (no atomics, no memset) ----------------
template<int OF>
__global__ __launch_bounds__(256)
void bn_stats(const float* __restrict__ x, int ldx, float* __restrict__ part)
{
    constexpr int RP = 256 / OF;
    const int tid = threadIdx.x;
    const int col = tid % OF;
    const int rsub = tid / OF;
    float s = 0.f, s2 = 0.f;
    for (int r = blockIdx.x * RP + rsub; r < N_NODES; r += gridDim.x * RP) {
        float v = x[(size_t)r * ldx + col];
        s += v;
        s2 = fmaf(v, v, s2);
    }
    if constexpr (RP > 1) {
        __shared__ float sh[2][256];
        sh[0][tid] = s; sh[1][tid] = s2;
        __syncthreads();
        if (rsub == 0) {
#pragma unroll
            for (int j = 1; j < RP; ++j) { s += sh[0][col + j * OF]; s2 += sh[1][col + j * OF]; }
        }
    }
    if (rsub == 0) {
        part[(size_t)blockIdx.x * 2 * OF + col] = s;
        part[(size_t)blockIdx.x * 2 * OF + OF + col] = s2;
    }
}

template<int OF>
__global__ void bn_finalize(const float* __restrict__ part, const float* __restrict__ gamma,
                            const float* __restrict__ beta, float* __restrict__ ss)
{
    int c = threadIdx.x;
    if (c >= OF) return;
    float s = 0.f, s2 = 0.f;
    for (int b = 0; b < 256; ++b) {
        s += part[(size_t)b * 2 * OF + c];
        s2 += part[(size_t)b * 2 * OF + OF + c];
    }
    float mean = s / (float)N_NODES;
    float var = s2 / (float)N_NODES - mean * mean;
    float inv = rsqrtf(var + EPS_BN);
    float sc = inv * gamma[c];
    ss[c] = sc;
    ss[OF + c] = beta[c] - mean * sc;
}

// ---------------- BN apply + fused graph pooling (batch sorted -> running sums) ----------------
template<int OF, bool WB>
__global__ __launch_bounds__(256)
void bn_apply_pool(float* __restrict__ x, int ldx, const float* __restrict__ ss,
                   ushort* __restrict__ xb, int ldxb,
                   const int* __restrict__ batch, float* __restrict__ pool, int poff)
{
    const int tid = threadIdx.x;
    if constexpr (OF == 256) {
        const int c = tid;
        const int r0 = blockIdx.x * 16;
        const float sc = ss[c], sh = ss[OF + c];
        float psum = 0.f;
        int curg = batch[r0];
#pragma unroll
        for (int i = 0; i < 16; ++i) {
            int r = r0 + i;
            int g = batch[r];
            if (g != curg) {
                atomicAdd(&pool[(size_t)curg * XS_COLS + poff + c], psum);
                psum = 0.f; curg = g;
            }
            float v = fmaf(x[(size_t)r * ldx + c], sc, sh);
            x[(size_t)r * ldx + c] = v;
            if constexpr (WB) xb[(size_t)r * ldxb + c] = f2bf(v);
            psum += v;
        }
        atomicAdd(&pool[(size_t)curg * XS_COLS + poff + c], psum);
    } else {
        const int c = tid & 63;
        const int rsub = tid >> 6;
        const int r0 = blockIdx.x * 16;
        const float sc = ss[c], sh = ss[OF + c];
        float psum = 0.f;
        int curg = batch[r0 + rsub];
#pragma unroll
        for (int i = 0; i < 4; ++i) {
            int r = r0 + rsub + i * 4;
            int g = batch[r];
            if (g != curg) {
                atomicAdd(&pool[(size_t)curg * XS_COLS + poff + c], psum);
                psum = 0.f; curg = g;
            }
            float v = fmaf(x[(size_t)r * ldx + c], sc, sh);
            x[(size_t)r * ldx + c] = v;
            if constexpr (WB) xb[(size_t)r * ldxb + c] = f2bf(v);
            psum += v;
        }
        atomicAdd(&pool[(size_t)curg * XS_COLS + poff + c], psum);
    }
}

extern "C" void kernel_launch(void* const* d_in, const int* in_sizes, int n_in,
                              void* d_out, int out_size, void* d_ws, size_t ws_size,
                              hipStream_t stream)
{
    const float* x     = (const float*)d_in[0];
    const int*   ei    = (const int*)d_in[1];
    const int*   batch = (const int*)d_in[2];
    const float* W[3]    = {(const float*)d_in[3],  (const float*)d_in[9],  (const float*)d_in[15]};
    const float* asrc[3] = {(const float*)d_in[4],  (const float*)d_in[10], (const float*)d_in[16]};
    const float* adst[3] = {(const float*)d_in[5],  (const float*)d_in[11], (const float*)d_in[17]};
    const float* bia[3]  = {(const float*)d_in[6],  (const float*)d_in[12], (const float*)d_in[18]};
    const float* gam[3]  = {(const float*)d_in[7],  (const float*)d_in[13], (const float*)d_in[19]};
    const float* bet[3]  = {(const float*)d_in[8],  (const float*)d_in[14], (const float*)d_in[20]};

    char* wp = (char*)d_ws;
    auto alloc = [&](size_t bytes) -> void* {
        void* p = (void*)wp;
        wp += (bytes + 255) & ~(size_t)255;
        return p;
    };
    ushort* hbf   = (ushort*)alloc((size_t)N_NODES * 256 * 2);
    ushort* AbfA  = (ushort*)alloc((size_t)M_PAD * 256 * 2);
    float*  a_s   = (float*)alloc((size_t)N_NODES * 4 * 4);
    float*  a_d   = (float*)alloc((size_t)N_NODES * 4 * 4);
    int*    counts = (int*)alloc((size_t)N_NODES * 4);
    int*    offs   = (int*)alloc((size_t)(N_NODES + 1) * 4);
    int*    cursor = (int*)alloc((size_t)N_NODES * 4);
    int*    incl   = (int*)alloc((size_t)N_NODES * 4);
    int*    bsums  = (int*)alloc(1024);
    int*    ssrc   = (int*)alloc((size_t)E_TOT * 4);
    float*  bnpart = (float*)alloc((size_t)256 * 2 * 256 * 4);
    float*  bnss   = (float*)alloc(2 * 256 * 4);
    ushort* Wt0    = (ushort*)alloc(256 * 128 * 2);
    ushort* Wt1    = (ushort*)alloc(256 * 256 * 2);
    ushort* Wt2    = (ushort*)alloc(64 * 256 * 2);

    float* pool = (float*)d_out;                    // [128, 576]
    float* xs   = pool + (size_t)NGRAPH * XS_COLS;  // [50000, 576]

    // ---- setup ----
    hipMemsetAsync(counts, 0, (size_t)N_NODES * 4, stream);
    hipMemsetAsync(pool, 0, (size_t)NGRAPH * XS_COLS * 4, stream);
    edge_count<<<ceil_div(E_TOT, 256), 256, 0, stream>>>(ei, counts);
    const int NSB = ceil_div(N_NODES, 256);
    scan_block<<<NSB, 256, 0, stream>>>(counts, N_NODES, incl, bsums);
    scan_sums<<<1, 256, 0, stream>>>(bsums, NSB);
    scan_final<<<NSB, 256, 0, stream>>>(incl, counts, bsums, N_NODES, offs, cursor);
    edge_scatter<<<ceil_div(E_TOT, 256), 256, 0, stream>>>(ei, cursor, ssrc);
    const int PREP_ITEMS = 256 * 128 + 256 * 256 + 64 * 256;
    prep_w<<<ceil_div(PREP_ITEMS, 256), 256, 0, stream>>>(W[0], W[1], W[2], Wt0, Wt1, Wt2);

    const int NW2 = ceil_div(N_NODES, 8);   // 6250
    const int NMB = ceil_div(N_NODES, 128);
    const int NBA = N_NODES / 16;           // 3125, exact

    // ---------------- layer 0: 128 -> 4x64 concat (256) ----------------
    {
        gemm_bf16_w<true><<<NMB, 512, 0, stream>>>(x, 128, Wt0, 128, hbf, N_NODES, 128,
                                                   asrc[0], adst[0], a_s, a_d);
        gat_fused2<4, 64><<<NW2, 256, 0, stream>>>(offs, ssrc, a_s, a_d, hbf, bia[0], xs + 0, XS_COLS);
        bn_stats<256><<<256, 256, 0, stream>>>(xs + 0, XS_COLS, bnpart);
        bn_finalize<256><<<1, 256, 0, stream>>>(bnpart, gam[0], bet[0], bnss);
        bn_apply_pool<256, true><<<NBA, 256, 0, stream>>>(xs + 0, XS_COLS, bnss, AbfA, 256,
                                                          batch, pool, 0);
    }
    // ---------------- layer 1: 256 -> 4x64 concat (256) ----------------
    {
        gemm_bf16_w<false><<<NMB, 512, 0, stream>>>(AbfA, 256, Wt1, 256, hbf, N_NODES, 256,
                                                    asrc[1], adst[1], a_s, a_d);
        gat_fused2<4, 64><<<NW2, 256, 0, stream>>>(offs, ssrc, a_s, a_d, hbf, bia[1], xs + 256, XS_COLS);
        bn_stats<256><<<256, 256, 0, stream>>>(xs + 256, XS_COLS, bnpart);
        bn_finalize<256><<<1, 256, 0, stream>>>(bnpart, gam[1], bet[1], bnss);
        bn_apply_pool<256, true><<<NBA, 256, 0, stream>>>(xs + 256, XS_COLS, bnss, AbfA, 256,
                                                          batch, pool, 256);
    }
    // ---------------- layer 2: 256 -> 1x64 ----------------
    {
        dim3 grid(NMB, 1);
        gemm_bf16<128, 64, 64, 1><<<grid, 256, 0, stream>>>(AbfA, 256, Wt2, 256, hbf, 64, N_NODES, 256,
                                                            asrc[2], adst[2], a_s, a_d);
        gat_fused2<1, 64><<<NW2, 256, 0, stream>>>(offs, ssrc, a_s, a_d, hbf, bia[2], xs + 512, XS_COLS);
        bn_stats<64><<<256, 256, 0, stream>>>(xs + 512, XS_COLS, bnpart);
        bn_finalize<64><<<1, 64, 0, stream>>>(bnpart, gam[2], bet[2], bnss);
        bn_apply_pool<64, false><<<NBA, 256, 0, stream>>>(xs + 512, XS_COLS, bnss, nullptr, 0,
                                                          batch, pool, 512);
    }
}

// Round 8
// 461.722 us; speedup vs baseline: 2.5334x; 1.1540x over previous
//
#include <hip/hip_runtime.h>
#include <math.h>

#define N_NODES 50000
#define NUM_E   800000
#define E_TOT   (NUM_E + N_NODES)   // 850000 (self loops appended)
#define M_PAD   50048               // N_NODES rounded up to 128
#define NGRAPH  128
#define XS_COLS 576
#define EPS_BN  1e-5f

static inline int ceil_div(int a, int b) { return (a + b - 1) / b; }

typedef __attribute__((ext_vector_type(8))) short short8;
typedef __attribute__((ext_vector_type(4))) float f32x4;

__device__ __forceinline__ float bf2f(ushort u) {
    union { unsigned int i; float f; } v; v.i = ((unsigned int)u) << 16; return v.f;
}
__device__ __forceinline__ ushort f2bf(float f) {
    union { float f; unsigned int i; } v; v.f = f;
    unsigned int r = v.i + 0x7FFF + ((v.i >> 16) & 1);
    return (ushort)(r >> 16);
}
__device__ __forceinline__ float lrelu(float l) { return l > 0.f ? l : 0.2f * l; }

// ---------------- prep: 3 weight transposes ----------------
__global__ __launch_bounds__(256)
void prep_w(const float* __restrict__ W0, const float* __restrict__ W1,
            const float* __restrict__ W2,
            ushort* __restrict__ Wt0, ushort* __restrict__ Wt1, ushort* __restrict__ Wt2)
{
    int j = blockIdx.x * 256 + threadIdx.x;
    if (j < 256 * 128) { Wt0[j] = f2bf(W0[(size_t)(j % 128) * 256 + (j / 128)]); return; }
    j -= 256 * 128;
    if (j < 256 * 256) { Wt1[j] = f2bf(W1[(size_t)(j % 256) * 256 + (j / 256)]); return; }
    j -= 256 * 256;
    if (j < 64 * 256)  { Wt2[j] = f2bf(W2[(size_t)(j % 256) * 64 + (j / 256)]); }
}

// ---------------- wide bf16 MFMA GEMM (BM=128, BN=256=all cols, 8 waves) ----------------
template<bool AF32>
__global__ __launch_bounds__(512)
void gemm_bf16_w(const void* __restrict__ Av, int lda,
                 const ushort* __restrict__ Bt, int ldb,
                 ushort* __restrict__ C, int M, int K,
                 const float* __restrict__ asrc, const float* __restrict__ adst,
                 float* __restrict__ a_s, float* __restrict__ a_d)
{
    __shared__ __align__(16) ushort As[128][64 + 8];
    __shared__ __align__(16) ushort Bs[256][64 + 8];
    const int tid = threadIdx.x;
    const int lane = tid & 63;
    const int w = tid >> 6;
    const int m0 = blockIdx.x * 128;

    f32x4 acc[16] = {};

    for (int k0 = 0; k0 < K; k0 += 64) {
#pragma unroll
        for (int j = 0; j < 2; ++j) {
            int c = tid + j * 512;
            int r = c >> 3, cc = (c & 7) * 8;
            if constexpr (AF32) {
                const float* Af = (const float*)Av;
                int m = m0 + r; if (m >= M) m = M - 1;
                float4 v0 = *reinterpret_cast<const float4*>(Af + (size_t)m * lda + k0 + cc);
                float4 v1 = *reinterpret_cast<const float4*>(Af + (size_t)m * lda + k0 + cc + 4);
                short8 v = {(short)f2bf(v0.x), (short)f2bf(v0.y), (short)f2bf(v0.z), (short)f2bf(v0.w),
                            (short)f2bf(v1.x), (short)f2bf(v1.y), (short)f2bf(v1.z), (short)f2bf(v1.w)};
                *reinterpret_cast<short8*>(&As[r][cc]) = v;
            } else {
                const ushort* Ab = (const ushort*)Av;
                short8 v = *reinterpret_cast<const short8*>(Ab + (size_t)(m0 + r) * lda + k0 + cc);
                *reinterpret_cast<short8*>(&As[r][cc]) = v;
            }
        }
#pragma unroll
        for (int j = 0; j < 4; ++j) {
            int c = tid + j * 512;
            int r = c >> 3, cc = (c & 7) * 8;
            short8 v = *reinterpret_cast<const short8*>(Bt + (size_t)r * ldb + k0 + cc);
            *reinterpret_cast<short8*>(&Bs[r][cc]) = v;
        }
        __syncthreads();
#pragma unroll
        for (int kc = 0; kc < 64; kc += 32) {
            short8 a = *reinterpret_cast<const short8*>(&As[w * 16 + (lane & 15)][kc + (lane >> 4) * 8]);
#pragma unroll
            for (int nf = 0; nf < 16; ++nf) {
                short8 b = *reinterpret_cast<const short8*>(&Bs[nf * 16 + (lane & 15)][kc + (lane >> 4) * 8]);
                acc[nf] = __builtin_amdgcn_mfma_f32_16x16x32_bf16(a, b, acc[nf], 0, 0, 0);
            }
        }
        __syncthreads();
    }

    const int mbase = m0 + w * 16 + (lane >> 4) * 4;
#pragma unroll
    for (int r = 0; r < 4; ++r) {
        int m = mbase + r;
        if (m < M) {
#pragma unroll
            for (int nf = 0; nf < 16; ++nf)
                C[(size_t)m * 256 + nf * 16 + (lane & 15)] = f2bf(acc[nf][r]);
        }
    }

    float asl[16], adl[16];
#pragma unroll
    for (int nf = 0; nf < 16; ++nf) {
        int col = nf * 16 + (lane & 15);
        asl[nf] = asrc[col];
        adl[nf] = adst[col];
    }
#pragma unroll
    for (int r = 0; r < 4; ++r) {
        float ps[4] = {0.f, 0.f, 0.f, 0.f};
        float pd[4] = {0.f, 0.f, 0.f, 0.f};
#pragma unroll
        for (int nf = 0; nf < 16; ++nf) {
            int h = nf >> 2;
            ps[h] = fmaf(acc[nf][r], asl[nf], ps[h]);
            pd[h] = fmaf(acc[nf][r], adl[nf], pd[h]);
        }
#pragma unroll
        for (int h = 0; h < 4; ++h) {
#pragma unroll
            for (int o = 1; o < 16; o <<= 1) {
                ps[h] += __shfl_xor(ps[h], o, 64);
                pd[h] += __shfl_xor(pd[h], o, 64);
            }
        }
        int m = mbase + r;
        if ((lane & 15) == 0 && m < M) {
#pragma unroll
            for (int h = 0; h < 4; ++h) {
                a_s[(size_t)m * 4 + h] = ps[h];
                a_d[(size_t)m * 4 + h] = pd[h];
            }
        }
    }
}

// ---------------- narrow GEMM for layer 2 (BN=64, H=1 epilogue) ----------------
template<int BM, int BN, int BK, int H>
__global__ __launch_bounds__(256)
void gemm_bf16(const ushort* __restrict__ A, int lda,
               const ushort* __restrict__ Bt, int ldb,
               ushort* __restrict__ C, int ldc, int M, int K,
               const float* __restrict__ asrc, const float* __restrict__ adst,
               float* __restrict__ a_s, float* __restrict__ a_d)
{
    static_assert(BM == 128 && BN == 64 && BK == 64, "tuned variant");
    __shared__ __align__(16) ushort As[BM][BK + 8];
    __shared__ __align__(16) ushort Bs[BN][BK + 8];
    const int tid = threadIdx.x;
    const int lane = tid & 63;
    const int w = tid >> 6;
    const int m0 = blockIdx.x * BM;
    const int n0 = blockIdx.y * BN;

    f32x4 acc[2][4] = {};

    for (int k0 = 0; k0 < K; k0 += BK) {
#pragma unroll
        for (int j = 0; j < 4; ++j) {
            int c = tid + j * 256;
            int r = c >> 3, cc = (c & 7) * 8;
            short8 v = *reinterpret_cast<const short8*>(A + (size_t)(m0 + r) * lda + k0 + cc);
            *reinterpret_cast<short8*>(&As[r][cc]) = v;
        }
#pragma unroll
        for (int j = 0; j < 2; ++j) {
            int c = tid + j * 256;
            int r = c >> 3, cc = (c & 7) * 8;
            short8 v = *reinterpret_cast<const short8*>(Bt + (size_t)(n0 + r) * ldb + k0 + cc);
            *reinterpret_cast<short8*>(&Bs[r][cc]) = v;
        }
        __syncthreads();
#pragma unroll
        for (int kc = 0; kc < BK; kc += 32) {
            short8 a[2], b[4];
#pragma unroll
            for (int mf = 0; mf < 2; ++mf)
                a[mf] = *reinterpret_cast<const short8*>(&As[w * 32 + mf * 16 + (lane & 15)][kc + (lane >> 4) * 8]);
#pragma unroll
            for (int nf = 0; nf < 4; ++nf)
                b[nf] = *reinterpret_cast<const short8*>(&Bs[nf * 16 + (lane & 15)][kc + (lane >> 4) * 8]);
#pragma unroll
            for (int mf = 0; mf < 2; ++mf)
#pragma unroll
                for (int nf = 0; nf < 4; ++nf)
                    acc[mf][nf] = __builtin_amdgcn_mfma_f32_16x16x32_bf16(a[mf], b[nf], acc[mf][nf], 0, 0, 0);
        }
        __syncthreads();
    }

#pragma unroll
    for (int mf = 0; mf < 2; ++mf) {
        int mbase = m0 + w * 32 + mf * 16 + (lane >> 4) * 4;
#pragma unroll
        for (int r = 0; r < 4; ++r) {
            int m = mbase + r;
            if (m < M) {
#pragma unroll
                for (int nf = 0; nf < 4; ++nf)
                    C[(size_t)m * ldc + n0 + nf * 16 + (lane & 15)] = f2bf(acc[mf][nf][r]);
            }
        }
    }

    const int hd = blockIdx.y;
    float asl[4], adl[4];
#pragma unroll
    for (int nf = 0; nf < 4; ++nf) {
        int col = n0 + nf * 16 + (lane & 15);
        asl[nf] = asrc[col];
        adl[nf] = adst[col];
    }
#pragma unroll
    for (int mf = 0; mf < 2; ++mf) {
#pragma unroll
        for (int r = 0; r < 4; ++r) {
            float ps = 0.f, pd = 0.f;
#pragma unroll
            for (int nf = 0; nf < 4; ++nf) {
                ps = fmaf(acc[mf][nf][r], asl[nf], ps);
                pd = fmaf(acc[mf][nf][r], adl[nf], pd);
            }
#pragma unroll
            for (int o = 1; o < 16; o <<= 1) {
                ps += __shfl_xor(ps, o, 64);
                pd += __shfl_xor(pd, o, 64);
            }
            int m = m0 + w * 32 + mf * 16 + (lane >> 4) * 4 + r;
            if ((lane & 15) == 0 && m < M) {
                a_s[(size_t)m * H + hd] = ps;
                a_d[(size_t)m * H + hd] = pd;
            }
        }
    }
}

// ---------------- fused softmax + gather + BN-stats; y out in bf16 ----------------
// 2 dst per wave (32 lanes each); 8 dst per block (grid exact: 6250*8 = 50000).
template<int H, int C>
__global__ __launch_bounds__(256)
void gat_fused2(const int* __restrict__ offs, const int* __restrict__ ssrc,
                const float* __restrict__ a_s, const float* __restrict__ a_d,
                const ushort* __restrict__ hf, const float* __restrict__ bias,
                ushort* __restrict__ ybuf, float* __restrict__ bnsum)
{
    constexpr int V = (H * C) / 32;   // 8 (H=4) or 2 (H=1)
    constexpr int OF = H * C;         // 256 or 64
    __shared__ float alsh[4][2][64 * H];
    __shared__ int   ssh[4][2][64];
    __shared__ float ysh[8][OF];
    const int tid = threadIdx.x;
    const int lane = tid & 63;
    const int wv = tid >> 6;
    const int half = lane >> 5;
    const int ll = lane & 31;
    const int dl = wv * 2 + half;           // local dst 0..7
    const int dst = blockIdx.x * 8 + dl;
    const int e0 = offs[dst], e1 = offs[dst + 1];
    const int deg = e1 - e0;
    const int hd = (ll * V) / C;

    float ad[H];
    if constexpr (H == 4) {
        float4 v = *reinterpret_cast<const float4*>(a_d + (size_t)dst * 4);
        ad[0] = v.x; ad[1] = v.y; ad[2] = v.z; ad[3] = v.w;
    } else ad[0] = a_d[dst];

    float acc[V];
#pragma unroll
    for (int k = 0; k < V; ++k) acc[k] = 0.f;

    if (deg <= 64) {
        // ---- phase 1: up to 2 edges per lane; alpha+src cached in LDS ----
        const bool a0 = ll < deg;
        const bool a1 = 32 + ll < deg;
        const int s0 = ssrc[e0 + (a0 ? ll : 0)];
        const int s1 = ssrc[e0 + (a1 ? 32 + ll : 0)];
        float l0[H], l1[H], mx[H], sm[H];
        if constexpr (H == 4) {
            float4 v0 = *reinterpret_cast<const float4*>(a_s + (size_t)s0 * 4);
            float4 v1 = *reinterpret_cast<const float4*>(a_s + (size_t)s1 * 4);
            l0[0] = lrelu(v0.x + ad[0]); l0[1] = lrelu(v0.y + ad[1]);
            l0[2] = lrelu(v0.z + ad[2]); l0[3] = lrelu(v0.w + ad[3]);
            l1[0] = lrelu(v1.x + ad[0]); l1[1] = lrelu(v1.y + ad[1]);
            l1[2] = lrelu(v1.z + ad[2]); l1[3] = lrelu(v1.w + ad[3]);
        } else {
            l0[0] = lrelu(a_s[s0] + ad[0]);
            l1[0] = lrelu(a_s[s1] + ad[0]);
        }
#pragma unroll
        for (int t = 0; t < H; ++t) {
            float m = a0 ? l0[t] : -INFINITY;
            if (a1) m = fmaxf(m, l1[t]);
#pragma unroll
            for (int o = 1; o < 32; o <<= 1) m = fmaxf(m, __shfl_xor(m, o, 64));
            mx[t] = m;
            float s = (a0 ? __expf(l0[t] - m) : 0.f) + (a1 ? __expf(l1[t] - m) : 0.f);
#pragma unroll
            for (int o = 1; o < 32; o <<= 1) s += __shfl_xor(s, o, 64);
            sm[t] = s;
        }
        float inv[H];
#pragma unroll
        for (int t = 0; t < H; ++t) inv[t] = 1.f / (sm[t] + 1e-16f);
        if (a0) {
            ssh[wv][half][ll] = s0;
            if constexpr (H == 4) {
                float4 av = {__expf(l0[0] - mx[0]) * inv[0], __expf(l0[1] - mx[1]) * inv[1],
                             __expf(l0[2] - mx[2]) * inv[2], __expf(l0[3] - mx[3]) * inv[3]};
                *reinterpret_cast<float4*>(&alsh[wv][half][ll * 4]) = av;
            } else alsh[wv][half][ll] = __expf(l0[0] - mx[0]) * inv[0];
        }
        if (a1) {
            ssh[wv][half][32 + ll] = s1;
            if constexpr (H == 4) {
                float4 av = {__expf(l1[0] - mx[0]) * inv[0], __expf(l1[1] - mx[1]) * inv[1],
                             __expf(l1[2] - mx[2]) * inv[2], __expf(l1[3] - mx[3]) * inv[3]};
                *reinterpret_cast<float4*>(&alsh[wv][half][(32 + ll) * 4]) = av;
            } else alsh[wv][half][32 + ll] = __expf(l1[0] - mx[0]) * inv[0];
        }
        // same wave produces & consumes its own LDS slots: no barrier needed

        // ---- phase 2: serial gather, 4-wide, 16B loads (H=4) ----
        const ushort* hlane = hf + (size_t)ll * V;
        int j = 0;
        for (; j + 3 < deg; j += 4) {
            int sj[4]; float al[4];
#pragma unroll
            for (int k = 0; k < 4; ++k) {
                sj[k] = ssh[wv][half][j + k];
                al[k] = alsh[wv][half][(j + k) * H + hd];
            }
            if constexpr (V == 8) {
                short8 hv[4];
#pragma unroll
                for (int k = 0; k < 4; ++k)
                    hv[k] = *reinterpret_cast<const short8*>(hlane + (size_t)sj[k] * OF);
#pragma unroll
                for (int k = 0; k < 4; ++k)
#pragma unroll
                    for (int i = 0; i < 8; ++i)
                        acc[i] = fmaf(al[k], bf2f((ushort)hv[k][i]), acc[i]);
            } else {
                ushort2 hv[4];
#pragma unroll
                for (int k = 0; k < 4; ++k)
                    hv[k] = *reinterpret_cast<const ushort2*>(hlane + (size_t)sj[k] * OF);
#pragma unroll
                for (int k = 0; k < 4; ++k) {
                    acc[0] = fmaf(al[k], bf2f(hv[k].x), acc[0]);
                    acc[1] = fmaf(al[k], bf2f(hv[k].y), acc[1]);
                }
            }
        }
        for (; j < deg; ++j) {
            int sj = ssh[wv][half][j];
            float al = alsh[wv][half][j * H + hd];
            if constexpr (V == 8) {
                short8 hv = *reinterpret_cast<const short8*>(hlane + (size_t)sj * OF);
#pragma unroll
                for (int i = 0; i < 8; ++i)
                    acc[i] = fmaf(al, bf2f((ushort)hv[i]), acc[i]);
            } else {
                ushort2 hv = *reinterpret_cast<const ushort2*>(hlane + (size_t)sj * OF);
                acc[0] = fmaf(al, bf2f(hv.x), acc[0]);
                acc[1] = fmaf(al, bf2f(hv.y), acc[1]);
            }
        }
    } else {
        // ---- fallback (deg > 64, rare): 32-lane strided two-pass + recompute ----
        float mx[H], sm[H];
#pragma unroll
        for (int t = 0; t < H; ++t) mx[t] = -INFINITY;
        for (int e = e0 + ll; e < e1; e += 32) {
            int s = ssrc[e];
            float asv[H];
            if constexpr (H == 4) {
                float4 v = *reinterpret_cast<const float4*>(a_s + (size_t)s * 4);
                asv[0] = v.x; asv[1] = v.y; asv[2] = v.z; asv[3] = v.w;
            } else asv[0] = a_s[s];
#pragma unroll
            for (int t = 0; t < H; ++t) mx[t] = fmaxf(mx[t], lrelu(asv[t] + ad[t]));
        }
#pragma unroll
        for (int t = 0; t < H; ++t)
#pragma unroll
            for (int o = 1; o < 32; o <<= 1) mx[t] = fmaxf(mx[t], __shfl_xor(mx[t], o, 64));
#pragma unroll
        for (int t = 0; t < H; ++t) sm[t] = 0.f;
        for (int e = e0 + ll; e < e1; e += 32) {
            int s = ssrc[e];
            float asv[H];
            if constexpr (H == 4) {
                float4 v = *reinterpret_cast<const float4*>(a_s + (size_t)s * 4);
                asv[0] = v.x; asv[1] = v.y; asv[2] = v.z; asv[3] = v.w;
            } else asv[0] = a_s[s];
#pragma unroll
            for (int t = 0; t < H; ++t) sm[t] += __expf(lrelu(asv[t] + ad[t]) - mx[t]);
        }
#pragma unroll
        for (int t = 0; t < H; ++t)
#pragma unroll
            for (int o = 1; o < 32; o <<= 1) sm[t] += __shfl_xor(sm[t], o, 64);

        float mxl = mx[0], sml = sm[0], adl = ad[0];
#pragma unroll
        for (int t = 1; t < H; ++t) {
            mxl = (hd == t) ? mx[t] : mxl;
            sml = (hd == t) ? sm[t] : sml;
            adl = (hd == t) ? ad[t] : adl;
        }
        const float invl = 1.f / (sml + 1e-16f);
        const ushort* hlane = hf + (size_t)ll * V;
        for (int e = e0; e < e1; ++e) {
            int s0 = ssrc[e];
            float al0 = __expf(lrelu(a_s[(size_t)s0 * H + hd] + adl) - mxl) * invl;
            if constexpr (V == 8) {
                short8 hv = *reinterpret_cast<const short8*>(hlane + (size_t)s0 * OF);
#pragma unroll
                for (int i = 0; i < 8; ++i)
                    acc[i] = fmaf(al0, bf2f((ushort)hv[i]), acc[i]);
            } else {
                ushort2 hv = *reinterpret_cast<const ushort2*>(hlane + (size_t)s0 * OF);
                acc[0] = fmaf(al0, bf2f(hv.x), acc[0]);
                acc[1] = fmaf(al0, bf2f(hv.y), acc[1]);
            }
        }
    }

    // epilogue: + bias, ELU -> y (bf16 out + LDS stage for BN stats)
    float res[V];
#pragma unroll
    for (int i = 0; i < V; ++i) {
        float t = acc[i] + bias[ll * V + i];
        res[i] = t > 0.f ? t : (expf(t) - 1.f);
    }
    if constexpr (V == 8) {
        short8 yv = {(short)f2bf(res[0]), (short)f2bf(res[1]), (short)f2bf(res[2]), (short)f2bf(res[3]),
                     (short)f2bf(res[4]), (short)f2bf(res[5]), (short)f2bf(res[6]), (short)f2bf(res[7])};
        *reinterpret_cast<short8*>(&ybuf[(size_t)dst * OF + ll * 8]) = yv;
        *reinterpret_cast<f32x4*>(&ysh[dl][ll * 8 + 0]) = f32x4{res[0], res[1], res[2], res[3]};
        *reinterpret_cast<f32x4*>(&ysh[dl][ll * 8 + 4]) = f32x4{res[4], res[5], res[6], res[7]};
    } else {
        ushort2 yv = {f2bf(res[0]), f2bf(res[1])};
        *reinterpret_cast<ushort2*>(&ybuf[(size_t)dst * OF + ll * 2]) = yv;
        ysh[dl][ll * 2 + 0] = res[0];
        ysh[dl][ll * 2 + 1] = res[1];
    }
    __syncthreads();
    // BN partial sums: thread c reduces column c over the 8 staged rows
    if (tid < OF) {
        float s = 0.f, s2 = 0.f;
#pragma unroll
        for (int d = 0; d < 8; ++d) {
            float v = ysh[d][tid];
            s += v;
            s2 = fmaf(v, v, s2);
        }
        int slot = blockIdx.x & 7;
        atomicAdd(&bnsum[(size_t)slot * 2 * OF + tid], s);
        atomicAdd(&bnsum[(size_t)slot * 2 * OF + OF + tid], s2);
    }
}

// ---------------- edge bucketing ----------------
__global__ void edge_count(const int* __restrict__ ei, int* __restrict__ counts)
{
    int i = blockIdx.x * blockDim.x + threadIdx.x;
    if (i >= E_TOT) return;
    int dst = (i < NUM_E) ? ei[NUM_E + i] : (i - NUM_E);
    atomicAdd(&counts[dst], 1);
}

__global__ void edge_scatter(const int* __restrict__ ei, int* __restrict__ cursor,
                             int* __restrict__ ssrc)
{
    int i = blockIdx.x * blockDim.x + threadIdx.x;
    if (i >= E_TOT) return;
    int src, dst;
    if (i < NUM_E) { src = ei[i]; dst = ei[NUM_E + i]; }
    else           { src = dst = i - NUM_E; }
    int pos = atomicAdd(&cursor[dst], 1);
    ssrc[pos] = src;
}

// ---------------- scan: block scan then final with in-block prefix of bsums ----------------
__global__ void scan_block(const int* __restrict__ in, int n,
                           int* __restrict__ incl, int* __restrict__ bsum)
{
    __shared__ int sh[256];
    int tid = threadIdx.x;
    int i = blockIdx.x * 256 + tid;
    int v = (i < n) ? in[i] : 0;
    sh[tid] = v;
    __syncthreads();
    for (int o = 1; o < 256; o <<= 1) {
        int t = (tid >= o) ? sh[tid - o] : 0;
        __syncthreads();
        sh[tid] += t;
        __syncthreads();
    }
    if (i < n) incl[i] = sh[tid];
    if (tid == 255) bsum[blockIdx.x] = sh[255];
}

__global__ void scan_final(const int* __restrict__ incl, const int* __restrict__ in,
                           const int* __restrict__ bsum, int n,
                           int* __restrict__ offs, int* __restrict__ cursor)
{
    __shared__ int sh[256];
    const int tid = threadIdx.x;
    const int bi = blockIdx.x;
    sh[tid] = (tid < bi) ? bsum[tid] : 0;   // bi <= 195 < 256
    __syncthreads();
    for (int o = 128; o > 0; o >>= 1) {
        if (tid < o) sh[tid] += sh[tid + o];
        __syncthreads();
    }
    const int pref = sh[0];
    int i = bi * 256 + tid;
    if (i >= n) return;
    int excl = incl[i] - in[i] + pref;
    offs[i] = excl;
    cursor[i] = excl;
    if (i == n - 1) offs[n] = incl[i] + pref;
}

// ---------------- BN finalize: reduce 8 slots -> scale/shift ----------------
template<int OF>
__global__ void bn_finalize(const float* __restrict__ bnsum, const float* __restrict__ gamma,
                            const float* __restrict__ beta, float* __restrict__ ss)
{
    int c = threadIdx.x;
    if (c >= OF) return;
    float s = 0.f, s2 = 0.f;
#pragma unroll
    for (int slot = 0; slot < 8; ++slot) {
        s += bnsum[(size_t)slot * 2 * OF + c];
        s2 += bnsum[(size_t)slot * 2 * OF + OF + c];
    }
    float mean = s / (float)N_NODES;
    float var = s2 / (float)N_NODES - mean * mean;
    float inv = rsqrtf(var + EPS_BN);
    float sc = inv * gamma[c];
    ss[c] = sc;
    ss[OF + c] = beta[c] - mean * sc;
}

// ---------------- BN apply from y(bf16) + write xs fp32 (+AbfA bf16) + fused pooling ----------------
template<int OF, bool WB>
__global__ __launch_bounds__(256)
void bn_apply_pool(const ushort* __restrict__ y, float* __restrict__ xs, int ldx,
                   const float* __restrict__ ss, ushort* __restrict__ xb, int ldxb,
                   const int* __restrict__ batch, float* __restrict__ pool, int poff)
{
    const int tid = threadIdx.x;
    constexpr int CP = OF / 2;        // column pairs per row: 128 or 32
    constexpr int RS = 256 / CP;      // parallel row lanes: 2 or 8
    const int c = (tid % CP) * 2;
    const int rsub = tid / CP;
    const int r0 = blockIdx.x * 16;
    const float sc0 = ss[c], sh0 = ss[OF + c];
    const float sc1 = ss[c + 1], sh1 = ss[OF + c + 1];
    float ps0 = 0.f, ps1 = 0.f;
    int curg = batch[r0 + rsub];
#pragma unroll
    for (int i = 0; i < 16 / RS; ++i) {
        int r = r0 + rsub + i * RS;
        int g = batch[r];
        if (g != curg) {
            atomicAdd(&pool[(size_t)curg * XS_COLS + poff + c], ps0);
            atomicAdd(&pool[(size_t)curg * XS_COLS + poff + c + 1], ps1);
            ps0 = ps1 = 0.f; curg = g;
        }
        ushort2 hv = *reinterpret_cast<const ushort2*>(y + (size_t)r * OF + c);
        float v0 = fmaf(bf2f(hv.x), sc0, sh0);
        float v1 = fmaf(bf2f(hv.y), sc1, sh1);
        float2 vv = {v0, v1};
        *reinterpret_cast<float2*>(&xs[(size_t)r * ldx + c]) = vv;
        if constexpr (WB) {
            ushort2 bb = {f2bf(v0), f2bf(v1)};
            *reinterpret_cast<ushort2*>(&xb[(size_t)r * ldxb + c]) = bb;
        }
        ps0 += v0; ps1 += v1;
    }
    atomicAdd(&pool[(size_t)curg * XS_COLS + poff + c], ps0);
    atomicAdd(&pool[(size_t)curg * XS_COLS + poff + c + 1], ps1);
}

extern "C" void kernel_launch(void* const* d_in, const int* in_sizes, int n_in,
                              void* d_out, int out_size, void* d_ws, size_t ws_size,
                              hipStream_t stream)
{
    const float* x     = (const float*)d_in[0];
    const int*   ei    = (const int*)d_in[1];
    const int*   batch = (const int*)d_in[2];
    const float* W[3]    = {(const float*)d_in[3],  (const float*)d_in[9],  (const float*)d_in[15]};
    const float* asrc[3] = {(const float*)d_in[4],  (const float*)d_in[10], (const float*)d_in[16]};
    const float* adst[3] = {(const float*)d_in[5],  (const float*)d_in[11], (const float*)d_in[17]};
    const float* bia[3]  = {(const float*)d_in[6],  (const float*)d_in[12], (const float*)d_in[18]};
    const float* gam[3]  = {(const float*)d_in[7],  (const float*)d_in[13], (const float*)d_in[19]};
    const float* bet[3]  = {(const float*)d_in[8],  (const float*)d_in[14], (const float*)d_in[20]};

    char* wp = (char*)d_ws;
    auto alloc = [&](size_t bytes) -> void* {
        void* p = (void*)wp;
        wp += (bytes + 255) & ~(size_t)255;
        return p;
    };
    ushort* hbf   = (ushort*)alloc((size_t)N_NODES * 256 * 2);
    ushort* ybuf  = (ushort*)alloc((size_t)N_NODES * 256 * 2);
    ushort* AbfA  = (ushort*)alloc((size_t)M_PAD * 256 * 2);
    float*  a_s   = (float*)alloc((size_t)N_NODES * 4 * 4);
    float*  a_d   = (float*)alloc((size_t)N_NODES * 4 * 4);
    int*    counts = (int*)alloc((size_t)N_NODES * 4);
    int*    offs   = (int*)alloc((size_t)(N_NODES + 1) * 4);
    int*    cursor = (int*)alloc((size_t)N_NODES * 4);
    int*    incl   = (int*)alloc((size_t)N_NODES * 4);
    int*    bsums  = (int*)alloc(1024);
    int*    ssrc   = (int*)alloc((size_t)E_TOT * 4);
    float*  bnsum  = (float*)alloc((size_t)8 * 2 * 256 * 4);
    float*  bnss   = (float*)alloc(2 * 256 * 4);
    ushort* Wt0    = (ushort*)alloc(256 * 128 * 2);
    ushort* Wt1    = (ushort*)alloc(256 * 256 * 2);
    ushort* Wt2    = (ushort*)alloc(64 * 256 * 2);

    float* pool = (float*)d_out;                    // [128, 576]
    float* xs   = pool + (size_t)NGRAPH * XS_COLS;  // [50000, 576]

    // ---- setup ----
    hipMemsetAsync(counts, 0, (size_t)N_NODES * 4, stream);
    hipMemsetAsync(pool, 0, (size_t)NGRAPH * XS_COLS * 4, stream);
    edge_count<<<ceil_div(E_TOT, 256), 256, 0, stream>>>(ei, counts);
    const int NSB = ceil_div(N_NODES, 256);
    scan_block<<<NSB, 256, 0, stream>>>(counts, N_NODES, incl, bsums);
    scan_final<<<NSB, 256, 0, stream>>>(incl, counts, bsums, N_NODES, offs, cursor);
    edge_scatter<<<ceil_div(E_TOT, 256), 256, 0, stream>>>(ei, cursor, ssrc);
    const int PREP_ITEMS = 256 * 128 + 256 * 256 + 64 * 256;
    prep_w<<<ceil_div(PREP_ITEMS, 256), 256, 0, stream>>>(W[0], W[1], W[2], Wt0, Wt1, Wt2);

    const int NW2 = ceil_div(N_NODES, 8);   // 6250 (exact: 6250*8 = 50000)
    const int NMB = ceil_div(N_NODES, 128);
    const int NBA = N_NODES / 16;           // 3125, exact

    // ---------------- layer 0: 128 -> 4x64 concat (256) ----------------
    {
        gemm_bf16_w<true><<<NMB, 512, 0, stream>>>(x, 128, Wt0, 128, hbf, N_NODES, 128,
                                                   asrc[0], adst[0], a_s, a_d);
        hipMemsetAsync(bnsum, 0, (size_t)8 * 2 * 256 * 4, stream);
        gat_fused2<4, 64><<<NW2, 256, 0, stream>>>(offs, ssrc, a_s, a_d, hbf, bia[0], ybuf, bnsum);
        bn_finalize<256><<<1, 256, 0, stream>>>(bnsum, gam[0], bet[0], bnss);
        bn_apply_pool<256, true><<<NBA, 256, 0, stream>>>(ybuf, xs + 0, XS_COLS, bnss, AbfA, 256,
                                                          batch, pool, 0);
    }
    // ---------------- layer 1: 256 -> 4x64 concat (256) ----------------
    {
        gemm_bf16_w<false><<<NMB, 512, 0, stream>>>(AbfA, 256, Wt1, 256, hbf, N_NODES, 256,
                                                    asrc[1], adst[1], a_s, a_d);
        hipMemsetAsync(bnsum, 0, (size_t)8 * 2 * 256 * 4, stream);
        gat_fused2<4, 64><<<NW2, 256, 0, stream>>>(offs, ssrc, a_s, a_d, hbf, bia[1], ybuf, bnsum);
        bn_finalize<256><<<1, 256, 0, stream>>>(bnsum, gam[1], bet[1], bnss);
        bn_apply_pool<256, true><<<NBA, 256, 0, stream>>>(ybuf, xs + 256, XS_COLS, bnss, AbfA, 256,
                                                          batch, pool, 256);
    }
    // ---------------- layer 2: 256 -> 1x64 ----------------
    {
        dim3 grid(NMB, 1);
        gemm_bf16<128, 64, 64, 1><<<grid, 256, 0, stream>>>(AbfA, 256, Wt2, 256, hbf, 64, N_NODES, 256,
                                                            asrc[2], adst[2], a_s, a_d);
        hipMemsetAsync(bnsum, 0, (size_t)8 * 2 * 256 * 4, stream);
        gat_fused2<1, 64><<<NW2, 256, 0, stream>>>(offs, ssrc, a_s, a_d, hbf, bia[2], ybuf, bnsum);
        bn_finalize<64><<<1, 64, 0, stream>>>(bnsum, gam[2], bet[2], bnss);
        bn_apply_pool<64, false><<<NBA, 256, 0, stream>>>(ybuf, xs + 512, XS_COLS, bnss, nullptr, 0,
                                                          batch, pool, 512);
    }
}